// Round 1
// baseline (660.510 us; speedup 1.0000x reference)
//
#include <hip/hip_runtime.h>

namespace {

constexpr int NN   = 307;
constexpr int LNUM = 12;
constexpr int SP   = NN * LNUM;        // 3684
constexpr int DCH  = 128;
constexpr int HH   = 8;
constexpr int DK   = 16;
constexpr int BB   = 8;
constexpr int SZB  = DCH * SP;         // 471552 per batch
constexpr int SZ   = BB * SZB;         // 3772416 total
constexpr int ADJN = NN * NN;          // 94249
constexpr int DN   = DCH * NN;         // 39296 (layernorm group size)
constexpr int LN_CH = 48;
constexpr int LN_DNC = 819;            // ceil(39296/48)
constexpr int MST  = HH * LNUM * NN * DK;  // mem_bank per-slot stride = 471552

// ---------------- small prep kernels ----------------

// Transpose all 7 [128][128] weight matrices into Wt[c][o] layout.
__global__ __launch_bounds__(256) void k_transW(
    const float* __restrict__ W0, const float* __restrict__ W1,
    const float* __restrict__ W2, const float* __restrict__ W3,
    const float* __restrict__ W4, const float* __restrict__ W5,
    const float* __restrict__ W6, float* __restrict__ Wt) {
  const float* srcs[7] = {W0, W1, W2, W3, W4, W5, W6};
  int w = blockIdx.y;
  int idx = blockIdx.x * 256 + threadIdx.x;   // 0..16383
  int o = idx >> 7, c = idx & 127;
  Wt[w * 16384 + c * 128 + o] = srcs[w][idx];
}

// s1 = softmax(relu(nv1 @ nv2), axis=-1). One block per row i.
__global__ __launch_bounds__(320) void k_s1(
    const float* __restrict__ nv1, const float* __restrict__ nv2,
    float* __restrict__ out) {
  __shared__ float red[512];
  __shared__ float rowA[10];
  const int i = blockIdx.x, j = threadIdx.x;
  if (j < 10) rowA[j] = nv1[i * 10 + j];
  __syncthreads();
  float val = 0.f;
  if (j < NN) {
#pragma unroll
    for (int k = 0; k < 10; ++k) val += rowA[k] * nv2[k * NN + j];
    val = fmaxf(val, 0.f);
  }
  red[j] = (j < NN) ? val : -3.4e38f;
  if (j < 192) red[j + 320] = -3.4e38f;
  __syncthreads();
  for (int s = 256; s >= 1; s >>= 1) {
    if (j < s) red[j] = fmaxf(red[j], red[j + s]);
    __syncthreads();
  }
  float mx = red[0];
  __syncthreads();
  float e = (j < NN) ? __expf(val - mx) : 0.f;
  red[j] = e;
  if (j < 192) red[j + 320] = 0.f;
  __syncthreads();
  for (int s = 256; s >= 1; s >>= 1) {
    if (j < s) red[j] += red[j + s];
    __syncthreads();
  }
  if (j < NN) out[i * NN + j] = e / red[0];
}

// out = softmax(Sa @ Sb, axis=-1). One block per row i.
__global__ __launch_bounds__(320) void k_smm(
    const float* __restrict__ Sa, const float* __restrict__ Sb,
    float* __restrict__ out) {
  __shared__ float red[512];
  __shared__ float rowA[320];
  const int i = blockIdx.x, j = threadIdx.x;
  if (j < NN) rowA[j] = Sa[i * NN + j];
  __syncthreads();
  float val = 0.f;
  if (j < NN) {
    for (int k = 0; k < NN; ++k) val += rowA[k] * Sb[k * NN + j];
  }
  red[j] = (j < NN) ? val : -3.4e38f;
  if (j < 192) red[j + 320] = -3.4e38f;
  __syncthreads();
  for (int s = 256; s >= 1; s >>= 1) {
    if (j < s) red[j] = fmaxf(red[j], red[j + s]);
    __syncthreads();
  }
  float mx = red[0];
  __syncthreads();
  float e = (j < NN) ? __expf(val - mx) : 0.f;
  red[j] = e;
  if (j < 192) red[j + 320] = 0.f;
  __syncthreads();
  for (int s = 256; s >= 1; s >>= 1) {
    if (j < s) red[j] += red[j + s];
    __syncthreads();
  }
  if (j < NN) out[i * NN + j] = e / red[0];
}

// adj = sw0*s1 + sw1*s2 + sw2*s3, sw = softmax(sws)
__global__ void k_adj(const float* __restrict__ s1, const float* __restrict__ s2,
                      const float* __restrict__ s3, const float* __restrict__ sws,
                      float* __restrict__ adj) {
  int idx = blockIdx.x * 256 + threadIdx.x;
  if (idx >= ADJN) return;
  float w0 = sws[0], w1 = sws[1], w2 = sws[2];
  float m = fmaxf(w0, fmaxf(w1, w2));
  float e0 = __expf(w0 - m), e1 = __expf(w1 - m), e2 = __expf(w2 - m);
  float inv = 1.f / (e0 + e1 + e2);
  adj[idx] = (e0 * s1[idx] + e1 * s2[idx] + e2 * s3[idx]) * inv;
}

// mem_w[b][0..3]: avg -> MLP -> softmax -> imp* -> softmax. One block per b.
__global__ __launch_bounds__(128) void k_memw(
    const float* __restrict__ x, const float* __restrict__ A1,
    const float* __restrict__ a1b, const float* __restrict__ A2,
    const float* __restrict__ a2b, const float* __restrict__ mimp,
    float* __restrict__ memw) {
  const int b = blockIdx.x, t = threadIdx.x;
  __shared__ float avg[128];
  __shared__ float hbuf[64];
  __shared__ float lg[4];
  float s = 0.f;
  const float* xp = x + (size_t)(b * DCH + t) * SP;
  for (int i = 0; i < SP; ++i) s += xp[i];
  avg[t] = s * (1.f / SP);
  __syncthreads();
  if (t < 64) {
    float a = a1b[t];
    for (int d = 0; d < 128; ++d) a += avg[d] * A1[d * 64 + t];
    hbuf[t] = fmaxf(a, 0.f);
  }
  __syncthreads();
  if (t < 4) {
    float a = a2b[t];
    for (int j = 0; j < 64; ++j) a += hbuf[j] * A2[j * 4 + t];
    lg[t] = a;
  }
  __syncthreads();
  if (t == 0) {
    float mx = fmaxf(fmaxf(lg[0], lg[1]), fmaxf(lg[2], lg[3]));
    float e[4]; float se = 0.f;
    for (int m = 0; m < 4; ++m) { e[m] = __expf(lg[m] - mx); se += e[m]; }
    float w[4]; float mx2 = -3.4e38f;
    for (int m = 0; m < 4; ++m) { w[m] = mimp[m] * (e[m] / se); mx2 = fmaxf(mx2, w[m]); }
    float se2 = 0.f;
    for (int m = 0; m < 4; ++m) { e[m] = __expf(w[m] - mx2); se2 += e[m]; }
    for (int m = 0; m < 4; ++m) memw[b * 4 + m] = e[m] / se2;
  }
}

// ---------------- 1x1 conv (GEMM) ----------------
// MODE 0: in standard [B,D,S]; out = relu(acc+b) written to q5 layout [B,H,L,N,K]
// MODE 1: in y5 layout [B,H,L,N,K]; out standard = acc + b + input(residual)
// MODE 2: in standard; out = relu(acc+b)*(aw+1) + ab + ax   (ax standard layout)
// MODE 3: in standard; out = (acc + b + ax)*(aw+1) + ab     (ax standard layout)
template <int MODE>
__global__ __launch_bounds__(256) void k_conv(
    const float* __restrict__ X, const float* __restrict__ Wt,
    const float* __restrict__ bvec, float* __restrict__ out,
    const float* __restrict__ aw, const float* __restrict__ ab,
    const float* __restrict__ ax) {
  __shared__ float Xs[128][64];
  __shared__ float Ws[128][64];
  const int sBase = blockIdx.x * 64;
  const int oBase = blockIdx.y * 64;
  const int b = blockIdx.z;
  const int t = threadIdx.x;
#pragma unroll
  for (int i = 0; i < 32; ++i) {
    int idx = t + i * 256;
    int c = idx >> 6, u = idx & 63;
    Ws[c][u] = Wt[c * 128 + oBase + u];
    int s = sBase + u;
    float v = 0.f;
    if (s < SP) {
      if constexpr (MODE == 1) {
        int n = s / 12, l2 = s - n * 12;
        int hh = c >> 4, kk = c & 15;
        v = X[(((b * HH + hh) * LNUM + l2) * NN + n) * DK + kk];
      } else {
        v = X[(size_t)(b * DCH + c) * SP + s];
      }
    }
    Xs[c][u] = v;
  }
  __syncthreads();
  const int tx = t & 15, ty = t >> 4;
  float acc[4][4] = {};
#pragma unroll 4
  for (int c = 0; c < 128; ++c) {
    float4 xv = *(const float4*)&Xs[c][tx * 4];
    float4 wv = *(const float4*)&Ws[c][ty * 4];
    acc[0][0] += wv.x * xv.x; acc[0][1] += wv.x * xv.y; acc[0][2] += wv.x * xv.z; acc[0][3] += wv.x * xv.w;
    acc[1][0] += wv.y * xv.x; acc[1][1] += wv.y * xv.y; acc[1][2] += wv.y * xv.z; acc[1][3] += wv.y * xv.w;
    acc[2][0] += wv.z * xv.x; acc[2][1] += wv.z * xv.y; acc[2][2] += wv.z * xv.z; acc[2][3] += wv.z * xv.w;
    acc[3][0] += wv.w * xv.x; acc[3][1] += wv.w * xv.y; acc[3][2] += wv.w * xv.z; acc[3][3] += wv.w * xv.w;
  }
  const int s0 = sBase + tx * 4;
  const int o0 = oBase + ty * 4;

  if constexpr (MODE == 0) {
    const int hh = o0 >> 4, k0 = o0 & 15;
    float b0 = bvec[o0], b1 = bvec[o0 + 1], b2 = bvec[o0 + 2], b3 = bvec[o0 + 3];
#pragma unroll
    for (int si = 0; si < 4; ++si) {
      int s = s0 + si;
      if (s < SP) {
        int n = s / 12, l2 = s - n * 12;
        float4 val;
        val.x = fmaxf(acc[0][si] + b0, 0.f);
        val.y = fmaxf(acc[1][si] + b1, 0.f);
        val.z = fmaxf(acc[2][si] + b2, 0.f);
        val.w = fmaxf(acc[3][si] + b3, 0.f);
        *(float4*)(out + (((b * HH + hh) * LNUM + l2) * NN + n) * DK + k0) = val;
      }
    }
  } else if constexpr (MODE == 1) {
    if (s0 < SP) {
#pragma unroll
      for (int oi = 0; oi < 4; ++oi) {
        int o = o0 + oi;
        float bb = bvec[o];
        float4 val;
        val.x = acc[oi][0] + bb + Xs[o][tx * 4 + 0];
        val.y = acc[oi][1] + bb + Xs[o][tx * 4 + 1];
        val.z = acc[oi][2] + bb + Xs[o][tx * 4 + 2];
        val.w = acc[oi][3] + bb + Xs[o][tx * 4 + 3];
        *(float4*)(out + (size_t)(b * DCH + o) * SP + s0) = val;
      }
    }
  } else if constexpr (MODE == 2) {
    if (s0 < SP) {
#pragma unroll
      for (int oi = 0; oi < 4; ++oi) {
        int o = o0 + oi;
        float bb = bvec[o];
        float4 w  = *(const float4*)(aw + o * SP + s0);
        float4 bi = *(const float4*)(ab + o * SP + s0);
        float4 xv = *(const float4*)(ax + (size_t)(b * DCH + o) * SP + s0);
        float4 val;
        float r;
        r = fmaxf(acc[oi][0] + bb, 0.f); val.x = r * (w.x + 1.f) + bi.x + xv.x;
        r = fmaxf(acc[oi][1] + bb, 0.f); val.y = r * (w.y + 1.f) + bi.y + xv.y;
        r = fmaxf(acc[oi][2] + bb, 0.f); val.z = r * (w.z + 1.f) + bi.z + xv.z;
        r = fmaxf(acc[oi][3] + bb, 0.f); val.w = r * (w.w + 1.f) + bi.w + xv.w;
        *(float4*)(out + (size_t)(b * DCH + o) * SP + s0) = val;
      }
    }
  } else {  // MODE 3
    if (s0 < SP) {
#pragma unroll
      for (int oi = 0; oi < 4; ++oi) {
        int o = o0 + oi;
        float bb = bvec[o];
        float4 w  = *(const float4*)(aw + o * SP + s0);
        float4 bi = *(const float4*)(ab + o * SP + s0);
        float4 zv = *(const float4*)(ax + (size_t)(b * DCH + o) * SP + s0);
        float4 val;
        float tt;
        tt = acc[oi][0] + bb + zv.x; val.x = tt * (w.x + 1.f) + bi.x;
        tt = acc[oi][1] + bb + zv.y; val.y = tt * (w.y + 1.f) + bi.y;
        tt = acc[oi][2] + bb + zv.z; val.z = tt * (w.z + 1.f) + bi.z;
        tt = acc[oi][3] + bb + zv.w; val.w = tt * (w.w + 1.f) + bi.w;
        *(float4*)(out + (size_t)(b * DCH + o) * SP + s0) = val;
      }
    }
  }
}

// GLU conv: out = (conv(X,W1)+b1) * sigmoid(conv(X,W2)+b2), standard layout in/out.
__global__ __launch_bounds__(256) void k_conv_glu(
    const float* __restrict__ X, const float* __restrict__ Wt1,
    const float* __restrict__ Wt2, const float* __restrict__ b1,
    const float* __restrict__ b2, float* __restrict__ out) {
  __shared__ float Xs[128][64];
  __shared__ float W1s[128][32];
  __shared__ float W2s[128][32];
  const int sBase = blockIdx.x * 64;
  const int oBase = blockIdx.y * 32;
  const int b = blockIdx.z;
  const int t = threadIdx.x;
#pragma unroll
  for (int i = 0; i < 32; ++i) {
    int idx = t + i * 256;
    int c = idx >> 6, u = idx & 63;
    int s = sBase + u;
    Xs[c][u] = (s < SP) ? X[(size_t)(b * DCH + c) * SP + s] : 0.f;
  }
#pragma unroll
  for (int i = 0; i < 16; ++i) {
    int idx = t + i * 256;
    int c = idx >> 5, o = idx & 31;
    W1s[c][o] = Wt1[c * 128 + oBase + o];
    W2s[c][o] = Wt2[c * 128 + oBase + o];
  }
  __syncthreads();
  const int tx = t & 15, ty = t >> 4;
  float a1[2][4] = {};
  float a2[2][4] = {};
#pragma unroll 4
  for (int c = 0; c < 128; ++c) {
    float4 xv = *(const float4*)&Xs[c][tx * 4];
    float2 w1 = *(const float2*)&W1s[c][ty * 2];
    float2 w2 = *(const float2*)&W2s[c][ty * 2];
    a1[0][0] += w1.x * xv.x; a1[0][1] += w1.x * xv.y; a1[0][2] += w1.x * xv.z; a1[0][3] += w1.x * xv.w;
    a1[1][0] += w1.y * xv.x; a1[1][1] += w1.y * xv.y; a1[1][2] += w1.y * xv.z; a1[1][3] += w1.y * xv.w;
    a2[0][0] += w2.x * xv.x; a2[0][1] += w2.x * xv.y; a2[0][2] += w2.x * xv.z; a2[0][3] += w2.x * xv.w;
    a2[1][0] += w2.y * xv.x; a2[1][1] += w2.y * xv.y; a2[1][2] += w2.y * xv.z; a2[1][3] += w2.y * xv.w;
  }
  const int s0 = sBase + tx * 4;
  if (s0 < SP) {
#pragma unroll
    for (int oi = 0; oi < 2; ++oi) {
      int o = oBase + ty * 2 + oi;
      float bb1 = b1[o], bb2 = b2[o];
      float4 val;
      float v1, v2;
      v1 = a1[oi][0] + bb1; v2 = a2[oi][0] + bb2; val.x = v1 / (1.f + __expf(-v2));
      v1 = a1[oi][1] + bb1; v2 = a2[oi][1] + bb2; val.y = v1 / (1.f + __expf(-v2));
      v1 = a1[oi][2] + bb1; v2 = a2[oi][2] + bb2; val.z = v1 / (1.f + __expf(-v2));
      v1 = a1[oi][3] + bb1; v2 = a2[oi][3] + bb2; val.w = v1 / (1.f + __expf(-v2));
      *(float4*)(out + (size_t)(b * DCH + o) * SP + s0) = val;
    }
  }
}

// ---------------- attention + graph diffusion ----------------
// One block per (b,h,l). Thread t owns row n=t. Writes y5 [B,H,L,N,K].
__global__ __launch_bounds__(320) void k_attn(
    const float* __restrict__ q5, const float* __restrict__ v5,
    const float* __restrict__ memb, const float* __restrict__ memw,
    const float* __restrict__ adj, float* __restrict__ y5) {
  __shared__ float self[NN][DK];
  __shared__ float vl[NN][DK];
  const int l = blockIdx.x, h = blockIdx.y, b = blockIdx.z;
  const int t = threadIdx.x;
  const float w0 = memw[b * 4 + 0], w1 = memw[b * 4 + 1];
  const float w2 = memw[b * 4 + 2], w3 = memw[b * 4 + 3];
  const int slice = ((b * HH + h) * LNUM + l) * NN * DK;
  const int msl = (h * LNUM + l) * NN * DK;
  for (int idx = t; idx < NN * DK; idx += 320) {
    float m0 = memb[msl + idx];
    float m1 = memb[MST + msl + idx];
    float m2 = memb[2 * MST + msl + idx];
    float m3 = memb[3 * MST + msl + idx];
    ((float*)self)[idx] = w0 * m0 + w1 * m1 + w2 * m2 + w3 * m3;
    ((float*)vl)[idx] = v5[slice + idx];
  }
  __syncthreads();
  const bool act = (t < NN);
  float4 q0 = {0, 0, 0, 0}, q1 = q0, q2 = q0, q3 = q0;
  if (act) {
    const float4* qp = (const float4*)(q5 + slice + t * DK);
    q0 = qp[0]; q1 = qp[1]; q2 = qp[2]; q3 = qp[3];
  }
  // pass A: row max of logits
  float mx = -3.4e38f;
  for (int m = 0; m < NN; ++m) {
    const float4* sp = (const float4*)&self[m][0];
    float4 s0 = sp[0], s1 = sp[1], s2 = sp[2], s3 = sp[3];
    float s = q0.x * s0.x + q0.y * s0.y + q0.z * s0.z + q0.w * s0.w
            + q1.x * s1.x + q1.y * s1.y + q1.z * s1.z + q1.w * s1.w
            + q2.x * s2.x + q2.y * s2.y + q2.z * s2.z + q2.w * s2.w
            + q3.x * s3.x + q3.y * s3.y + q3.z * s3.z + q3.w * s3.w;
    mx = fmaxf(mx, s);
  }
  // pass B: softmax-weighted PV + graph accumulate
  float4 p0 = {0, 0, 0, 0}, p1 = p0, p2 = p0, p3 = p0;
  float4 g0 = p0, g1 = p0, g2 = p0, g3 = p0;
  float denom = 0.f;
  for (int m = 0; m < NN; ++m) {
    const float4* sp = (const float4*)&self[m][0];
    float4 s0 = sp[0], s1 = sp[1], s2 = sp[2], s3 = sp[3];
    float s = q0.x * s0.x + q0.y * s0.y + q0.z * s0.z + q0.w * s0.w
            + q1.x * s1.x + q1.y * s1.y + q1.z * s1.z + q1.w * s1.w
            + q2.x * s2.x + q2.y * s2.y + q2.z * s2.z + q2.w * s2.w
            + q3.x * s3.x + q3.y * s3.y + q3.z * s3.z + q3.w * s3.w;
    float p = __expf((s - mx) * 0.25f);
    denom += p;
    float a = act ? adj[m * NN + t] : 0.f;
    const float4* vp = (const float4*)&vl[m][0];
    float4 v0 = vp[0], v1 = vp[1], v2 = vp[2], v3 = vp[3];
    p0.x += p * v0.x; p0.y += p * v0.y; p0.z += p * v0.z; p0.w += p * v0.w;
    p1.x += p * v1.x; p1.y += p * v1.y; p1.z += p * v1.z; p1.w += p * v1.w;
    p2.x += p * v2.x; p2.y += p * v2.y; p2.z += p * v2.z; p2.w += p * v2.w;
    p3.x += p * v3.x; p3.y += p * v3.y; p3.z += p * v3.z; p3.w += p * v3.w;
    g0.x += a * v0.x; g0.y += a * v0.y; g0.z += a * v0.z; g0.w += a * v0.w;
    g1.x += a * v1.x; g1.y += a * v1.y; g1.z += a * v1.z; g1.w += a * v1.w;
    g2.x += a * v2.x; g2.y += a * v2.y; g2.z += a * v2.z; g2.w += a * v2.w;
    g3.x += a * v3.x; g3.y += a * v3.y; g3.z += a * v3.z; g3.w += a * v3.w;
  }
  if (act) {
    float inv = 1.f / denom;
    float4* op = (float4*)(y5 + slice + t * DK);
    float4 o0 = {p0.x * inv + g0.x, p0.y * inv + g0.y, p0.z * inv + g0.z, p0.w * inv + g0.w};
    float4 o1 = {p1.x * inv + g1.x, p1.y * inv + g1.y, p1.z * inv + g1.z, p1.w * inv + g1.w};
    float4 o2 = {p2.x * inv + g2.x, p2.y * inv + g2.y, p2.z * inv + g2.z, p2.w * inv + g2.w};
    float4 o3 = {p3.x * inv + g3.x, p3.y * inv + g3.y, p3.z * inv + g3.z, p3.w * inv + g3.w};
    op[0] = o0; op[1] = o1; op[2] = o2; op[3] = o3;
  }
}

// ---------------- layernorm over (D,N) per (b,l), 3-kernel split ----------------

__global__ __launch_bounds__(192) void k_lnstat(
    const float* __restrict__ in, float* __restrict__ pS, float* __restrict__ pSS) {
  const int c = blockIdx.x, b = blockIdx.y, t = threadIdx.x;
  const int dn0 = c * LN_DNC;
  const int dn1 = min(dn0 + LN_DNC, DN);
  const int cnt = (dn1 - dn0) * LNUM;
  const float* p = in + (size_t)b * SZB + (size_t)dn0 * LNUM;
  float s = 0.f, ss = 0.f;
  for (int i = t; i < cnt; i += 192) {  // i%12 == t%12 (192%12==0, base%12==0)
    float v = p[i];
    s += v; ss += v * v;
  }
  __shared__ float rs[192], rss[192];
  rs[t] = s; rss[t] = ss;
  __syncthreads();
  if (t < 12) {
    float S = 0.f, SS = 0.f;
    for (int j = t; j < 192; j += 12) { S += rs[j]; SS += rss[j]; }
    pS[(b * LN_CH + c) * 12 + t] = S;
    pSS[(b * LN_CH + c) * 12 + t] = SS;
  }
}

__global__ __launch_bounds__(96) void k_lnfin(
    const float* __restrict__ pS, const float* __restrict__ pSS,
    float* __restrict__ meanp, float* __restrict__ rstdp) {
  const int t = threadIdx.x;  // t = b*12 + l
  const int b = t / 12, l = t % 12;
  float S = 0.f, SS = 0.f;
  for (int c = 0; c < LN_CH; ++c) {
    S += pS[(b * LN_CH + c) * 12 + l];
    SS += pSS[(b * LN_CH + c) * 12 + l];
  }
  float mu = S * (1.f / DN);
  float var = SS * (1.f / DN) - mu * mu;
  meanp[t] = mu;
  rstdp[t] = rsqrtf(fmaxf(var, 0.f) + 1e-5f);
}

__global__ __launch_bounds__(256) void k_lnapply(
    const float* __restrict__ in, const float* __restrict__ meanp,
    const float* __restrict__ rstdp, float* __restrict__ outp) {
  const int i0 = (blockIdx.x * 256 + threadIdx.x) * 4;
  float4 v = *(const float4*)(in + i0);
  const int b = (int)((unsigned)i0 / (unsigned)SZB);
  const int r = i0 - b * SZB;
  const int l0 = r % 12;  // in {0,4,8}; l0+3 <= 11, no wrap
  const float* mp = meanp + b * 12;
  const float* rp = rstdp + b * 12;
  float4 o;
  o.x = (v.x - mp[l0 + 0]) * rp[l0 + 0];
  o.y = (v.y - mp[l0 + 1]) * rp[l0 + 1];
  o.z = (v.z - mp[l0 + 2]) * rp[l0 + 2];
  o.w = (v.w - mp[l0 + 3]) * rp[l0 + 3];
  *(float4*)(outp + i0) = o;
}

}  // namespace

extern "C" void kernel_launch(void* const* d_in, const int* in_sizes, int n_in,
                              void* d_out, int out_size, void* d_ws, size_t ws_size,
                              hipStream_t stream) {
  (void)in_sizes; (void)n_in; (void)out_size; (void)ws_size;
  const float* x    = (const float*)d_in[0];
  const float* Wq   = (const float*)d_in[1];
  const float* bq   = (const float*)d_in[2];
  const float* Wv   = (const float*)d_in[3];
  const float* bv   = (const float*)d_in[4];
  const float* Wc   = (const float*)d_in[5];
  const float* bc   = (const float*)d_in[6];
  const float* Wx   = (const float*)d_in[7];
  const float* bx   = (const float*)d_in[8];
  const float* Wg1  = (const float*)d_in[9];
  const float* bg1  = (const float*)d_in[10];
  const float* Wg2  = (const float*)d_in[11];
  const float* bg2  = (const float*)d_in[12];
  const float* Wg3  = (const float*)d_in[13];
  const float* bg3  = (const float*)d_in[14];
  const float* memb = (const float*)d_in[15];
  const float* mimp = (const float*)d_in[16];
  const float* A1   = (const float*)d_in[17];
  const float* a1b  = (const float*)d_in[18];
  const float* A2   = (const float*)d_in[19];
  const float* a2b  = (const float*)d_in[20];
  const float* wgt  = (const float*)d_in[21];
  const float* bia  = (const float*)d_in[22];
  const float* nv1  = (const float*)d_in[23];
  const float* nv2  = (const float*)d_in[24];
  const float* sws  = (const float*)d_in[25];

  // workspace layout (floats); total ~45.1 MB
  float* ws = (float*)d_ws;
  float* P0 = ws;
  float* P1 = ws + (size_t)SZ;
  float* P2 = ws + 2 * (size_t)SZ;
  float* sm = ws + 3 * (size_t)SZ;
  float* s1 = sm;
  float* s2 = sm + ADJN;
  float* s3 = sm + 2 * ADJN;
  float* adjp = sm + 3 * ADJN;
  float* memw = sm + 4 * ADJN;          // 32
  float* WtA  = memw + 32;              // 7*16384
  float* pS   = WtA + 7 * 16384;        // 8*48*12
  float* pSS  = pS + BB * LN_CH * 12;
  float* meanp = pSS + BB * LN_CH * 12; // 96
  float* rstdp = meanp + 96;            // 96

  k_transW<<<dim3(64, 7), 256, 0, stream>>>(Wq, Wv, Wx, Wc, Wg1, Wg2, Wg3, WtA);
  k_s1<<<NN, 320, 0, stream>>>(nv1, nv2, s1);
  k_smm<<<NN, 320, 0, stream>>>(s1, s1, s2);
  k_smm<<<NN, 320, 0, stream>>>(s2, s1, s3);
  k_adj<<<(ADJN + 255) / 256, 256, 0, stream>>>(s1, s2, s3, sws, adjp);
  k_memw<<<BB, 128, 0, stream>>>(x, A1, a1b, A2, a2b, mimp, memw);

  // q5, v5 projections (write permuted [B,H,L,N,K] layout)
  k_conv<0><<<dim3(58, 2, BB), 256, 0, stream>>>(x, WtA + 0 * 16384, bq, P0, nullptr, nullptr, nullptr);
  k_conv<0><<<dim3(58, 2, BB), 256, 0, stream>>>(x, WtA + 1 * 16384, bv, P1, nullptr, nullptr, nullptr);

  // attention + graph -> y5 (P2)
  k_attn<<<dim3(LNUM, HH, BB), 320, 0, stream>>>(P0, P1, memb, memw, adjp, P2);

  // t = y + conv(y, Wx, bx): y5 input, standard output (P0)
  k_conv<1><<<dim3(58, 2, BB), 256, 0, stream>>>(P2, WtA + 2 * 16384, bx, P0, nullptr, nullptr, nullptr);
  // z_in = relu(conv(t, Wc, bc))*(w+1) + bias + x  (P1)
  k_conv<2><<<dim3(58, 2, BB), 256, 0, stream>>>(P0, WtA + 3 * 16384, bc, P1, wgt, bia, x);

  // z = ln12(z_in)  (P1 -> P2)
  k_lnstat<<<dim3(LN_CH, BB), 192, 0, stream>>>(P1, pS, pSS);
  k_lnfin<<<1, 96, 0, stream>>>(pS, pSS, meanp, rstdp);
  k_lnapply<<<SZ / 1024, 256, 0, stream>>>(P1, meanp, rstdp, P2);

  // g = conv(z,Wg1,bg1)*sigmoid(conv(z,Wg2,bg2))  (P2 -> P0)
  k_conv_glu<<<dim3(58, 4, BB), 256, 0, stream>>>(P2, WtA + 4 * 16384, WtA + 5 * 16384, bg1, bg2, P0);
  // t2 = (conv(g,Wg3,bg3) + z)*(w+1) + bias  (P0 -> P1, z from P2)
  k_conv<3><<<dim3(58, 2, BB), 256, 0, stream>>>(P0, WtA + 6 * 16384, bg3, P1, wgt, bia, P2);

  // out = ln12(t2)
  k_lnstat<<<dim3(LN_CH, BB), 192, 0, stream>>>(P1, pS, pSS);
  k_lnfin<<<1, 96, 0, stream>>>(pS, pSS, meanp, rstdp);
  k_lnapply<<<SZ / 1024, 256, 0, stream>>>(P1, meanp, rstdp, (float*)d_out);
}

// Round 4
// 511.235 us; speedup vs baseline: 1.2920x; 1.2920x over previous
//
#include <hip/hip_runtime.h>

namespace {

constexpr int NN   = 307;
constexpr int LNUM = 12;
constexpr int SP   = NN * LNUM;        // 3684
constexpr int DCH  = 128;
constexpr int HH   = 8;
constexpr int DK   = 16;
constexpr int BB   = 8;
constexpr int SZB  = DCH * SP;         // 471552 per batch
constexpr int SZ   = BB * SZB;         // 3772416 total
constexpr int ADJN = NN * NN;          // 94249
constexpr int DN   = DCH * NN;         // 39296 (layernorm group size)
constexpr int LN_CH = 48;
constexpr int LN_DNC = 819;            // ceil(39296/48)
constexpr int MST  = HH * LNUM * NN * DK;  // mem_bank per-slot stride = 471552

typedef __attribute__((ext_vector_type(8))) short short8_t;
typedef __attribute__((ext_vector_type(4))) float f32x4;
typedef __attribute__((ext_vector_type(4))) unsigned short ushort4_t;

__device__ inline unsigned short f2bf(float f) {
  unsigned int u = __builtin_bit_cast(unsigned int, f);
  unsigned int r = (u + 0x7FFFu + ((u >> 16) & 1u)) >> 16;
  return (unsigned short)r;
}

// sigma-permuted column position for m within the V / adjT buffers
__device__ __host__ inline int posm(int m) {
  int q = (m & 15) >> 2, sub = (m >> 4) & 1, i = m & 3;
  return (m & ~31) + 8 * q + 4 * sub + i;
}

// ---------------- small prep kernels ----------------

__global__ __launch_bounds__(256) void k_transW(
    const float* __restrict__ W0, const float* __restrict__ W1,
    const float* __restrict__ W2, const float* __restrict__ W3,
    const float* __restrict__ W4, const float* __restrict__ W5,
    const float* __restrict__ W6, float* __restrict__ Wt) {
  const float* srcs[7] = {W0, W1, W2, W3, W4, W5, W6};
  int w = blockIdx.y;
  int idx = blockIdx.x * 256 + threadIdx.x;   // 0..16383
  int o = idx >> 7, c = idx & 127;
  Wt[w * 16384 + c * 128 + o] = srcs[w][idx];
}

// s1 = softmax(relu(nv1 @ nv2), axis=-1). One block per row i.
__global__ __launch_bounds__(320) void k_s1(
    const float* __restrict__ nv1, const float* __restrict__ nv2,
    float* __restrict__ out) {
  __shared__ float red[512];
  __shared__ float rowA[10];
  const int i = blockIdx.x, j = threadIdx.x;
  if (j < 10) rowA[j] = nv1[i * 10 + j];
  __syncthreads();
  float val = 0.f;
  if (j < NN) {
#pragma unroll
    for (int k = 0; k < 10; ++k) val += rowA[k] * nv2[k * NN + j];
    val = fmaxf(val, 0.f);
  }
  red[j] = (j < NN) ? val : -3.4e38f;
  if (j < 192) red[j + 320] = -3.4e38f;
  __syncthreads();
  for (int s = 256; s >= 1; s >>= 1) {
    if (j < s) red[j] = fmaxf(red[j], red[j + s]);
    __syncthreads();
  }
  float mx = red[0];
  __syncthreads();
  float e = (j < NN) ? __expf(val - mx) : 0.f;
  red[j] = e;
  if (j < 192) red[j + 320] = 0.f;
  __syncthreads();
  for (int s = 256; s >= 1; s >>= 1) {
    if (j < s) red[j] += red[j + s];
    __syncthreads();
  }
  if (j < NN) out[i * NN + j] = e / red[0];
}

// out = softmax(Sa @ Sb, axis=-1). One block per row i.
__global__ __launch_bounds__(320) void k_smm(
    const float* __restrict__ Sa, const float* __restrict__ Sb,
    float* __restrict__ out) {
  __shared__ float red[512];
  __shared__ float rowA[320];
  const int i = blockIdx.x, j = threadIdx.x;
  if (j < NN) rowA[j] = Sa[i * NN + j];
  __syncthreads();
  float val = 0.f;
  if (j < NN) {
    for (int k = 0; k < NN; ++k) val += rowA[k] * Sb[k * NN + j];
  }
  red[j] = (j < NN) ? val : -3.4e38f;
  if (j < 192) red[j + 320] = -3.4e38f;
  __syncthreads();
  for (int s = 256; s >= 1; s >>= 1) {
    if (j < s) red[j] = fmaxf(red[j], red[j + s]);
    __syncthreads();
  }
  float mx = red[0];
  __syncthreads();
  float e = (j < NN) ? __expf(val - mx) : 0.f;
  red[j] = e;
  if (j < 192) red[j + 320] = 0.f;
  __syncthreads();
  for (int s = 256; s >= 1; s >>= 1) {
    if (j < s) red[j] += red[j + s];
    __syncthreads();
  }
  if (j < NN) out[i * NN + j] = e / red[0];
}

// adjTb[n][posm(m)] = bf16( sw0*s1[m][n] + sw1*s2[m][n] + sw2*s3[m][n] ), zero-padded to 320x320.
__global__ __launch_bounds__(256) void k_adjT(
    const float* __restrict__ s1, const float* __restrict__ s2,
    const float* __restrict__ s3, const float* __restrict__ sws,
    unsigned int* __restrict__ adjTw) {   // u32 view of adjTb
  int idx = blockIdx.x * 256 + threadIdx.x;   // 0 .. 320*160-1
  if (idx >= 320 * 160) return;
  int n = idx / 160, wp = idx - n * 160;
  int pos0 = 2 * wp;
  int bq = pos0 & 31;
  int g = bq >> 3, sub = (bq >> 2) & 1, i = bq & 3;
  int m0 = (pos0 & ~31) + sub * 16 + 4 * g + i;   // m1 = m0 + 1
  float w0 = sws[0], w1 = sws[1], w2 = sws[2];
  float mm = fmaxf(w0, fmaxf(w1, w2));
  float e0 = __expf(w0 - mm), e1 = __expf(w1 - mm), e2 = __expf(w2 - mm);
  float inv = 1.f / (e0 + e1 + e2);
  e0 *= inv; e1 *= inv; e2 *= inv;
  float v0 = 0.f, v1 = 0.f;
  if (n < NN) {
    if (m0 < NN)     v0 = e0 * s1[m0 * NN + n] + e1 * s2[m0 * NN + n] + e2 * s3[m0 * NN + n];
    if (m0 + 1 < NN) v1 = e0 * s1[(m0 + 1) * NN + n] + e1 * s2[(m0 + 1) * NN + n] + e2 * s3[(m0 + 1) * NN + n];
  }
  adjTw[n * 160 + wp] = (unsigned int)f2bf(v0) | ((unsigned int)f2bf(v1) << 16);
}

// mem_w[b][0..3]
__global__ __launch_bounds__(128) void k_memw(
    const float* __restrict__ x, const float* __restrict__ A1,
    const float* __restrict__ a1b, const float* __restrict__ A2,
    const float* __restrict__ a2b, const float* __restrict__ mimp,
    float* __restrict__ memw) {
  const int b = blockIdx.x, t = threadIdx.x;
  __shared__ float avg[128];
  __shared__ float hbuf[64];
  __shared__ float lg[4];
  float s = 0.f;
  const float* xp = x + (size_t)(b * DCH + t) * SP;
  for (int i = 0; i < SP; ++i) s += xp[i];
  avg[t] = s * (1.f / SP);
  __syncthreads();
  if (t < 64) {
    float a = a1b[t];
    for (int d = 0; d < 128; ++d) a += avg[d] * A1[d * 64 + t];
    hbuf[t] = fmaxf(a, 0.f);
  }
  __syncthreads();
  if (t < 4) {
    float a = a2b[t];
    for (int j = 0; j < 64; ++j) a += hbuf[j] * A2[j * 4 + t];
    lg[t] = a;
  }
  __syncthreads();
  if (t == 0) {
    float mx = fmaxf(fmaxf(lg[0], lg[1]), fmaxf(lg[2], lg[3]));
    float e[4]; float se = 0.f;
    for (int m = 0; m < 4; ++m) { e[m] = __expf(lg[m] - mx); se += e[m]; }
    float w[4]; float mx2 = -3.4e38f;
    for (int m = 0; m < 4; ++m) { w[m] = mimp[m] * (e[m] / se); mx2 = fmaxf(mx2, w[m]); }
    float se2 = 0.f;
    for (int m = 0; m < 4; ++m) { e[m] = __expf(w[m] - mx2); se2 += e[m]; }
    for (int m = 0; m < 4; ++m) memw[b * 4 + m] = e[m] / se2;
  }
}

// ---------------- 1x1 conv (GEMM) ----------------
// MODE 0: in standard; out = relu(acc+b) -> q5b bf16, layout [slice][n(320 rows, 307 written)][16]
// MODE 4: in standard; out = relu(acc+b) -> vt5b bf16, layout [slice][16][posm(n) of 320]
// MODE 1: in y5 fp32 [slice][n][16]; out standard = acc + b + input(residual)
// MODE 2: in standard; out = relu(acc+b)*(aw+1) + ab + ax
// MODE 3: in standard; out = (acc + b + ax)*(aw+1) + ab
template <int MODE>
__global__ __launch_bounds__(256) void k_conv(
    const float* __restrict__ X, const float* __restrict__ Wt,
    const float* __restrict__ bvec, void* __restrict__ outv,
    const float* __restrict__ aw, const float* __restrict__ ab,
    const float* __restrict__ ax) {
  __shared__ float Xs[128][64];
  __shared__ float Ws[128][64];
  const int sBase = blockIdx.x * 64;
  const int oBase = blockIdx.y * 64;
  const int b = blockIdx.z;
  const int t = threadIdx.x;
#pragma unroll
  for (int i = 0; i < 32; ++i) {
    int idx = t + i * 256;
    int c = idx >> 6, u = idx & 63;
    Ws[c][u] = Wt[c * 128 + oBase + u];
    int s = sBase + u;
    float v = 0.f;
    if (s < SP) {
      if constexpr (MODE == 1) {
        int n = s / 12, l2 = s - n * 12;
        int hh = c >> 4, kk = c & 15;
        v = X[(((b * HH + hh) * LNUM + l2) * NN + n) * DK + kk];
      } else {
        v = X[(size_t)(b * DCH + c) * SP + s];
      }
    }
    Xs[c][u] = v;
  }
  __syncthreads();
  const int tx = t & 15, ty = t >> 4;
  float acc[4][4] = {};
#pragma unroll 4
  for (int c = 0; c < 128; ++c) {
    float4 xv = *(const float4*)&Xs[c][tx * 4];
    float4 wv = *(const float4*)&Ws[c][ty * 4];
    acc[0][0] += wv.x * xv.x; acc[0][1] += wv.x * xv.y; acc[0][2] += wv.x * xv.z; acc[0][3] += wv.x * xv.w;
    acc[1][0] += wv.y * xv.x; acc[1][1] += wv.y * xv.y; acc[1][2] += wv.y * xv.z; acc[1][3] += wv.y * xv.w;
    acc[2][0] += wv.z * xv.x; acc[2][1] += wv.z * xv.y; acc[2][2] += wv.z * xv.z; acc[2][3] += wv.z * xv.w;
    acc[3][0] += wv.w * xv.x; acc[3][1] += wv.w * xv.y; acc[3][2] += wv.w * xv.z; acc[3][3] += wv.w * xv.w;
  }
  const int s0 = sBase + tx * 4;
  const int o0 = oBase + ty * 4;

  if constexpr (MODE == 0) {
    // q5b bf16: [(slice*320 + n)*16 + k]
    if (s0 < SP) {
      unsigned short* qb = (unsigned short*)outv;
      const int hh = o0 >> 4, k0 = o0 & 15;
      float b0 = bvec[o0], b1 = bvec[o0 + 1], b2 = bvec[o0 + 2], b3 = bvec[o0 + 3];
      const int n = s0 / 12, l0 = s0 - n * 12;
#pragma unroll
      for (int si = 0; si < 4; ++si) {
        int sl = (b * HH + hh) * LNUM + (l0 + si);
        ushort4_t q4;
        q4.x = f2bf(fmaxf(acc[0][si] + b0, 0.f));
        q4.y = f2bf(fmaxf(acc[1][si] + b1, 0.f));
        q4.z = f2bf(fmaxf(acc[2][si] + b2, 0.f));
        q4.w = f2bf(fmaxf(acc[3][si] + b3, 0.f));
        *(ushort4_t*)(qb + (sl * 320 + n) * 16 + k0) = q4;
      }
    }
  } else if constexpr (MODE == 4) {
    // vt5b bf16: [(slice*16 + k)*320 + posm(n)]
    if (s0 < SP) {
      unsigned short* vb = (unsigned short*)outv;
      const int hh = o0 >> 4, k0 = o0 & 15;
      float bb[4] = {bvec[o0], bvec[o0 + 1], bvec[o0 + 2], bvec[o0 + 3]};
      const int n = s0 / 12, l0 = s0 - n * 12;
      const int pn = posm(n);
#pragma unroll
      for (int si = 0; si < 4; ++si) {
        int sl = (b * HH + hh) * LNUM + (l0 + si);
#pragma unroll
        for (int oi = 0; oi < 4; ++oi) {
          vb[(sl * 16 + k0 + oi) * 320 + pn] = f2bf(fmaxf(acc[oi][si] + bb[oi], 0.f));
        }
      }
    }
  } else if constexpr (MODE == 1) {
    if (s0 < SP) {
      float* out = (float*)outv;
#pragma unroll
      for (int oi = 0; oi < 4; ++oi) {
        int o = o0 + oi;
        float bb = bvec[o];
        float4 val;
        val.x = acc[oi][0] + bb + Xs[o][tx * 4 + 0];
        val.y = acc[oi][1] + bb + Xs[o][tx * 4 + 1];
        val.z = acc[oi][2] + bb + Xs[o][tx * 4 + 2];
        val.w = acc[oi][3] + bb + Xs[o][tx * 4 + 3];
        *(float4*)(out + (size_t)(b * DCH + o) * SP + s0) = val;
      }
    }
  } else if constexpr (MODE == 2) {
    if (s0 < SP) {
      float* out = (float*)outv;
#pragma unroll
      for (int oi = 0; oi < 4; ++oi) {
        int o = o0 + oi;
        float bb = bvec[o];
        float4 w  = *(const float4*)(aw + o * SP + s0);
        float4 bi = *(const float4*)(ab + o * SP + s0);
        float4 xv = *(const float4*)(ax + (size_t)(b * DCH + o) * SP + s0);
        float4 val;
        float r;
        r = fmaxf(acc[oi][0] + bb, 0.f); val.x = r * (w.x + 1.f) + bi.x + xv.x;
        r = fmaxf(acc[oi][1] + bb, 0.f); val.y = r * (w.y + 1.f) + bi.y + xv.y;
        r = fmaxf(acc[oi][2] + bb, 0.f); val.z = r * (w.z + 1.f) + bi.z + xv.z;
        r = fmaxf(acc[oi][3] + bb, 0.f); val.w = r * (w.w + 1.f) + bi.w + xv.w;
        *(float4*)(out + (size_t)(b * DCH + o) * SP + s0) = val;
      }
    }
  } else {  // MODE 3
    if (s0 < SP) {
      float* out = (float*)outv;
#pragma unroll
      for (int oi = 0; oi < 4; ++oi) {
        int o = o0 + oi;
        float bb = bvec[o];
        float4 w  = *(const float4*)(aw + o * SP + s0);
        float4 bi = *(const float4*)(ab + o * SP + s0);
        float4 zv = *(const float4*)(ax + (size_t)(b * DCH + o) * SP + s0);
        float4 val;
        float tt;
        tt = acc[oi][0] + bb + zv.x; val.x = tt * (w.x + 1.f) + bi.x;
        tt = acc[oi][1] + bb + zv.y; val.y = tt * (w.y + 1.f) + bi.y;
        tt = acc[oi][2] + bb + zv.z; val.z = tt * (w.z + 1.f) + bi.z;
        tt = acc[oi][3] + bb + zv.w; val.w = tt * (w.w + 1.f) + bi.w;
        *(float4*)(out + (size_t)(b * DCH + o) * SP + s0) = val;
      }
    }
  }
}

// GLU conv
__global__ __launch_bounds__(256) void k_conv_glu(
    const float* __restrict__ X, const float* __restrict__ Wt1,
    const float* __restrict__ Wt2, const float* __restrict__ b1,
    const float* __restrict__ b2, float* __restrict__ out) {
  __shared__ float Xs[128][64];
  __shared__ float W1s[128][32];
  __shared__ float W2s[128][32];
  const int sBase = blockIdx.x * 64;
  const int oBase = blockIdx.y * 32;
  const int b = blockIdx.z;
  const int t = threadIdx.x;
#pragma unroll
  for (int i = 0; i < 32; ++i) {
    int idx = t + i * 256;
    int c = idx >> 6, u = idx & 63;
    int s = sBase + u;
    Xs[c][u] = (s < SP) ? X[(size_t)(b * DCH + c) * SP + s] : 0.f;
  }
#pragma unroll
  for (int i = 0; i < 16; ++i) {
    int idx = t + i * 256;
    int c = idx >> 5, o = idx & 31;
    W1s[c][o] = Wt1[c * 128 + oBase + o];
    W2s[c][o] = Wt2[c * 128 + oBase + o];
  }
  __syncthreads();
  const int tx = t & 15, ty = t >> 4;
  float a1[2][4] = {};
  float a2[2][4] = {};
#pragma unroll 4
  for (int c = 0; c < 128; ++c) {
    float4 xv = *(const float4*)&Xs[c][tx * 4];
    float2 w1 = *(const float2*)&W1s[c][ty * 2];
    float2 w2 = *(const float2*)&W2s[c][ty * 2];
    a1[0][0] += w1.x * xv.x; a1[0][1] += w1.x * xv.y; a1[0][2] += w1.x * xv.z; a1[0][3] += w1.x * xv.w;
    a1[1][0] += w1.y * xv.x; a1[1][1] += w1.y * xv.y; a1[1][2] += w1.y * xv.z; a1[1][3] += w1.y * xv.w;
    a2[0][0] += w2.x * xv.x; a2[0][1] += w2.x * xv.y; a2[0][2] += w2.x * xv.z; a2[0][3] += w2.x * xv.w;
    a2[1][0] += w2.y * xv.x; a2[1][1] += w2.y * xv.y; a2[1][2] += w2.y * xv.z; a2[1][3] += w2.y * xv.w;
  }
  const int s0 = sBase + tx * 4;
  if (s0 < SP) {
#pragma unroll
    for (int oi = 0; oi < 2; ++oi) {
      int o = oBase + ty * 2 + oi;
      float bb1 = b1[o], bb2 = b2[o];
      float4 val;
      float v1, v2;
      v1 = a1[oi][0] + bb1; v2 = a2[oi][0] + bb2; val.x = v1 / (1.f + __expf(-v2));
      v1 = a1[oi][1] + bb1; v2 = a2[oi][1] + bb2; val.y = v1 / (1.f + __expf(-v2));
      v1 = a1[oi][2] + bb1; v2 = a2[oi][2] + bb2; val.z = v1 / (1.f + __expf(-v2));
      v1 = a1[oi][3] + bb1; v2 = a2[oi][3] + bb2; val.w = v1 / (1.f + __expf(-v2));
      *(float4*)(out + (size_t)(b * DCH + o) * SP + s0) = val;
    }
  }
}

// ---------------- MFMA attention + graph diffusion ----------------
// grid (LNUM, HH, BB), 256 threads (4 waves x 5 row-tiles of 16 rows).
__global__ __launch_bounds__(256) void k_attn_mfma(
    const unsigned short* __restrict__ q5b, const unsigned short* __restrict__ vt5b,
    const float* __restrict__ memb, const float* __restrict__ memw,
    const unsigned short* __restrict__ adjTb, float* __restrict__ y5) {
  __shared__ unsigned short Mb[320 * 24];   // combined memory, bf16, row stride 24
  __shared__ unsigned short Vt[16 * 328];   // V^T sigma-permuted, bf16, row stride 328
  const int l = blockIdx.x, h = blockIdx.y, b = blockIdx.z;
  const int t = threadIdx.x;
  const int slice = (b * HH + h) * LNUM + l;
  const int msl = (h * LNUM + l) * NN * DK;
  const float w0 = memw[b * 4 + 0], w1 = memw[b * 4 + 1];
  const float w2 = memw[b * 4 + 2], w3 = memw[b * 4 + 3];

  // stage combined memory -> Mb (bf16), rows >=307 zeroed
  for (int idx = t; idx < 640; idx += 256) {
    int n = idx >> 1, h8 = idx & 1;
    float v[8];
    if (n < NN) {
      int off = msl + n * 16 + h8 * 8;
      const float4* p0 = (const float4*)(memb + off);
      const float4* p1 = (const float4*)(memb + MST + off);
      const float4* p2 = (const float4*)(memb + 2 * MST + off);
      const float4* p3 = (const float4*)(memb + 3 * MST + off);
      float4 a0 = p0[0], a1 = p1[0], a2 = p2[0], a3 = p3[0];
      float4 c0 = p0[1], c1 = p1[1], c2 = p2[1], c3 = p3[1];
      v[0] = w0 * a0.x + w1 * a1.x + w2 * a2.x + w3 * a3.x;
      v[1] = w0 * a0.y + w1 * a1.y + w2 * a2.y + w3 * a3.y;
      v[2] = w0 * a0.z + w1 * a1.z + w2 * a2.z + w3 * a3.z;
      v[3] = w0 * a0.w + w1 * a1.w + w2 * a2.w + w3 * a3.w;
      v[4] = w0 * c0.x + w1 * c1.x + w2 * c2.x + w3 * c3.x;
      v[5] = w0 * c0.y + w1 * c1.y + w2 * c2.y + w3 * c3.y;
      v[6] = w0 * c0.z + w1 * c1.z + w2 * c2.z + w3 * c3.z;
      v[7] = w0 * c0.w + w1 * c1.w + w2 * c2.w + w3 * c3.w;
    } else {
#pragma unroll
      for (int j = 0; j < 8; ++j) v[j] = 0.f;
    }
    union { unsigned int w[4]; short8_t s; } u;
#pragma unroll
    for (int j = 0; j < 4; ++j)
      u.w[j] = (unsigned int)f2bf(v[2 * j]) | ((unsigned int)f2bf(v[2 * j + 1]) << 16);
    *(short8_t*)(Mb + n * 24 + h8 * 8) = u.s;
  }
  // stage Vt (copy global -> LDS with stride change 320 -> 328)
  {
    const unsigned short* vsl = vt5b + slice * (16 * 320);
    for (int c = t; c < 640; c += 256) {
      int row = c / 40, ch = c - row * 40;
      short8_t vv = *(const short8_t*)(vsl + row * 320 + ch * 8);
      *(short8_t*)(Vt + row * 328 + ch * 8) = vv;
    }
  }
  __syncthreads();
  // Zero the sigma-columns of Vt that k_conv<4> never writes (n = 307..319).
  // Without this, stale workspace bits (NaN/Inf bf16 patterns on graph replays)
  // reach the PV MFMA and 0*NaN = NaN contaminates the whole D tile.
  for (int idx = t; idx < 16 * 13; idx += 256) {
    int row = idx / 13, j = idx - row * 13;
    Vt[row * 328 + posm(NN + j)] = 0;
  }
  __syncthreads();

  const int wave = t >> 6, lane = t & 63;
  const int r = lane & 15, g = lane >> 4;
  const f32x4 zf = {0.f, 0.f, 0.f, 0.f};
  float maskv[4];
#pragma unroll
  for (int i = 0; i < 4; ++i) maskv[i] = (4 * g + i < 3) ? 1.f : 0.f;
  constexpr float CEXP = 0.25f * 1.44269504089f;

  const int ysl = slice * (NN * DK);
  for (int rt5 = 0; rt5 < 5; ++rt5) {
    const int n0 = (wave * 5 + rt5) * 16;
    short8_t bq = {0, 0, 0, 0, 0, 0, 0, 0};
    // guard n0+r < NN: rows 307..319 of q5b are never written by k_conv<0>
    if (g < 2 && n0 + r < NN) bq = *(const short8_t*)(q5b + (slice * 320 + n0 + r) * 16 + 8 * g);
    f32x4 accPV = zf, accG = zf;
    float dn = 0.f;
#pragma unroll 2
    for (int mt = 0; mt < 10; ++mt) {
      const int mb = mt * 32;
      short8_t am0 = {0, 0, 0, 0, 0, 0, 0, 0}, am1 = am0;
      if (g < 2) {
        am0 = *(const short8_t*)(Mb + (mb + r) * 24 + 8 * g);
        am1 = *(const short8_t*)(Mb + (mb + 16 + r) * 24 + 8 * g);
      }
      f32x4 s0 = __builtin_amdgcn_mfma_f32_16x16x32_bf16(am0, bq, zf, 0, 0, 0);
      f32x4 s1 = __builtin_amdgcn_mfma_f32_16x16x32_bf16(am1, bq, zf, 0, 0, 0);
      float p0[4], p1[4];
#pragma unroll
      for (int i = 0; i < 4; ++i) {
        p0[i] = __builtin_amdgcn_exp2f(s0[i] * CEXP);
        p1[i] = __builtin_amdgcn_exp2f(s1[i] * CEXP);
      }
      if (mt == 9) {
#pragma unroll
        for (int i = 0; i < 4; ++i) p1[i] *= maskv[i];
      }
      dn += p0[0] + p0[1] + p0[2] + p0[3] + p1[0] + p1[1] + p1[2] + p1[3];
      union { unsigned int w[4]; short8_t s; } up;
      asm("v_cvt_pk_bf16_f32 %0, %1, %2" : "=v"(up.w[0]) : "v"(p0[0]), "v"(p0[1]));
      asm("v_cvt_pk_bf16_f32 %0, %1, %2" : "=v"(up.w[1]) : "v"(p0[2]), "v"(p0[3]));
      asm("v_cvt_pk_bf16_f32 %0, %1, %2" : "=v"(up.w[2]) : "v"(p1[0]), "v"(p1[1]));
      asm("v_cvt_pk_bf16_f32 %0, %1, %2" : "=v"(up.w[3]) : "v"(p1[2]), "v"(p1[3]));
      short8_t bv = *(const short8_t*)(Vt + r * 328 + mb + 8 * g);
      accPV = __builtin_amdgcn_mfma_f32_16x16x32_bf16(up.s, bv, accPV, 0, 0, 0);
      short8_t aj = *(const short8_t*)(adjTb + (n0 + r) * 320 + mb + 8 * g);
      accG = __builtin_amdgcn_mfma_f32_16x16x32_bf16(aj, bv, accG, 0, 0, 0);
    }
    dn += __shfl_xor(dn, 16);
    dn += __shfl_xor(dn, 32);
#pragma unroll
    for (int i = 0; i < 4; ++i) {
      int n = n0 + 4 * g + i;
      float di = __shfl(dn, 4 * g + i);
      if (n < NN) y5[ysl + n * 16 + r] = accPV[i] / di + accG[i];
    }
  }
}

// ---------------- layernorm over (D,N) per (b,l), 3-kernel split ----------------

__global__ __launch_bounds__(192) void k_lnstat(
    const float* __restrict__ in, float* __restrict__ pS, float* __restrict__ pSS) {
  const int c = blockIdx.x, b = blockIdx.y, t = threadIdx.x;
  const int dn0 = c * LN_DNC;
  const int dn1 = min(dn0 + LN_DNC, DN);
  const int cnt = (dn1 - dn0) * LNUM;
  const float* p = in + (size_t)b * SZB + (size_t)dn0 * LNUM;
  float s = 0.f, ss = 0.f;
  for (int i = t; i < cnt; i += 192) {
    float v = p[i];
    s += v; ss += v * v;
  }
  __shared__ float rs[192], rss[192];
  rs[t] = s; rss[t] = ss;
  __syncthreads();
  if (t < 12) {
    float S = 0.f, SS = 0.f;
    for (int j = t; j < 192; j += 12) { S += rs[j]; SS += rss[j]; }
    pS[(b * LN_CH + c) * 12 + t] = S;
    pSS[(b * LN_CH + c) * 12 + t] = SS;
  }
}

__global__ __launch_bounds__(96) void k_lnfin(
    const float* __restrict__ pS, const float* __restrict__ pSS,
    float* __restrict__ meanp, float* __restrict__ rstdp) {
  const int t = threadIdx.x;
  const int b = t / 12, l = t % 12;
  float S = 0.f, SS = 0.f;
  for (int c = 0; c < LN_CH; ++c) {
    S += pS[(b * LN_CH + c) * 12 + l];
    SS += pSS[(b * LN_CH + c) * 12 + l];
  }
  float mu = S * (1.f / DN);
  float var = SS * (1.f / DN) - mu * mu;
  meanp[t] = mu;
  rstdp[t] = rsqrtf(fmaxf(var, 0.f) + 1e-5f);
}

__global__ __launch_bounds__(256) void k_lnapply(
    const float* __restrict__ in, const float* __restrict__ meanp,
    const float* __restrict__ rstdp, float* __restrict__ outp) {
  const int i0 = (blockIdx.x * 256 + threadIdx.x) * 4;
  float4 v = *(const float4*)(in + i0);
  const int b = (int)((unsigned)i0 / (unsigned)SZB);
  const int rr = i0 - b * SZB;
  const int l0 = rr % 12;
  const float* mp = meanp + b * 12;
  const float* rp = rstdp + b * 12;
  float4 o;
  o.x = (v.x - mp[l0 + 0]) * rp[l0 + 0];
  o.y = (v.y - mp[l0 + 1]) * rp[l0 + 1];
  o.z = (v.z - mp[l0 + 2]) * rp[l0 + 2];
  o.w = (v.w - mp[l0 + 3]) * rp[l0 + 3];
  *(float4*)(outp + i0) = o;
}

}  // namespace

extern "C" void kernel_launch(void* const* d_in, const int* in_sizes, int n_in,
                              void* d_out, int out_size, void* d_ws, size_t ws_size,
                              hipStream_t stream) {
  (void)in_sizes; (void)n_in; (void)out_size; (void)ws_size;
  const float* x    = (const float*)d_in[0];
  const float* Wq   = (const float*)d_in[1];
  const float* bq   = (const float*)d_in[2];
  const float* Wv   = (const float*)d_in[3];
  const float* bv   = (const float*)d_in[4];
  const float* Wc   = (const float*)d_in[5];
  const float* bc   = (const float*)d_in[6];
  const float* Wx   = (const float*)d_in[7];
  const float* bx   = (const float*)d_in[8];
  const float* Wg1  = (const float*)d_in[9];
  const float* bg1  = (const float*)d_in[10];
  const float* Wg2  = (const float*)d_in[11];
  const float* bg2  = (const float*)d_in[12];
  const float* Wg3  = (const float*)d_in[13];
  const float* bg3  = (const float*)d_in[14];
  const float* memb = (const float*)d_in[15];
  const float* mimp = (const float*)d_in[16];
  const float* A1   = (const float*)d_in[17];
  const float* a1b  = (const float*)d_in[18];
  const float* A2   = (const float*)d_in[19];
  const float* a2b  = (const float*)d_in[20];
  const float* wgt  = (const float*)d_in[21];
  const float* bia  = (const float*)d_in[22];
  const float* nv1  = (const float*)d_in[23];
  const float* nv2  = (const float*)d_in[24];
  const float* sws  = (const float*)d_in[25];

  float* ws = (float*)d_ws;
  float* P0 = ws;                        // also hosts q5b (bf16) before MODE1
  float* P1 = ws + (size_t)SZ;           // also hosts vt5b (bf16) before MODE2
  float* P2 = ws + 2 * (size_t)SZ;       // y5 fp32
  float* sm = ws + 3 * (size_t)SZ;
  float* s1 = sm;
  float* s2 = sm + ADJN;
  float* s3 = sm + 2 * ADJN;
  float* adjT_f = sm + 3 * ADJN;            // 51200 floats = 320*320 bf16
  float* memw = adjT_f + 51200;
  float* WtA  = memw + 32;                  // 7*16384
  float* pS   = WtA + 7 * 16384;
  float* pSS  = pS + BB * LN_CH * 12;
  float* meanp = pSS + BB * LN_CH * 12;
  float* rstdp = meanp + 96;

  unsigned short* q5b  = (unsigned short*)P0;
  unsigned short* vt5b = (unsigned short*)P1;
  unsigned short* adjTb = (unsigned short*)adjT_f;

  k_transW<<<dim3(64, 7), 256, 0, stream>>>(Wq, Wv, Wx, Wc, Wg1, Wg2, Wg3, WtA);
  k_s1<<<NN, 320, 0, stream>>>(nv1, nv2, s1);
  k_smm<<<NN, 320, 0, stream>>>(s1, s1, s2);
  k_smm<<<NN, 320, 0, stream>>>(s2, s1, s3);
  k_adjT<<<(320 * 160 + 255) / 256, 256, 0, stream>>>(s1, s2, s3, sws, (unsigned int*)adjTb);
  k_memw<<<BB, 128, 0, stream>>>(x, A1, a1b, A2, a2b, mimp, memw);

  // q5b, vt5b projections (bf16, MFMA-friendly layouts)
  k_conv<0><<<dim3(58, 2, BB), 256, 0, stream>>>(x, WtA + 0 * 16384, bq, q5b, nullptr, nullptr, nullptr);
  k_conv<4><<<dim3(58, 2, BB), 256, 0, stream>>>(x, WtA + 1 * 16384, bv, vt5b, nullptr, nullptr, nullptr);

  // MFMA attention + graph -> y5 (P2)
  k_attn_mfma<<<dim3(LNUM, HH, BB), 256, 0, stream>>>(q5b, vt5b, memb, memw, adjTb, P2);

  // t = y + conv(y, Wx, bx): y5 input, standard output (P0; q5b dead)
  k_conv<1><<<dim3(58, 2, BB), 256, 0, stream>>>(P2, WtA + 2 * 16384, bx, P0, nullptr, nullptr, nullptr);
  // z_in = relu(conv(t, Wc, bc))*(w+1) + bias + x  (P1; vt5b dead)
  k_conv<2><<<dim3(58, 2, BB), 256, 0, stream>>>(P0, WtA + 3 * 16384, bc, P1, wgt, bia, x);

  // z = ln12(z_in)  (P1 -> P2)
  k_lnstat<<<dim3(LN_CH, BB), 192, 0, stream>>>(P1, pS, pSS);
  k_lnfin<<<1, 96, 0, stream>>>(pS, pSS, meanp, rstdp);
  k_lnapply<<<SZ / 1024, 256, 0, stream>>>(P1, meanp, rstdp, P2);

  // g = conv(z,Wg1,bg1)*sigmoid(conv(z,Wg2,bg2))  (P2 -> P0)
  k_conv_glu<<<dim3(58, 4, BB), 256, 0, stream>>>(P2, WtA + 4 * 16384, WtA + 5 * 16384, bg1, bg2, P0);
  // t2 = (conv(g,Wg3,bg3) + z)*(w+1) + bias  (P0 -> P1, z from P2)
  k_conv<3><<<dim3(58, 2, BB), 256, 0, stream>>>(P0, WtA + 6 * 16384, bg3, P1, wgt, bia, P2);

  // out = ln12(t2)
  k_lnstat<<<dim3(LN_CH, BB), 192, 0, stream>>>(P1, pS, pSS);
  k_lnfin<<<1, 96, 0, stream>>>(pS, pSS, meanp, rstdp);
  k_lnapply<<<SZ / 1024, 256, 0, stream>>>(P1, meanp, rstdp, (float*)d_out);
}

// Round 5
// 408.150 us; speedup vs baseline: 1.6183x; 1.2526x over previous
//
#include <hip/hip_runtime.h>

namespace {

constexpr int NN   = 307;
constexpr int LNUM = 12;
constexpr int SP   = NN * LNUM;        // 3684
constexpr int DCH  = 128;
constexpr int HH   = 8;
constexpr int DK   = 16;
constexpr int BB   = 8;
constexpr int SZB  = DCH * SP;         // 471552 per batch
constexpr int SZ   = BB * SZB;         // 3772416 total
constexpr int ADJN = NN * NN;          // 94249
constexpr int DN   = DCH * NN;         // 39296 (layernorm group size)
constexpr int LN_CH = 48;
constexpr int LN_DNC = 819;            // ceil(39296/48)
constexpr int MST  = HH * LNUM * NN * DK;  // mem_bank per-slot stride = 471552

typedef __attribute__((ext_vector_type(8))) short short8_t;
typedef __attribute__((ext_vector_type(4))) float f32x4;
typedef __attribute__((ext_vector_type(4))) unsigned short ushort4_t;

__device__ inline unsigned short f2bf(float f) {
  unsigned int u = __builtin_bit_cast(unsigned int, f);
  unsigned int r = (u + 0x7FFFu + ((u >> 16) & 1u)) >> 16;
  return (unsigned short)r;
}

// sigma-permuted column position for m within the V / adjT buffers
__device__ __host__ inline int posm(int m) {
  int q = (m & 15) >> 2, sub = (m >> 4) & 1, i = m & 3;
  return (m & ~31) + 8 * q + 4 * sub + i;
}

// ---------------- small prep kernels ----------------

__global__ __launch_bounds__(256) void k_transW(
    const float* __restrict__ W0, const float* __restrict__ W1,
    const float* __restrict__ W2, const float* __restrict__ W3,
    const float* __restrict__ W4, const float* __restrict__ W5,
    const float* __restrict__ W6, float* __restrict__ Wt) {
  const float* srcs[7] = {W0, W1, W2, W3, W4, W5, W6};
  int w = blockIdx.y;
  int idx = blockIdx.x * 256 + threadIdx.x;   // 0..16383
  int o = idx >> 7, c = idx & 127;
  Wt[w * 16384 + c * 128 + o] = srcs[w][idx];
}

// s1 = softmax(relu(nv1 @ nv2), axis=-1). One block per row i.
__global__ __launch_bounds__(320) void k_s1(
    const float* __restrict__ nv1, const float* __restrict__ nv2,
    float* __restrict__ out) {
  __shared__ float red[512];
  __shared__ float rowA[10];
  const int i = blockIdx.x, j = threadIdx.x;
  if (j < 10) rowA[j] = nv1[i * 10 + j];
  __syncthreads();
  float val = 0.f;
  if (j < NN) {
#pragma unroll
    for (int k = 0; k < 10; ++k) val += rowA[k] * nv2[k * NN + j];
    val = fmaxf(val, 0.f);
  }
  red[j] = (j < NN) ? val : -3.4e38f;
  if (j < 192) red[j + 320] = -3.4e38f;
  __syncthreads();
  for (int s = 256; s >= 1; s >>= 1) {
    if (j < s) red[j] = fmaxf(red[j], red[j + s]);
    __syncthreads();
  }
  float mx = red[0];
  __syncthreads();
  float e = (j < NN) ? __expf(val - mx) : 0.f;
  red[j] = e;
  if (j < 192) red[j + 320] = 0.f;
  __syncthreads();
  for (int s = 256; s >= 1; s >>= 1) {
    if (j < s) red[j] += red[j + s];
    __syncthreads();
  }
  if (j < NN) out[i * NN + j] = e / red[0];
}

// out = softmax(Sa @ Sb, axis=-1). One block per row i.
__global__ __launch_bounds__(320) void k_smm(
    const float* __restrict__ Sa, const float* __restrict__ Sb,
    float* __restrict__ out) {
  __shared__ float red[512];
  __shared__ float rowA[320];
  const int i = blockIdx.x, j = threadIdx.x;
  if (j < NN) rowA[j] = Sa[i * NN + j];
  __syncthreads();
  float val = 0.f;
  if (j < NN) {
    for (int k = 0; k < NN; ++k) val += rowA[k] * Sb[k * NN + j];
  }
  red[j] = (j < NN) ? val : -3.4e38f;
  if (j < 192) red[j + 320] = -3.4e38f;
  __syncthreads();
  for (int s = 256; s >= 1; s >>= 1) {
    if (j < s) red[j] = fmaxf(red[j], red[j + s]);
    __syncthreads();
  }
  float mx = red[0];
  __syncthreads();
  float e = (j < NN) ? __expf(val - mx) : 0.f;
  red[j] = e;
  if (j < 192) red[j + 320] = 0.f;
  __syncthreads();
  for (int s = 256; s >= 1; s >>= 1) {
    if (j < s) red[j] += red[j + s];
    __syncthreads();
  }
  if (j < NN) out[i * NN + j] = e / red[0];
}

// adjTb[n][posm(m)] = bf16( sw0*s1[m][n] + sw1*s2[m][n] + sw2*s3[m][n] ), zero-padded to 320x320.
__global__ __launch_bounds__(256) void k_adjT(
    const float* __restrict__ s1, const float* __restrict__ s2,
    const float* __restrict__ s3, const float* __restrict__ sws,
    unsigned int* __restrict__ adjTw) {   // u32 view of adjTb
  int idx = blockIdx.x * 256 + threadIdx.x;   // 0 .. 320*160-1
  if (idx >= 320 * 160) return;
  int n = idx / 160, wp = idx - n * 160;
  int pos0 = 2 * wp;
  int bq = pos0 & 31;
  int g = bq >> 3, sub = (bq >> 2) & 1, i = bq & 3;
  int m0 = (pos0 & ~31) + sub * 16 + 4 * g + i;   // m1 = m0 + 1
  float w0 = sws[0], w1 = sws[1], w2 = sws[2];
  float mm = fmaxf(w0, fmaxf(w1, w2));
  float e0 = __expf(w0 - mm), e1 = __expf(w1 - mm), e2 = __expf(w2 - mm);
  float inv = 1.f / (e0 + e1 + e2);
  e0 *= inv; e1 *= inv; e2 *= inv;
  float v0 = 0.f, v1 = 0.f;
  if (n < NN) {
    if (m0 < NN)     v0 = e0 * s1[m0 * NN + n] + e1 * s2[m0 * NN + n] + e2 * s3[m0 * NN + n];
    if (m0 + 1 < NN) v1 = e0 * s1[(m0 + 1) * NN + n] + e1 * s2[(m0 + 1) * NN + n] + e2 * s3[(m0 + 1) * NN + n];
  }
  adjTw[n * 160 + wp] = (unsigned int)f2bf(v0) | ((unsigned int)f2bf(v1) << 16);
}

// avg[b*128+d] = mean over SP of x[b][d][:]. One wave per row, coalesced float4.
__global__ __launch_bounds__(256) void k_avg(
    const float* __restrict__ x, float* __restrict__ avg) {
  const int row = blockIdx.x * 4 + (threadIdx.x >> 6);   // 0..1023 = b*128+d
  const int lane = threadIdx.x & 63;
  const float* p = x + (size_t)row * SP;
  float s = 0.f;
  for (int i = lane; i < SP / 4; i += 64) {    // SP/4 = 921 float4s
    float4 v = *(const float4*)(p + i * 4);
    s += v.x + v.y + v.z + v.w;
  }
  s += __shfl_xor(s, 1);  s += __shfl_xor(s, 2);  s += __shfl_xor(s, 4);
  s += __shfl_xor(s, 8);  s += __shfl_xor(s, 16); s += __shfl_xor(s, 32);
  if (lane == 0) avg[row] = s * (1.f / SP);
}

// mem_w[b][0..3] from precomputed avg. One (tiny) block per b.
__global__ __launch_bounds__(128) void k_memw2(
    const float* __restrict__ avgg, const float* __restrict__ A1,
    const float* __restrict__ a1b, const float* __restrict__ A2,
    const float* __restrict__ a2b, const float* __restrict__ mimp,
    float* __restrict__ memw) {
  const int b = blockIdx.x, t = threadIdx.x;
  __shared__ float avg[128];
  __shared__ float hbuf[64];
  __shared__ float lg[4];
  avg[t] = avgg[b * 128 + t];
  __syncthreads();
  if (t < 64) {
    float a = a1b[t];
    for (int d = 0; d < 128; ++d) a += avg[d] * A1[d * 64 + t];
    hbuf[t] = fmaxf(a, 0.f);
  }
  __syncthreads();
  if (t < 4) {
    float a = a2b[t];
    for (int j = 0; j < 64; ++j) a += hbuf[j] * A2[j * 4 + t];
    lg[t] = a;
  }
  __syncthreads();
  if (t == 0) {
    float mx = fmaxf(fmaxf(lg[0], lg[1]), fmaxf(lg[2], lg[3]));
    float e[4]; float se = 0.f;
    for (int m = 0; m < 4; ++m) { e[m] = __expf(lg[m] - mx); se += e[m]; }
    float w[4]; float mx2 = -3.4e38f;
    for (int m = 0; m < 4; ++m) { w[m] = mimp[m] * (e[m] / se); mx2 = fmaxf(mx2, w[m]); }
    float se2 = 0.f;
    for (int m = 0; m < 4; ++m) { e[m] = __expf(w[m] - mx2); se2 += e[m]; }
    for (int m = 0; m < 4; ++m) memw[b * 4 + m] = e[m] / se2;
  }
}

// ---------------- 1x1 conv (GEMM) ----------------
// MODE 0: in standard; out = relu(acc+b) -> q5b bf16, layout [slice][n(320 rows, 307 written)][16]
// MODE 4: in standard; out = relu(acc+b) -> vt5b bf16, layout [slice][16][posm(n) of 320]
// MODE 1: in y5 fp32 [slice][n][16]; out standard = acc + b + input(residual)
// MODE 2: in standard; out = relu(acc+b)*(aw+1) + ab + ax
// MODE 3: in standard; out = (acc + b + ax)*(aw+1) + ab
template <int MODE>
__global__ __launch_bounds__(256) void k_conv(
    const float* __restrict__ X, const float* __restrict__ Wt,
    const float* __restrict__ bvec, void* __restrict__ outv,
    const float* __restrict__ aw, const float* __restrict__ ab,
    const float* __restrict__ ax) {
  __shared__ float Xs[128][64];
  __shared__ float Ws[128][64];
  const int sBase = blockIdx.x * 64;
  const int oBase = blockIdx.y * 64;
  const int b = blockIdx.z;
  const int t = threadIdx.x;
#pragma unroll
  for (int i = 0; i < 32; ++i) {
    int idx = t + i * 256;
    int c = idx >> 6, u = idx & 63;
    Ws[c][u] = Wt[c * 128 + oBase + u];
    int s = sBase + u;
    float v = 0.f;
    if (s < SP) {
      if constexpr (MODE == 1) {
        int n = s / 12, l2 = s - n * 12;
        int hh = c >> 4, kk = c & 15;
        v = X[(((b * HH + hh) * LNUM + l2) * NN + n) * DK + kk];
      } else {
        v = X[(size_t)(b * DCH + c) * SP + s];
      }
    }
    Xs[c][u] = v;
  }
  __syncthreads();
  const int tx = t & 15, ty = t >> 4;
  float acc[4][4] = {};
#pragma unroll 4
  for (int c = 0; c < 128; ++c) {
    float4 xv = *(const float4*)&Xs[c][tx * 4];
    float4 wv = *(const float4*)&Ws[c][ty * 4];
    acc[0][0] += wv.x * xv.x; acc[0][1] += wv.x * xv.y; acc[0][2] += wv.x * xv.z; acc[0][3] += wv.x * xv.w;
    acc[1][0] += wv.y * xv.x; acc[1][1] += wv.y * xv.y; acc[1][2] += wv.y * xv.z; acc[1][3] += wv.y * xv.w;
    acc[2][0] += wv.z * xv.x; acc[2][1] += wv.z * xv.y; acc[2][2] += wv.z * xv.z; acc[2][3] += wv.z * xv.w;
    acc[3][0] += wv.w * xv.x; acc[3][1] += wv.w * xv.y; acc[3][2] += wv.w * xv.z; acc[3][3] += wv.w * xv.w;
  }
  const int s0 = sBase + tx * 4;
  const int o0 = oBase + ty * 4;

  if constexpr (MODE == 0) {
    // q5b bf16: [(slice*320 + n)*16 + k]
    if (s0 < SP) {
      unsigned short* qb = (unsigned short*)outv;
      const int hh = o0 >> 4, k0 = o0 & 15;
      float b0 = bvec[o0], b1 = bvec[o0 + 1], b2 = bvec[o0 + 2], b3 = bvec[o0 + 3];
      const int n = s0 / 12, l0 = s0 - n * 12;
#pragma unroll
      for (int si = 0; si < 4; ++si) {
        int sl = (b * HH + hh) * LNUM + (l0 + si);
        ushort4_t q4;
        q4.x = f2bf(fmaxf(acc[0][si] + b0, 0.f));
        q4.y = f2bf(fmaxf(acc[1][si] + b1, 0.f));
        q4.z = f2bf(fmaxf(acc[2][si] + b2, 0.f));
        q4.w = f2bf(fmaxf(acc[3][si] + b3, 0.f));
        *(ushort4_t*)(qb + (sl * 320 + n) * 16 + k0) = q4;
      }
    }
  } else if constexpr (MODE == 4) {
    // vt5b bf16: [(slice*16 + k)*320 + posm(n)]
    if (s0 < SP) {
      unsigned short* vb = (unsigned short*)outv;
      const int hh = o0 >> 4, k0 = o0 & 15;
      float bb[4] = {bvec[o0], bvec[o0 + 1], bvec[o0 + 2], bvec[o0 + 3]};
      const int n = s0 / 12, l0 = s0 - n * 12;
      const int pn = posm(n);
#pragma unroll
      for (int si = 0; si < 4; ++si) {
        int sl = (b * HH + hh) * LNUM + (l0 + si);
#pragma unroll
        for (int oi = 0; oi < 4; ++oi) {
          vb[(sl * 16 + k0 + oi) * 320 + pn] = f2bf(fmaxf(acc[oi][si] + bb[oi], 0.f));
        }
      }
    }
  } else if constexpr (MODE == 1) {
    if (s0 < SP) {
      float* out = (float*)outv;
#pragma unroll
      for (int oi = 0; oi < 4; ++oi) {
        int o = o0 + oi;
        float bb = bvec[o];
        float4 val;
        val.x = acc[oi][0] + bb + Xs[o][tx * 4 + 0];
        val.y = acc[oi][1] + bb + Xs[o][tx * 4 + 1];
        val.z = acc[oi][2] + bb + Xs[o][tx * 4 + 2];
        val.w = acc[oi][3] + bb + Xs[o][tx * 4 + 3];
        *(float4*)(out + (size_t)(b * DCH + o) * SP + s0) = val;
      }
    }
  } else if constexpr (MODE == 2) {
    if (s0 < SP) {
      float* out = (float*)outv;
#pragma unroll
      for (int oi = 0; oi < 4; ++oi) {
        int o = o0 + oi;
        float bb = bvec[o];
        float4 w  = *(const float4*)(aw + o * SP + s0);
        float4 bi = *(const float4*)(ab + o * SP + s0);
        float4 xv = *(const float4*)(ax + (size_t)(b * DCH + o) * SP + s0);
        float4 val;
        float r;
        r = fmaxf(acc[oi][0] + bb, 0.f); val.x = r * (w.x + 1.f) + bi.x + xv.x;
        r = fmaxf(acc[oi][1] + bb, 0.f); val.y = r * (w.y + 1.f) + bi.y + xv.y;
        r = fmaxf(acc[oi][2] + bb, 0.f); val.z = r * (w.z + 1.f) + bi.z + xv.z;
        r = fmaxf(acc[oi][3] + bb, 0.f); val.w = r * (w.w + 1.f) + bi.w + xv.w;
        *(float4*)(out + (size_t)(b * DCH + o) * SP + s0) = val;
      }
    }
  } else {  // MODE 3
    if (s0 < SP) {
      float* out = (float*)outv;
#pragma unroll
      for (int oi = 0; oi < 4; ++oi) {
        int o = o0 + oi;
        float bb = bvec[o];
        float4 w  = *(const float4*)(aw + o * SP + s0);
        float4 bi = *(const float4*)(ab + o * SP + s0);
        float4 zv = *(const float4*)(ax + (size_t)(b * DCH + o) * SP + s0);
        float4 val;
        float tt;
        tt = acc[oi][0] + bb + zv.x; val.x = tt * (w.x + 1.f) + bi.x;
        tt = acc[oi][1] + bb + zv.y; val.y = tt * (w.y + 1.f) + bi.y;
        tt = acc[oi][2] + bb + zv.z; val.z = tt * (w.z + 1.f) + bi.z;
        tt = acc[oi][3] + bb + zv.w; val.w = tt * (w.w + 1.f) + bi.w;
        *(float4*)(out + (size_t)(b * DCH + o) * SP + s0) = val;
      }
    }
  }
}

// GLU conv
__global__ __launch_bounds__(256) void k_conv_glu(
    const float* __restrict__ X, const float* __restrict__ Wt1,
    const float* __restrict__ Wt2, const float* __restrict__ b1,
    const float* __restrict__ b2, float* __restrict__ out) {
  __shared__ float Xs[128][64];
  __shared__ float W1s[128][32];
  __shared__ float W2s[128][32];
  const int sBase = blockIdx.x * 64;
  const int oBase = blockIdx.y * 32;
  const int b = blockIdx.z;
  const int t = threadIdx.x;
#pragma unroll
  for (int i = 0; i < 32; ++i) {
    int idx = t + i * 256;
    int c = idx >> 6, u = idx & 63;
    int s = sBase + u;
    Xs[c][u] = (s < SP) ? X[(size_t)(b * DCH + c) * SP + s] : 0.f;
  }
#pragma unroll
  for (int i = 0; i < 16; ++i) {
    int idx = t + i * 256;
    int c = idx >> 5, o = idx & 31;
    W1s[c][o] = Wt1[c * 128 + oBase + o];
    W2s[c][o] = Wt2[c * 128 + oBase + o];
  }
  __syncthreads();
  const int tx = t & 15, ty = t >> 4;
  float a1[2][4] = {};
  float a2[2][4] = {};
#pragma unroll 4
  for (int c = 0; c < 128; ++c) {
    float4 xv = *(const float4*)&Xs[c][tx * 4];
    float2 w1 = *(const float2*)&W1s[c][ty * 2];
    float2 w2 = *(const float2*)&W2s[c][ty * 2];
    a1[0][0] += w1.x * xv.x; a1[0][1] += w1.x * xv.y; a1[0][2] += w1.x * xv.z; a1[0][3] += w1.x * xv.w;
    a1[1][0] += w1.y * xv.x; a1[1][1] += w1.y * xv.y; a1[1][2] += w1.y * xv.z; a1[1][3] += w1.y * xv.w;
    a2[0][0] += w2.x * xv.x; a2[0][1] += w2.x * xv.y; a2[0][2] += w2.x * xv.z; a2[0][3] += w2.x * xv.w;
    a2[1][0] += w2.y * xv.x; a2[1][1] += w2.y * xv.y; a2[1][2] += w2.y * xv.z; a2[1][3] += w2.y * xv.w;
  }
  const int s0 = sBase + tx * 4;
  if (s0 < SP) {
#pragma unroll
    for (int oi = 0; oi < 2; ++oi) {
      int o = oBase + ty * 2 + oi;
      float bb1 = b1[o], bb2 = b2[o];
      float4 val;
      float v1, v2;
      v1 = a1[oi][0] + bb1; v2 = a2[oi][0] + bb2; val.x = v1 / (1.f + __expf(-v2));
      v1 = a1[oi][1] + bb1; v2 = a2[oi][1] + bb2; val.y = v1 / (1.f + __expf(-v2));
      v1 = a1[oi][2] + bb1; v2 = a2[oi][2] + bb2; val.z = v1 / (1.f + __expf(-v2));
      v1 = a1[oi][3] + bb1; v2 = a2[oi][3] + bb2; val.w = v1 / (1.f + __expf(-v2));
      *(float4*)(out + (size_t)(b * DCH + o) * SP + s0) = val;
    }
  }
}

// ---------------- MFMA attention + graph diffusion ----------------
// grid (LNUM, HH, BB), 256 threads (4 waves x 5 row-tiles of 16 rows).
__global__ __launch_bounds__(256) void k_attn_mfma(
    const unsigned short* __restrict__ q5b, const unsigned short* __restrict__ vt5b,
    const float* __restrict__ memb, const float* __restrict__ memw,
    const unsigned short* __restrict__ adjTb, float* __restrict__ y5) {
  __shared__ unsigned short Mb[320 * 24];   // combined memory, bf16, row stride 24
  __shared__ unsigned short Vt[16 * 328];   // V^T sigma-permuted, bf16, row stride 328
  const int l = blockIdx.x, h = blockIdx.y, b = blockIdx.z;
  const int t = threadIdx.x;
  const int slice = (b * HH + h) * LNUM + l;
  const int msl = (h * LNUM + l) * NN * DK;
  const float w0 = memw[b * 4 + 0], w1 = memw[b * 4 + 1];
  const float w2 = memw[b * 4 + 2], w3 = memw[b * 4 + 3];

  // stage combined memory -> Mb (bf16), rows >=307 zeroed
  for (int idx = t; idx < 640; idx += 256) {
    int n = idx >> 1, h8 = idx & 1;
    float v[8];
    if (n < NN) {
      int off = msl + n * 16 + h8 * 8;
      const float4* p0 = (const float4*)(memb + off);
      const float4* p1 = (const float4*)(memb + MST + off);
      const float4* p2 = (const float4*)(memb + 2 * MST + off);
      const float4* p3 = (const float4*)(memb + 3 * MST + off);
      float4 a0 = p0[0], a1 = p1[0], a2 = p2[0], a3 = p3[0];
      float4 c0 = p0[1], c1 = p1[1], c2 = p2[1], c3 = p3[1];
      v[0] = w0 * a0.x + w1 * a1.x + w2 * a2.x + w3 * a3.x;
      v[1] = w0 * a0.y + w1 * a1.y + w2 * a2.y + w3 * a3.y;
      v[2] = w0 * a0.z + w1 * a1.z + w2 * a2.z + w3 * a3.z;
      v[3] = w0 * a0.w + w1 * a1.w + w2 * a2.w + w3 * a3.w;
      v[4] = w0 * c0.x + w1 * c1.x + w2 * c2.x + w3 * c3.x;
      v[5] = w0 * c0.y + w1 * c1.y + w2 * c2.y + w3 * c3.y;
      v[6] = w0 * c0.z + w1 * c1.z + w2 * c2.z + w3 * c3.z;
      v[7] = w0 * c0.w + w1 * c1.w + w2 * c2.w + w3 * c3.w;
    } else {
#pragma unroll
      for (int j = 0; j < 8; ++j) v[j] = 0.f;
    }
    union { unsigned int w[4]; short8_t s; } u;
#pragma unroll
    for (int j = 0; j < 4; ++j)
      u.w[j] = (unsigned int)f2bf(v[2 * j]) | ((unsigned int)f2bf(v[2 * j + 1]) << 16);
    *(short8_t*)(Mb + n * 24 + h8 * 8) = u.s;
  }
  // stage Vt (copy global -> LDS with stride change 320 -> 328)
  {
    const unsigned short* vsl = vt5b + slice * (16 * 320);
    for (int c = t; c < 640; c += 256) {
      int row = c / 40, ch = c - row * 40;
      short8_t vv = *(const short8_t*)(vsl + row * 320 + ch * 8);
      *(short8_t*)(Vt + row * 328 + ch * 8) = vv;
    }
  }
  __syncthreads();
  // Zero the sigma-columns of Vt that k_conv<4> never writes (n = 307..319).
  // Without this, stale workspace bits (NaN/Inf bf16 patterns on graph replays)
  // reach the PV MFMA and 0*NaN = NaN contaminates the whole D tile.
  for (int idx = t; idx < 16 * 13; idx += 256) {
    int row = idx / 13, j = idx - row * 13;
    Vt[row * 328 + posm(NN + j)] = 0;
  }
  __syncthreads();

  const int wave = t >> 6, lane = t & 63;
  const int r = lane & 15, g = lane >> 4;
  const f32x4 zf = {0.f, 0.f, 0.f, 0.f};
  float maskv[4];
#pragma unroll
  for (int i = 0; i < 4; ++i) maskv[i] = (4 * g + i < 3) ? 1.f : 0.f;
  constexpr float CEXP = 0.25f * 1.44269504089f;

  const int ysl = slice * (NN * DK);
  for (int rt5 = 0; rt5 < 5; ++rt5) {
    const int n0 = (wave * 5 + rt5) * 16;
    short8_t bq = {0, 0, 0, 0, 0, 0, 0, 0};
    // guard n0+r < NN: rows 307..319 of q5b are never written by k_conv<0>
    if (g < 2 && n0 + r < NN) bq = *(const short8_t*)(q5b + (slice * 320 + n0 + r) * 16 + 8 * g);
    f32x4 accPV = zf, accG = zf;
    float dn = 0.f;
#pragma unroll 2
    for (int mt = 0; mt < 10; ++mt) {
      const int mb = mt * 32;
      short8_t am0 = {0, 0, 0, 0, 0, 0, 0, 0}, am1 = am0;
      if (g < 2) {
        am0 = *(const short8_t*)(Mb + (mb + r) * 24 + 8 * g);
        am1 = *(const short8_t*)(Mb + (mb + 16 + r) * 24 + 8 * g);
      }
      f32x4 s0 = __builtin_amdgcn_mfma_f32_16x16x32_bf16(am0, bq, zf, 0, 0, 0);
      f32x4 s1 = __builtin_amdgcn_mfma_f32_16x16x32_bf16(am1, bq, zf, 0, 0, 0);
      float p0[4], p1[4];
#pragma unroll
      for (int i = 0; i < 4; ++i) {
        p0[i] = __builtin_amdgcn_exp2f(s0[i] * CEXP);
        p1[i] = __builtin_amdgcn_exp2f(s1[i] * CEXP);
      }
      if (mt == 9) {
#pragma unroll
        for (int i = 0; i < 4; ++i) p1[i] *= maskv[i];
      }
      dn += p0[0] + p0[1] + p0[2] + p0[3] + p1[0] + p1[1] + p1[2] + p1[3];
      union { unsigned int w[4]; short8_t s; } up;
      asm("v_cvt_pk_bf16_f32 %0, %1, %2" : "=v"(up.w[0]) : "v"(p0[0]), "v"(p0[1]));
      asm("v_cvt_pk_bf16_f32 %0, %1, %2" : "=v"(up.w[1]) : "v"(p0[2]), "v"(p0[3]));
      asm("v_cvt_pk_bf16_f32 %0, %1, %2" : "=v"(up.w[2]) : "v"(p1[0]), "v"(p1[1]));
      asm("v_cvt_pk_bf16_f32 %0, %1, %2" : "=v"(up.w[3]) : "v"(p1[2]), "v"(p1[3]));
      short8_t bv = *(const short8_t*)(Vt + r * 328 + mb + 8 * g);
      accPV = __builtin_amdgcn_mfma_f32_16x16x32_bf16(up.s, bv, accPV, 0, 0, 0);
      short8_t aj = *(const short8_t*)(adjTb + (n0 + r) * 320 + mb + 8 * g);
      accG = __builtin_amdgcn_mfma_f32_16x16x32_bf16(aj, bv, accG, 0, 0, 0);
    }
    dn += __shfl_xor(dn, 16);
    dn += __shfl_xor(dn, 32);
#pragma unroll
    for (int i = 0; i < 4; ++i) {
      int n = n0 + 4 * g + i;
      float di = __shfl(dn, 4 * g + i);
      if (n < NN) y5[ysl + n * 16 + r] = accPV[i] / di + accG[i];
    }
  }
}

// ---------------- layernorm over (D,N) per (b,l), 3-kernel split ----------------

__global__ __launch_bounds__(192) void k_lnstat(
    const float* __restrict__ in, float* __restrict__ pS, float* __restrict__ pSS) {
  const int c = blockIdx.x, b = blockIdx.y, t = threadIdx.x;
  const int dn0 = c * LN_DNC;
  const int dn1 = min(dn0 + LN_DNC, DN);
  const int cnt = (dn1 - dn0) * LNUM;
  const float* p = in + (size_t)b * SZB + (size_t)dn0 * LNUM;
  float s = 0.f, ss = 0.f;
  for (int i = t; i < cnt; i += 192) {
    float v = p[i];
    s += v; ss += v * v;
  }
  __shared__ float rs[192], rss[192];
  rs[t] = s; rss[t] = ss;
  __syncthreads();
  if (t < 12) {
    float S = 0.f, SS = 0.f;
    for (int j = t; j < 192; j += 12) { S += rs[j]; SS += rss[j]; }
    pS[(b * LN_CH + c) * 12 + t] = S;
    pSS[(b * LN_CH + c) * 12 + t] = SS;
  }
}

__global__ __launch_bounds__(96) void k_lnfin(
    const float* __restrict__ pS, const float* __restrict__ pSS,
    float* __restrict__ meanp, float* __restrict__ rstdp) {
  const int t = threadIdx.x;
  const int b = t / 12, l = t % 12;
  float S = 0.f, SS = 0.f;
  for (int c = 0; c < LN_CH; ++c) {
    S += pS[(b * LN_CH + c) * 12 + l];
    SS += pSS[(b * LN_CH + c) * 12 + l];
  }
  float mu = S * (1.f / DN);
  float var = SS * (1.f / DN) - mu * mu;
  meanp[t] = mu;
  rstdp[t] = rsqrtf(fmaxf(var, 0.f) + 1e-5f);
}

__global__ __launch_bounds__(256) void k_lnapply(
    const float* __restrict__ in, const float* __restrict__ meanp,
    const float* __restrict__ rstdp, float* __restrict__ outp) {
  const int i0 = (blockIdx.x * 256 + threadIdx.x) * 4;
  float4 v = *(const float4*)(in + i0);
  const int b = (int)((unsigned)i0 / (unsigned)SZB);
  const int rr = i0 - b * SZB;
  const int l0 = rr % 12;
  const float* mp = meanp + b * 12;
  const float* rp = rstdp + b * 12;
  float4 o;
  o.x = (v.x - mp[l0 + 0]) * rp[l0 + 0];
  o.y = (v.y - mp[l0 + 1]) * rp[l0 + 1];
  o.z = (v.z - mp[l0 + 2]) * rp[l0 + 2];
  o.w = (v.w - mp[l0 + 3]) * rp[l0 + 3];
  *(float4*)(outp + i0) = o;
}

}  // namespace

extern "C" void kernel_launch(void* const* d_in, const int* in_sizes, int n_in,
                              void* d_out, int out_size, void* d_ws, size_t ws_size,
                              hipStream_t stream) {
  (void)in_sizes; (void)n_in; (void)out_size; (void)ws_size;
  const float* x    = (const float*)d_in[0];
  const float* Wq   = (const float*)d_in[1];
  const float* bq   = (const float*)d_in[2];
  const float* Wv   = (const float*)d_in[3];
  const float* bv   = (const float*)d_in[4];
  const float* Wc   = (const float*)d_in[5];
  const float* bc   = (const float*)d_in[6];
  const float* Wx   = (const float*)d_in[7];
  const float* bx   = (const float*)d_in[8];
  const float* Wg1  = (const float*)d_in[9];
  const float* bg1  = (const float*)d_in[10];
  const float* Wg2  = (const float*)d_in[11];
  const float* bg2  = (const float*)d_in[12];
  const float* Wg3  = (const float*)d_in[13];
  const float* bg3  = (const float*)d_in[14];
  const float* memb = (const float*)d_in[15];
  const float* mimp = (const float*)d_in[16];
  const float* A1   = (const float*)d_in[17];
  const float* a1b  = (const float*)d_in[18];
  const float* A2   = (const float*)d_in[19];
  const float* a2b  = (const float*)d_in[20];
  const float* wgt  = (const float*)d_in[21];
  const float* bia  = (const float*)d_in[22];
  const float* nv1  = (const float*)d_in[23];
  const float* nv2  = (const float*)d_in[24];
  const float* sws  = (const float*)d_in[25];

  float* ws = (float*)d_ws;
  float* P0 = ws;                        // also hosts q5b (bf16) before MODE1
  float* P1 = ws + (size_t)SZ;           // also hosts vt5b (bf16) before MODE2
  float* P2 = ws + 2 * (size_t)SZ;       // y5 fp32
  float* sm = ws + 3 * (size_t)SZ;
  float* s1 = sm;
  float* s2 = sm + ADJN;
  float* s3 = sm + 2 * ADJN;
  float* adjT_f = sm + 3 * ADJN;            // 51200 floats = 320*320 bf16
  float* memw = adjT_f + 51200;
  float* WtA  = memw + 32;                  // 7*16384
  float* pS   = WtA + 7 * 16384;
  float* pSS  = pS + BB * LN_CH * 12;
  float* meanp = pSS + BB * LN_CH * 12;
  float* rstdp = meanp + 96;
  float* avgb  = rstdp + 96;                // 1024 floats

  unsigned short* q5b  = (unsigned short*)P0;
  unsigned short* vt5b = (unsigned short*)P1;
  unsigned short* adjTb = (unsigned short*)adjT_f;

  k_transW<<<dim3(64, 7), 256, 0, stream>>>(Wq, Wv, Wx, Wc, Wg1, Wg2, Wg3, WtA);
  k_s1<<<NN, 320, 0, stream>>>(nv1, nv2, s1);
  k_smm<<<NN, 320, 0, stream>>>(s1, s1, s2);
  k_smm<<<NN, 320, 0, stream>>>(s2, s1, s3);
  k_adjT<<<(320 * 160 + 255) / 256, 256, 0, stream>>>(s1, s2, s3, sws, (unsigned int*)adjTb);
  k_avg<<<BB * DCH / 4, 256, 0, stream>>>(x, avgb);
  k_memw2<<<BB, 128, 0, stream>>>(avgb, A1, a1b, A2, a2b, mimp, memw);

  // q5b, vt5b projections (bf16, MFMA-friendly layouts)
  k_conv<0><<<dim3(58, 2, BB), 256, 0, stream>>>(x, WtA + 0 * 16384, bq, q5b, nullptr, nullptr, nullptr);
  k_conv<4><<<dim3(58, 2, BB), 256, 0, stream>>>(x, WtA + 1 * 16384, bv, vt5b, nullptr, nullptr, nullptr);

  // MFMA attention + graph -> y5 (P2)
  k_attn_mfma<<<dim3(LNUM, HH, BB), 256, 0, stream>>>(q5b, vt5b, memb, memw, adjTb, P2);

  // t = y + conv(y, Wx, bx): y5 input, standard output (P0; q5b dead)
  k_conv<1><<<dim3(58, 2, BB), 256, 0, stream>>>(P2, WtA + 2 * 16384, bx, P0, nullptr, nullptr, nullptr);
  // z_in = relu(conv(t, Wc, bc))*(w+1) + bias + x  (P1; vt5b dead)
  k_conv<2><<<dim3(58, 2, BB), 256, 0, stream>>>(P0, WtA + 3 * 16384, bc, P1, wgt, bia, x);

  // z = ln12(z_in)  (P1 -> P2)
  k_lnstat<<<dim3(LN_CH, BB), 192, 0, stream>>>(P1, pS, pSS);
  k_lnfin<<<1, 96, 0, stream>>>(pS, pSS, meanp, rstdp);
  k_lnapply<<<SZ / 1024, 256, 0, stream>>>(P1, meanp, rstdp, P2);

  // g = conv(z,Wg1,bg1)*sigmoid(conv(z,Wg2,bg2))  (P2 -> P0)
  k_conv_glu<<<dim3(58, 4, BB), 256, 0, stream>>>(P2, WtA + 4 * 16384, WtA + 5 * 16384, bg1, bg2, P0);
  // t2 = (conv(g,Wg3,bg3) + z)*(w+1) + bias  (P0 -> P1, z from P2)
  k_conv<3><<<dim3(58, 2, BB), 256, 0, stream>>>(P0, WtA + 6 * 16384, bg3, P1, wgt, bia, P2);

  // out = ln12(t2)
  k_lnstat<<<dim3(LN_CH, BB), 192, 0, stream>>>(P1, pS, pSS);
  k_lnfin<<<1, 96, 0, stream>>>(pS, pSS, meanp, rstdp);
  k_lnapply<<<SZ / 1024, 256, 0, stream>>>(P1, meanp, rstdp, (float*)d_out);
}

// Round 6
// 260.560 us; speedup vs baseline: 2.5350x; 1.5664x over previous
//
#include <hip/hip_runtime.h>

namespace {

constexpr int NN   = 307;
constexpr int LNUM = 12;
constexpr int SP   = NN * LNUM;        // 3684
constexpr int DCH  = 128;
constexpr int HH   = 8;
constexpr int DK   = 16;
constexpr int BB   = 8;
constexpr int SZB  = DCH * SP;         // 471552 per batch
constexpr int SZ   = BB * SZB;         // 3772416 total
constexpr int ADJN = NN * NN;          // 94249
constexpr int DN   = DCH * NN;         // 39296 (layernorm group size)
constexpr int LN_CH = 48;
constexpr int LN_DNC = 819;            // ceil(39296/48)
constexpr int MST  = HH * LNUM * NN * DK;  // mem_bank per-slot stride = 471552

typedef __attribute__((ext_vector_type(8))) short short8_t;
typedef __attribute__((ext_vector_type(4))) float f32x4;
typedef __attribute__((ext_vector_type(4))) unsigned short ushort4_t;

__device__ inline unsigned short f2bf(float f) {
  unsigned int u = __builtin_bit_cast(unsigned int, f);
  unsigned int r = (u + 0x7FFFu + ((u >> 16) & 1u)) >> 16;
  return (unsigned short)r;
}

// sigma-permuted column position for m within the V / adjT buffers
__device__ __host__ inline int posm(int m) {
  int q = (m & 15) >> 2, sub = (m >> 4) & 1, i = m & 3;
  return (m & ~31) + 8 * q + 4 * sub + i;
}

// ---------------- small prep kernels ----------------

// Convert all 7 [128][128] weight matrices to bf16, SAME layout [o][c].
__global__ __launch_bounds__(256) void k_cvtW(
    const float* __restrict__ W0, const float* __restrict__ W1,
    const float* __restrict__ W2, const float* __restrict__ W3,
    const float* __restrict__ W4, const float* __restrict__ W5,
    const float* __restrict__ W6, unsigned int* __restrict__ Wb) {
  const float* srcs[7] = {W0, W1, W2, W3, W4, W5, W6};
  int idx = blockIdx.x * 256 + threadIdx.x;   // 0..57343 (7*8192 u32)
  int w = idx >> 13, off = idx & 8191;
  const float* s = srcs[w];
  float v0 = s[off * 2], v1 = s[off * 2 + 1];
  unsigned int pk;
  asm("v_cvt_pk_bf16_f32 %0, %1, %2" : "=v"(pk) : "v"(v0), "v"(v1));
  Wb[idx] = pk;
}

// s1 = softmax(relu(nv1 @ nv2), axis=-1). One block per row i.
__global__ __launch_bounds__(320) void k_s1(
    const float* __restrict__ nv1, const float* __restrict__ nv2,
    float* __restrict__ out) {
  __shared__ float red[512];
  __shared__ float rowA[10];
  const int i = blockIdx.x, j = threadIdx.x;
  if (j < 10) rowA[j] = nv1[i * 10 + j];
  __syncthreads();
  float val = 0.f;
  if (j < NN) {
#pragma unroll
    for (int k = 0; k < 10; ++k) val += rowA[k] * nv2[k * NN + j];
    val = fmaxf(val, 0.f);
  }
  red[j] = (j < NN) ? val : -3.4e38f;
  if (j < 192) red[j + 320] = -3.4e38f;
  __syncthreads();
  for (int s = 256; s >= 1; s >>= 1) {
    if (j < s) red[j] = fmaxf(red[j], red[j + s]);
    __syncthreads();
  }
  float mx = red[0];
  __syncthreads();
  float e = (j < NN) ? __expf(val - mx) : 0.f;
  red[j] = e;
  if (j < 192) red[j + 320] = 0.f;
  __syncthreads();
  for (int s = 256; s >= 1; s >>= 1) {
    if (j < s) red[j] += red[j + s];
    __syncthreads();
  }
  if (j < NN) out[i * NN + j] = e / red[0];
}

// out = softmax(Sa @ Sb, axis=-1). One block per row i.
__global__ __launch_bounds__(320) void k_smm(
    const float* __restrict__ Sa, const float* __restrict__ Sb,
    float* __restrict__ out) {
  __shared__ float red[512];
  __shared__ float rowA[320];
  const int i = blockIdx.x, j = threadIdx.x;
  if (j < NN) rowA[j] = Sa[i * NN + j];
  __syncthreads();
  float val = 0.f;
  if (j < NN) {
    for (int k = 0; k < NN; ++k) val += rowA[k] * Sb[k * NN + j];
  }
  red[j] = (j < NN) ? val : -3.4e38f;
  if (j < 192) red[j + 320] = -3.4e38f;
  __syncthreads();
  for (int s = 256; s >= 1; s >>= 1) {
    if (j < s) red[j] = fmaxf(red[j], red[j + s]);
    __syncthreads();
  }
  float mx = red[0];
  __syncthreads();
  float e = (j < NN) ? __expf(val - mx) : 0.f;
  red[j] = e;
  if (j < 192) red[j + 320] = 0.f;
  __syncthreads();
  for (int s = 256; s >= 1; s >>= 1) {
    if (j < s) red[j] += red[j + s];
    __syncthreads();
  }
  if (j < NN) out[i * NN + j] = e / red[0];
}

// adjTb[n][posm(m)] = bf16( sw0*s1[m][n] + sw1*s2[m][n] + sw2*s3[m][n] ), zero-padded to 320x320.
__global__ __launch_bounds__(256) void k_adjT(
    const float* __restrict__ s1, const float* __restrict__ s2,
    const float* __restrict__ s3, const float* __restrict__ sws,
    unsigned int* __restrict__ adjTw) {   // u32 view of adjTb
  int idx = blockIdx.x * 256 + threadIdx.x;   // 0 .. 320*160-1
  if (idx >= 320 * 160) return;
  int n = idx / 160, wp = idx - n * 160;
  int pos0 = 2 * wp;
  int bq = pos0 & 31;
  int g = bq >> 3, sub = (bq >> 2) & 1, i = bq & 3;
  int m0 = (pos0 & ~31) + sub * 16 + 4 * g + i;   // m1 = m0 + 1
  float w0 = sws[0], w1 = sws[1], w2 = sws[2];
  float mm = fmaxf(w0, fmaxf(w1, w2));
  float e0 = __expf(w0 - mm), e1 = __expf(w1 - mm), e2 = __expf(w2 - mm);
  float inv = 1.f / (e0 + e1 + e2);
  e0 *= inv; e1 *= inv; e2 *= inv;
  float v0 = 0.f, v1 = 0.f;
  if (n < NN) {
    if (m0 < NN)     v0 = e0 * s1[m0 * NN + n] + e1 * s2[m0 * NN + n] + e2 * s3[m0 * NN + n];
    if (m0 + 1 < NN) v1 = e0 * s1[(m0 + 1) * NN + n] + e1 * s2[(m0 + 1) * NN + n] + e2 * s3[(m0 + 1) * NN + n];
  }
  adjTw[n * 160 + wp] = (unsigned int)f2bf(v0) | ((unsigned int)f2bf(v1) << 16);
}

// avg[b*128+d] = mean over SP of x[b][d][:]. One wave per row, coalesced float4.
__global__ __launch_bounds__(256) void k_avg(
    const float* __restrict__ x, float* __restrict__ avg) {
  const int row = blockIdx.x * 4 + (threadIdx.x >> 6);   // 0..1023 = b*128+d
  const int lane = threadIdx.x & 63;
  const float* p = x + (size_t)row * SP;
  float s = 0.f;
  for (int i = lane; i < SP / 4; i += 64) {    // SP/4 = 921 float4s
    float4 v = *(const float4*)(p + i * 4);
    s += v.x + v.y + v.z + v.w;
  }
  s += __shfl_xor(s, 1);  s += __shfl_xor(s, 2);  s += __shfl_xor(s, 4);
  s += __shfl_xor(s, 8);  s += __shfl_xor(s, 16); s += __shfl_xor(s, 32);
  if (lane == 0) avg[row] = s * (1.f / SP);
}

// mem_w[b][0..3] from precomputed avg. One (tiny) block per b.
__global__ __launch_bounds__(128) void k_memw2(
    const float* __restrict__ avgg, const float* __restrict__ A1,
    const float* __restrict__ a1b, const float* __restrict__ A2,
    const float* __restrict__ a2b, const float* __restrict__ mimp,
    float* __restrict__ memw) {
  const int b = blockIdx.x, t = threadIdx.x;
  __shared__ float avg[128];
  __shared__ float hbuf[64];
  __shared__ float lg[4];
  avg[t] = avgg[b * 128 + t];
  __syncthreads();
  if (t < 64) {
    float a = a1b[t];
    for (int d = 0; d < 128; ++d) a += avg[d] * A1[d * 64 + t];
    hbuf[t] = fmaxf(a, 0.f);
  }
  __syncthreads();
  if (t < 4) {
    float a = a2b[t];
    for (int j = 0; j < 64; ++j) a += hbuf[j] * A2[j * 4 + t];
    lg[t] = a;
  }
  __syncthreads();
  if (t == 0) {
    float mx = fmaxf(fmaxf(lg[0], lg[1]), fmaxf(lg[2], lg[3]));
    float e[4]; float se = 0.f;
    for (int m = 0; m < 4; ++m) { e[m] = __expf(lg[m] - mx); se += e[m]; }
    float w[4]; float mx2 = -3.4e38f;
    for (int m = 0; m < 4; ++m) { w[m] = mimp[m] * (e[m] / se); mx2 = fmaxf(mx2, w[m]); }
    float se2 = 0.f;
    for (int m = 0; m < 4; ++m) { e[m] = __expf(w[m] - mx2); se2 += e[m]; }
    for (int m = 0; m < 4; ++m) memw[b * 4 + m] = e[m] / se2;
  }
}

// ---------------- MFMA 1x1 conv (GEMM) ----------------
// C[s][o] = X^T[s][c] * W^T[o][c] via mfma(A=X_frag, B=W_frag).
// Block: 256 thr = 4 waves; tile: 64 s (16/wave) x 128 o; K=128 unrolled.
// LDS: Xs [64 s][128 c] bf16 XOR-swizzled (16KB), Ws [128 o][128 c] (32KB).
// Lane(r,g) reg i holds C[sBase + wave*16 + 4g + i][ot*16 + r] -> float4 stores.
// MODE 0: out = relu(acc+b) -> q5b bf16 [sl][n][16]
// MODE 4: out = relu(acc+b) -> vt5b bf16 [sl][16][posm(n)]
// MODE 1: X = y5 fp32 [sl][n][16]; out std = acc + b + y
// MODE 2: out std = relu(acc+b)*(aw+1) + ab + ax
// MODE 3: out std = (acc + b + ax)*(aw+1) + ab
template <int MODE>
__global__ __launch_bounds__(256) void k_convm(
    const unsigned short* __restrict__ Wbf, const float* __restrict__ X,
    const float* __restrict__ bvec, void* __restrict__ outv,
    const float* __restrict__ aw, const float* __restrict__ ab,
    const float* __restrict__ ax) {
  __shared__ unsigned short Xs[64 * 128];
  __shared__ unsigned short Ws[128 * 128];
  const int sBase = blockIdx.x * 64;
  const int b = blockIdx.z;
  const int t = threadIdx.x;

  // stage X -> Xs bf16 [s][c], byte swizzle: off = u*256 + ((2c) ^ ((u&7)<<4))
  {
    const int u = t & 63, cp = t >> 6;
    const int s = sBase + u;
    const bool in = s < SP;
    const int n = s / 12, l2 = s - n * 12;
#pragma unroll
    for (int it = 0; it < 16; ++it) {
      int c0 = it * 8 + cp * 2;
      float v0 = 0.f, v1 = 0.f;
      if (in) {
        if constexpr (MODE == 1) {
          v0 = X[(((b * HH + (c0 >> 4)) * LNUM + l2) * NN + n) * DK + (c0 & 15)];
          v1 = X[(((b * HH + ((c0 + 1) >> 4)) * LNUM + l2) * NN + n) * DK + ((c0 + 1) & 15)];
        } else {
          v0 = X[(size_t)(b * DCH + c0) * SP + s];
          v1 = X[(size_t)(b * DCH + c0 + 1) * SP + s];
        }
      }
      unsigned int pk;
      asm("v_cvt_pk_bf16_f32 %0, %1, %2" : "=v"(pk) : "v"(v0), "v"(v1));
      *(unsigned int*)((char*)Xs + u * 256 + ((2 * c0) ^ ((u & 7) << 4))) = pk;
    }
  }
  // stage Wbf -> Ws [o][c] swizzled (coalesced 16B global reads)
  {
    const int o = t >> 1, half = t & 1;
    const unsigned short* src = Wbf + o * 128 + half * 64;
#pragma unroll
    for (int j = 0; j < 8; ++j) {
      short8_t v = *(const short8_t*)(src + j * 8);
      *(short8_t*)((char*)Ws + o * 256 + ((half * 128 + j * 16) ^ ((o & 7) << 4))) = v;
    }
  }
  __syncthreads();

  const int wave = t >> 6, lane = t & 63;
  const int r = lane & 15, g = lane >> 4;
  const int swz = (r & 7) << 4;

  short8_t xa[4];
#pragma unroll
  for (int kk = 0; kk < 4; ++kk)
    xa[kk] = *(const short8_t*)((const char*)Xs + (wave * 16 + r) * 256 + ((kk * 64 + g * 16) ^ swz));

  const f32x4 zf = {0.f, 0.f, 0.f, 0.f};
  f32x4 acc[8];
#pragma unroll
  for (int ot = 0; ot < 8; ++ot) acc[ot] = zf;
#pragma unroll
  for (int ot = 0; ot < 8; ++ot) {
#pragma unroll
    for (int kk = 0; kk < 4; ++kk) {
      short8_t wb = *(const short8_t*)((const char*)Ws + (ot * 16 + r) * 256 + ((kk * 64 + g * 16) ^ swz));
      acc[ot] = __builtin_amdgcn_mfma_f32_16x16x32_bf16(xa[kk], wb, acc[ot], 0, 0, 0);
    }
  }

  const int s0 = sBase + wave * 16 + 4 * g;   // SP%4==0: whole float4 in/out of range
  if (s0 >= SP) return;

  if constexpr (MODE == 0) {
    unsigned short* qb = (unsigned short*)outv;
#pragma unroll
    for (int ot = 0; ot < 8; ++ot) {
      float bv = bvec[ot * 16 + r];
#pragma unroll
      for (int i = 0; i < 4; ++i) {
        int s = s0 + i, n = s / 12, l2 = s - n * 12;
        qb[((b * 8 + ot) * 12 + l2) * 5120 + n * 16 + r] = f2bf(fmaxf(acc[ot][i] + bv, 0.f));
      }
    }
  } else if constexpr (MODE == 4) {
    unsigned short* vb = (unsigned short*)outv;
#pragma unroll
    for (int ot = 0; ot < 8; ++ot) {
      float bv = bvec[ot * 16 + r];
#pragma unroll
      for (int i = 0; i < 4; ++i) {
        int s = s0 + i, n = s / 12, l2 = s - n * 12;
        vb[((b * 8 + ot) * 12 + l2) * 5120 + r * 320 + posm(n)] = f2bf(fmaxf(acc[ot][i] + bv, 0.f));
      }
    }
  } else if constexpr (MODE == 1) {
    float* out = (float*)outv;
#pragma unroll
    for (int ot = 0; ot < 8; ++ot) {
      int o = ot * 16 + r;
      float bv = bvec[o];
      float4 val;
#pragma unroll
      for (int i = 0; i < 4; ++i) {
        int s = s0 + i, n = s / 12, l2 = s - n * 12;
        float y = X[(((b * 8 + ot) * 12 + l2) * NN + n) * DK + r];
        (&val.x)[i] = acc[ot][i] + bv + y;
      }
      *(float4*)(out + (size_t)(b * DCH + o) * SP + s0) = val;
    }
  } else if constexpr (MODE == 2) {
    float* out = (float*)outv;
#pragma unroll
    for (int ot = 0; ot < 8; ++ot) {
      int o = ot * 16 + r;
      float bv = bvec[o];
      float4 w4 = *(const float4*)(aw + o * SP + s0);
      float4 b4 = *(const float4*)(ab + o * SP + s0);
      float4 x4 = *(const float4*)(ax + (size_t)(b * DCH + o) * SP + s0);
      float4 val;
#pragma unroll
      for (int i = 0; i < 4; ++i) {
        float rr = fmaxf(acc[ot][i] + bv, 0.f);
        (&val.x)[i] = rr * ((&w4.x)[i] + 1.f) + (&b4.x)[i] + (&x4.x)[i];
      }
      *(float4*)(out + (size_t)(b * DCH + o) * SP + s0) = val;
    }
  } else {  // MODE 3
    float* out = (float*)outv;
#pragma unroll
    for (int ot = 0; ot < 8; ++ot) {
      int o = ot * 16 + r;
      float bv = bvec[o];
      float4 w4 = *(const float4*)(aw + o * SP + s0);
      float4 b4 = *(const float4*)(ab + o * SP + s0);
      float4 z4 = *(const float4*)(ax + (size_t)(b * DCH + o) * SP + s0);
      float4 val;
#pragma unroll
      for (int i = 0; i < 4; ++i) {
        float tt = acc[ot][i] + bv + (&z4.x)[i];
        (&val.x)[i] = tt * ((&w4.x)[i] + 1.f) + (&b4.x)[i];
      }
      *(float4*)(out + (size_t)(b * DCH + o) * SP + s0) = val;
    }
  }
}

// GLU conv via MFMA: two weight matrices staged sequentially in the same LDS (<=48KB).
__global__ __launch_bounds__(256) void k_convm_glu(
    const unsigned short* __restrict__ Wb1, const unsigned short* __restrict__ Wb2,
    const float* __restrict__ X, const float* __restrict__ b1,
    const float* __restrict__ b2, float* __restrict__ out) {
  __shared__ unsigned short Xs[64 * 128];
  __shared__ unsigned short Ws[128 * 128];
  const int sBase = blockIdx.x * 64;
  const int b = blockIdx.z;
  const int t = threadIdx.x;

  {
    const int u = t & 63, cp = t >> 6;
    const int s = sBase + u;
    const bool in = s < SP;
#pragma unroll
    for (int it = 0; it < 16; ++it) {
      int c0 = it * 8 + cp * 2;
      float v0 = 0.f, v1 = 0.f;
      if (in) {
        v0 = X[(size_t)(b * DCH + c0) * SP + s];
        v1 = X[(size_t)(b * DCH + c0 + 1) * SP + s];
      }
      unsigned int pk;
      asm("v_cvt_pk_bf16_f32 %0, %1, %2" : "=v"(pk) : "v"(v0), "v"(v1));
      *(unsigned int*)((char*)Xs + u * 256 + ((2 * c0) ^ ((u & 7) << 4))) = pk;
    }
  }
  const int o = t >> 1, half = t & 1;
  {
    const unsigned short* src = Wb1 + o * 128 + half * 64;
#pragma unroll
    for (int j = 0; j < 8; ++j) {
      short8_t v = *(const short8_t*)(src + j * 8);
      *(short8_t*)((char*)Ws + o * 256 + ((half * 128 + j * 16) ^ ((o & 7) << 4))) = v;
    }
  }
  __syncthreads();

  const int wave = t >> 6, lane = t & 63;
  const int r = lane & 15, g = lane >> 4;
  const int swz = (r & 7) << 4;

  short8_t xa[4];
#pragma unroll
  for (int kk = 0; kk < 4; ++kk)
    xa[kk] = *(const short8_t*)((const char*)Xs + (wave * 16 + r) * 256 + ((kk * 64 + g * 16) ^ swz));

  const f32x4 zf = {0.f, 0.f, 0.f, 0.f};
  f32x4 acc1[8], acc2[8];
#pragma unroll
  for (int ot = 0; ot < 8; ++ot) { acc1[ot] = zf; acc2[ot] = zf; }
#pragma unroll
  for (int ot = 0; ot < 8; ++ot) {
#pragma unroll
    for (int kk = 0; kk < 4; ++kk) {
      short8_t wb = *(const short8_t*)((const char*)Ws + (ot * 16 + r) * 256 + ((kk * 64 + g * 16) ^ swz));
      acc1[ot] = __builtin_amdgcn_mfma_f32_16x16x32_bf16(xa[kk], wb, acc1[ot], 0, 0, 0);
    }
  }
  __syncthreads();   // all waves done reading Ws
  {
    const unsigned short* src = Wb2 + o * 128 + half * 64;
#pragma unroll
    for (int j = 0; j < 8; ++j) {
      short8_t v = *(const short8_t*)(src + j * 8);
      *(short8_t*)((char*)Ws + o * 256 + ((half * 128 + j * 16) ^ ((o & 7) << 4))) = v;
    }
  }
  __syncthreads();
#pragma unroll
  for (int ot = 0; ot < 8; ++ot) {
#pragma unroll
    for (int kk = 0; kk < 4; ++kk) {
      short8_t wb = *(const short8_t*)((const char*)Ws + (ot * 16 + r) * 256 + ((kk * 64 + g * 16) ^ swz));
      acc2[ot] = __builtin_amdgcn_mfma_f32_16x16x32_bf16(xa[kk], wb, acc2[ot], 0, 0, 0);
    }
  }

  const int s0 = sBase + wave * 16 + 4 * g;
  if (s0 >= SP) return;
#pragma unroll
  for (int ot = 0; ot < 8; ++ot) {
    int oo = ot * 16 + r;
    float bb1 = b1[oo], bb2 = b2[oo];
    float4 val;
#pragma unroll
    for (int i = 0; i < 4; ++i) {
      float v1 = acc1[ot][i] + bb1;
      float v2 = acc2[ot][i] + bb2;
      (&val.x)[i] = v1 / (1.f + __expf(-v2));
    }
    *(float4*)(out + (size_t)(b * DCH + oo) * SP + s0) = val;
  }
}

// ---------------- MFMA attention + graph diffusion ----------------
// grid (LNUM, HH, BB), 256 threads (4 waves x 5 row-tiles of 16 rows).
__global__ __launch_bounds__(256) void k_attn_mfma(
    const unsigned short* __restrict__ q5b, const unsigned short* __restrict__ vt5b,
    const float* __restrict__ memb, const float* __restrict__ memw,
    const unsigned short* __restrict__ adjTb, float* __restrict__ y5) {
  __shared__ unsigned short Mb[320 * 24];   // combined memory, bf16, row stride 24
  __shared__ unsigned short Vt[16 * 328];   // V^T sigma-permuted, bf16, row stride 328
  const int l = blockIdx.x, h = blockIdx.y, b = blockIdx.z;
  const int t = threadIdx.x;
  const int slice = (b * HH + h) * LNUM + l;
  const int msl = (h * LNUM + l) * NN * DK;
  const float w0 = memw[b * 4 + 0], w1 = memw[b * 4 + 1];
  const float w2 = memw[b * 4 + 2], w3 = memw[b * 4 + 3];

  for (int idx = t; idx < 640; idx += 256) {
    int n = idx >> 1, h8 = idx & 1;
    float v[8];
    if (n < NN) {
      int off = msl + n * 16 + h8 * 8;
      const float4* p0 = (const float4*)(memb + off);
      const float4* p1 = (const float4*)(memb + MST + off);
      const float4* p2 = (const float4*)(memb + 2 * MST + off);
      const float4* p3 = (const float4*)(memb + 3 * MST + off);
      float4 a0 = p0[0], a1 = p1[0], a2 = p2[0], a3 = p3[0];
      float4 c0 = p0[1], c1 = p1[1], c2 = p2[1], c3 = p3[1];
      v[0] = w0 * a0.x + w1 * a1.x + w2 * a2.x + w3 * a3.x;
      v[1] = w0 * a0.y + w1 * a1.y + w2 * a2.y + w3 * a3.y;
      v[2] = w0 * a0.z + w1 * a1.z + w2 * a2.z + w3 * a3.z;
      v[3] = w0 * a0.w + w1 * a1.w + w2 * a2.w + w3 * a3.w;
      v[4] = w0 * c0.x + w1 * c1.x + w2 * c2.x + w3 * c3.x;
      v[5] = w0 * c0.y + w1 * c1.y + w2 * c2.y + w3 * c3.y;
      v[6] = w0 * c0.z + w1 * c1.z + w2 * c2.z + w3 * c3.z;
      v[7] = w0 * c0.w + w1 * c1.w + w2 * c2.w + w3 * c3.w;
    } else {
#pragma unroll
      for (int j = 0; j < 8; ++j) v[j] = 0.f;
    }
    union { unsigned int w[4]; short8_t s; } u;
#pragma unroll
    for (int j = 0; j < 4; ++j)
      u.w[j] = (unsigned int)f2bf(v[2 * j]) | ((unsigned int)f2bf(v[2 * j + 1]) << 16);
    *(short8_t*)(Mb + n * 24 + h8 * 8) = u.s;
  }
  {
    const unsigned short* vsl = vt5b + slice * (16 * 320);
    for (int c = t; c < 640; c += 256) {
      int row = c / 40, ch = c - row * 40;
      short8_t vv = *(const short8_t*)(vsl + row * 320 + ch * 8);
      *(short8_t*)(Vt + row * 328 + ch * 8) = vv;
    }
  }
  __syncthreads();
  // Zero sigma-columns of Vt never written by the v-conv (n = 307..319):
  // stale workspace bits would otherwise reach the PV MFMA (0*NaN = NaN).
  for (int idx = t; idx < 16 * 13; idx += 256) {
    int row = idx / 13, j = idx - row * 13;
    Vt[row * 328 + posm(NN + j)] = 0;
  }
  __syncthreads();

  const int wave = t >> 6, lane = t & 63;
  const int r = lane & 15, g = lane >> 4;
  const f32x4 zf = {0.f, 0.f, 0.f, 0.f};
  float maskv[4];
#pragma unroll
  for (int i = 0; i < 4; ++i) maskv[i] = (4 * g + i < 3) ? 1.f : 0.f;
  constexpr float CEXP = 0.25f * 1.44269504089f;

  const int ysl = slice * (NN * DK);
  for (int rt5 = 0; rt5 < 5; ++rt5) {
    const int n0 = (wave * 5 + rt5) * 16;
    short8_t bq = {0, 0, 0, 0, 0, 0, 0, 0};
    if (g < 2 && n0 + r < NN) bq = *(const short8_t*)(q5b + (slice * 320 + n0 + r) * 16 + 8 * g);
    f32x4 accPV = zf, accG = zf;
    float dn = 0.f;
#pragma unroll 2
    for (int mt = 0; mt < 10; ++mt) {
      const int mb = mt * 32;
      short8_t am0 = {0, 0, 0, 0, 0, 0, 0, 0}, am1 = am0;
      if (g < 2) {
        am0 = *(const short8_t*)(Mb + (mb + r) * 24 + 8 * g);
        am1 = *(const short8_t*)(Mb + (mb + 16 + r) * 24 + 8 * g);
      }
      f32x4 s0 = __builtin_amdgcn_mfma_f32_16x16x32_bf16(am0, bq, zf, 0, 0, 0);
      f32x4 s1 = __builtin_amdgcn_mfma_f32_16x16x32_bf16(am1, bq, zf, 0, 0, 0);
      float p0[4], p1[4];
#pragma unroll
      for (int i = 0; i < 4; ++i) {
        p0[i] = __builtin_amdgcn_exp2f(s0[i] * CEXP);
        p1[i] = __builtin_amdgcn_exp2f(s1[i] * CEXP);
      }
      if (mt == 9) {
#pragma unroll
        for (int i = 0; i < 4; ++i) p1[i] *= maskv[i];
      }
      dn += p0[0] + p0[1] + p0[2] + p0[3] + p1[0] + p1[1] + p1[2] + p1[3];
      union { unsigned int w[4]; short8_t s; } up;
      asm("v_cvt_pk_bf16_f32 %0, %1, %2" : "=v"(up.w[0]) : "v"(p0[0]), "v"(p0[1]));
      asm("v_cvt_pk_bf16_f32 %0, %1, %2" : "=v"(up.w[1]) : "v"(p0[2]), "v"(p0[3]));
      asm("v_cvt_pk_bf16_f32 %0, %1, %2" : "=v"(up.w[2]) : "v"(p1[0]), "v"(p1[1]));
      asm("v_cvt_pk_bf16_f32 %0, %1, %2" : "=v"(up.w[3]) : "v"(p1[2]), "v"(p1[3]));
      short8_t bv = *(const short8_t*)(Vt + r * 328 + mb + 8 * g);
      accPV = __builtin_amdgcn_mfma_f32_16x16x32_bf16(up.s, bv, accPV, 0, 0, 0);
      short8_t aj = *(const short8_t*)(adjTb + (n0 + r) * 320 + mb + 8 * g);
      accG = __builtin_amdgcn_mfma_f32_16x16x32_bf16(aj, bv, accG, 0, 0, 0);
    }
    dn += __shfl_xor(dn, 16);
    dn += __shfl_xor(dn, 32);
#pragma unroll
    for (int i = 0; i < 4; ++i) {
      int n = n0 + 4 * g + i;
      float di = __shfl(dn, 4 * g + i);
      if (n < NN) y5[ysl + n * 16 + r] = accPV[i] / di + accG[i];
    }
  }
}

// ---------------- layernorm over (D,N) per (b,l), 3-kernel split ----------------

__global__ __launch_bounds__(192) void k_lnstat(
    const float* __restrict__ in, float* __restrict__ pS, float* __restrict__ pSS) {
  const int c = blockIdx.x, b = blockIdx.y, t = threadIdx.x;
  const int dn0 = c * LN_DNC;
  const int dn1 = min(dn0 + LN_DNC, DN);
  const int cnt = (dn1 - dn0) * LNUM;
  const float* p = in + (size_t)b * SZB + (size_t)dn0 * LNUM;
  float s = 0.f, ss = 0.f;
  for (int i = t; i < cnt; i += 192) {
    float v = p[i];
    s += v; ss += v * v;
  }
  __shared__ float rs[192], rss[192];
  rs[t] = s; rss[t] = ss;
  __syncthreads();
  if (t < 12) {
    float S = 0.f, SS = 0.f;
    for (int j = t; j < 192; j += 12) { S += rs[j]; SS += rss[j]; }
    pS[(b * LN_CH + c) * 12 + t] = S;
    pSS[(b * LN_CH + c) * 12 + t] = SS;
  }
}

__global__ __launch_bounds__(96) void k_lnfin(
    const float* __restrict__ pS, const float* __restrict__ pSS,
    float* __restrict__ meanp, float* __restrict__ rstdp) {
  const int t = threadIdx.x;
  const int b = t / 12, l = t % 12;
  float S = 0.f, SS = 0.f;
  for (int c = 0; c < LN_CH; ++c) {
    S += pS[(b * LN_CH + c) * 12 + l];
    SS += pSS[(b * LN_CH + c) * 12 + l];
  }
  float mu = S * (1.f / DN);
  float var = SS * (1.f / DN) - mu * mu;
  meanp[t] = mu;
  rstdp[t] = rsqrtf(fmaxf(var, 0.f) + 1e-5f);
}

__global__ __launch_bounds__(256) void k_lnapply(
    const float* __restrict__ in, const float* __restrict__ meanp,
    const float* __restrict__ rstdp, float* __restrict__ outp) {
  const int i0 = (blockIdx.x * 256 + threadIdx.x) * 4;
  float4 v = *(const float4*)(in + i0);
  const int b = (int)((unsigned)i0 / (unsigned)SZB);
  const int rr = i0 - b * SZB;
  const int l0 = rr % 12;
  const float* mp = meanp + b * 12;
  const float* rp = rstdp + b * 12;
  float4 o;
  o.x = (v.x - mp[l0 + 0]) * rp[l0 + 0];
  o.y = (v.y - mp[l0 + 1]) * rp[l0 + 1];
  o.z = (v.z - mp[l0 + 2]) * rp[l0 + 2];
  o.w = (v.w - mp[l0 + 3]) * rp[l0 + 3];
  *(float4*)(outp + i0) = o;
}

}  // namespace

extern "C" void kernel_launch(void* const* d_in, const int* in_sizes, int n_in,
                              void* d_out, int out_size, void* d_ws, size_t ws_size,
                              hipStream_t stream) {
  (void)in_sizes; (void)n_in; (void)out_size; (void)ws_size;
  const float* x    = (const float*)d_in[0];
  const float* Wq   = (const float*)d_in[1];
  const float* bq   = (const float*)d_in[2];
  const float* Wv   = (const float*)d_in[3];
  const float* bv   = (const float*)d_in[4];
  const float* Wc   = (const float*)d_in[5];
  const float* bc   = (const float*)d_in[6];
  const float* Wx   = (const float*)d_in[7];
  const float* bx   = (const float*)d_in[8];
  const float* Wg1  = (const float*)d_in[9];
  const float* bg1  = (const float*)d_in[10];
  const float* Wg2  = (const float*)d_in[11];
  const float* bg2  = (const float*)d_in[12];
  const float* Wg3  = (const float*)d_in[13];
  const float* bg3  = (const float*)d_in[14];
  const float* memb = (const float*)d_in[15];
  const float* mimp = (const float*)d_in[16];
  const float* A1   = (const float*)d_in[17];
  const float* a1b  = (const float*)d_in[18];
  const float* A2   = (const float*)d_in[19];
  const float* a2b  = (const float*)d_in[20];
  const float* wgt  = (const float*)d_in[21];
  const float* bia  = (const float*)d_in[22];
  const float* nv1  = (const float*)d_in[23];
  const float* nv2  = (const float*)d_in[24];
  const float* sws  = (const float*)d_in[25];

  float* ws = (float*)d_ws;
  float* P0 = ws;                        // also hosts q5b (bf16) before MODE1
  float* P1 = ws + (size_t)SZ;           // also hosts vt5b (bf16) before MODE2
  float* P2 = ws + 2 * (size_t)SZ;       // y5 fp32
  float* sm = ws + 3 * (size_t)SZ;
  float* s1 = sm;
  float* s2 = sm + ADJN;
  float* s3 = sm + 2 * ADJN;
  float* adjT_f = sm + 3 * ADJN;            // 51200 floats = 320*320 bf16
  float* memw = adjT_f + 51200;
  float* WbSlot = memw + 32;                // 7*16384 floats reserved; bf16 W uses half
  float* pS   = WbSlot + 7 * 16384;
  float* pSS  = pS + BB * LN_CH * 12;
  float* meanp = pSS + BB * LN_CH * 12;
  float* rstdp = meanp + 96;
  float* avgb  = rstdp + 96;                // 1024 floats

  unsigned short* q5b  = (unsigned short*)P0;
  unsigned short* vt5b = (unsigned short*)P1;
  unsigned short* adjTb = (unsigned short*)adjT_f;
  unsigned short* Wb7  = (unsigned short*)WbSlot;   // 7 x [128][128] bf16, layout [o][c]

  k_cvtW<<<224, 256, 0, stream>>>(Wq, Wv, Wx, Wc, Wg1, Wg2, Wg3, (unsigned int*)Wb7);
  k_s1<<<NN, 320, 0, stream>>>(nv1, nv2, s1);
  k_smm<<<NN, 320, 0, stream>>>(s1, s1, s2);
  k_smm<<<NN, 320, 0, stream>>>(s2, s1, s3);
  k_adjT<<<(320 * 160 + 255) / 256, 256, 0, stream>>>(s1, s2, s3, sws, (unsigned int*)adjTb);
  k_avg<<<BB * DCH / 4, 256, 0, stream>>>(x, avgb);
  k_memw2<<<BB, 128, 0, stream>>>(avgb, A1, a1b, A2, a2b, mimp, memw);

  // q5b, vt5b projections (bf16 MFMA, attention layouts)
  k_convm<0><<<dim3(58, 1, BB), 256, 0, stream>>>(Wb7 + 0 * 16384, x, bq, q5b, nullptr, nullptr, nullptr);
  k_convm<4><<<dim3(58, 1, BB), 256, 0, stream>>>(Wb7 + 1 * 16384, x, bv, vt5b, nullptr, nullptr, nullptr);

  // MFMA attention + graph -> y5 (P2)
  k_attn_mfma<<<dim3(LNUM, HH, BB), 256, 0, stream>>>(q5b, vt5b, memb, memw, adjTb, P2);

  // t = y + conv(y, Wx, bx): y5 input, standard output (P0; q5b dead)
  k_convm<1><<<dim3(58, 1, BB), 256, 0, stream>>>(Wb7 + 2 * 16384, P2, bx, P0, nullptr, nullptr, nullptr);
  // z_in = relu(conv(t, Wc, bc))*(w+1) + bias + x  (P1; vt5b dead)
  k_convm<2><<<dim3(58, 1, BB), 256, 0, stream>>>(Wb7 + 3 * 16384, P0, bc, P1, wgt, bia, x);

  // z = ln12(z_in)  (P1 -> P2)
  k_lnstat<<<dim3(LN_CH, BB), 192, 0, stream>>>(P1, pS, pSS);
  k_lnfin<<<1, 96, 0, stream>>>(pS, pSS, meanp, rstdp);
  k_lnapply<<<SZ / 1024, 256, 0, stream>>>(P1, meanp, rstdp, P2);

  // g = conv(z,Wg1,bg1)*sigmoid(conv(z,Wg2,bg2))  (P2 -> P0)
  k_convm_glu<<<dim3(58, 1, BB), 256, 0, stream>>>(Wb7 + 4 * 16384, Wb7 + 5 * 16384, P2, bg1, bg2, P0);
  // t2 = (conv(g,Wg3,bg3) + z)*(w+1) + bias  (P0 -> P1, z from P2)
  k_convm<3><<<dim3(58, 1, BB), 256, 0, stream>>>(Wb7 + 6 * 16384, P0, bg3, P1, wgt, bia, P2);

  // out = ln12(t2)
  k_lnstat<<<dim3(LN_CH, BB), 192, 0, stream>>>(P1, pS, pSS);
  k_lnfin<<<1, 96, 0, stream>>>(pS, pSS, meanp, rstdp);
  k_lnapply<<<SZ / 1024, 256, 0, stream>>>(P1, meanp, rstdp, (float*)d_out);
}

// Round 7
// 233.819 us; speedup vs baseline: 2.8249x; 1.1144x over previous
//
#include <hip/hip_runtime.h>

namespace {

constexpr int NN   = 307;
constexpr int LNUM = 12;
constexpr int SP   = NN * LNUM;        // 3684
constexpr int DCH  = 128;
constexpr int HH   = 8;
constexpr int DK   = 16;
constexpr int BB   = 8;
constexpr int SZB  = DCH * SP;         // 471552 per batch
constexpr int SZ   = BB * SZB;         // 3772416 total
constexpr int ADJN = NN * NN;          // 94249
constexpr int DN   = DCH * NN;         // 39296 (layernorm group size)
constexpr int LN_CH = 48;              // chunks for std-layout lnstat
constexpr int LN_DNC = 819;
constexpr int LN_RCH = 58;             // chunks for R-layout lnstat (64 s each)
constexpr int MST  = HH * LNUM * NN * DK;  // mem_bank per-slot stride

typedef __attribute__((ext_vector_type(8))) short short8_t;
typedef __attribute__((ext_vector_type(4))) float f32x4;

__device__ inline unsigned short f2bf(float f) {
  unsigned int u = __builtin_bit_cast(unsigned int, f);
  unsigned int r = (u + 0x7FFFu + ((u >> 16) & 1u)) >> 16;
  return (unsigned short)r;
}
__device__ inline float bf2f(unsigned short h) {
  unsigned int u = ((unsigned int)h) << 16;
  return __builtin_bit_cast(float, u);
}

// sigma-permuted column position for m within the V / adjT buffers
__device__ __host__ inline int posm(int m) {
  int q = (m & 15) >> 2, sub = (m >> 4) & 1, i = m & 3;
  return (m & ~31) + 8 * q + 4 * sub + i;
}

// ---------------- small prep kernels ----------------

// Convert all 7 [128][128] weight matrices to bf16, layout [o][c].
__global__ __launch_bounds__(256) void k_cvtW(
    const float* __restrict__ W0, const float* __restrict__ W1,
    const float* __restrict__ W2, const float* __restrict__ W3,
    const float* __restrict__ W4, const float* __restrict__ W5,
    const float* __restrict__ W6, unsigned int* __restrict__ Wb) {
  const float* srcs[7] = {W0, W1, W2, W3, W4, W5, W6};
  int idx = blockIdx.x * 256 + threadIdx.x;   // 0..57343
  int w = idx >> 13, off = idx & 8191;
  const float* s = srcs[w];
  float v0 = s[off * 2], v1 = s[off * 2 + 1];
  unsigned int pk;
  asm("v_cvt_pk_bf16_f32 %0, %1, %2" : "=v"(pk) : "v"(v0), "v"(v1));
  Wb[idx] = pk;
}

__global__ __launch_bounds__(320) void k_s1(
    const float* __restrict__ nv1, const float* __restrict__ nv2,
    float* __restrict__ out) {
  __shared__ float red[512];
  __shared__ float rowA[10];
  const int i = blockIdx.x, j = threadIdx.x;
  if (j < 10) rowA[j] = nv1[i * 10 + j];
  __syncthreads();
  float val = 0.f;
  if (j < NN) {
#pragma unroll
    for (int k = 0; k < 10; ++k) val += rowA[k] * nv2[k * NN + j];
    val = fmaxf(val, 0.f);
  }
  red[j] = (j < NN) ? val : -3.4e38f;
  if (j < 192) red[j + 320] = -3.4e38f;
  __syncthreads();
  for (int s = 256; s >= 1; s >>= 1) {
    if (j < s) red[j] = fmaxf(red[j], red[j + s]);
    __syncthreads();
  }
  float mx = red[0];
  __syncthreads();
  float e = (j < NN) ? __expf(val - mx) : 0.f;
  red[j] = e;
  if (j < 192) red[j + 320] = 0.f;
  __syncthreads();
  for (int s = 256; s >= 1; s >>= 1) {
    if (j < s) red[j] += red[j + s];
    __syncthreads();
  }
  if (j < NN) out[i * NN + j] = e / red[0];
}

__global__ __launch_bounds__(320) void k_smm(
    const float* __restrict__ Sa, const float* __restrict__ Sb,
    float* __restrict__ out) {
  __shared__ float red[512];
  __shared__ float rowA[320];
  const int i = blockIdx.x, j = threadIdx.x;
  if (j < NN) rowA[j] = Sa[i * NN + j];
  __syncthreads();
  float val = 0.f;
  if (j < NN) {
    for (int k = 0; k < NN; ++k) val += rowA[k] * Sb[k * NN + j];
  }
  red[j] = (j < NN) ? val : -3.4e38f;
  if (j < 192) red[j + 320] = -3.4e38f;
  __syncthreads();
  for (int s = 256; s >= 1; s >>= 1) {
    if (j < s) red[j] = fmaxf(red[j], red[j + s]);
    __syncthreads();
  }
  float mx = red[0];
  __syncthreads();
  float e = (j < NN) ? __expf(val - mx) : 0.f;
  red[j] = e;
  if (j < 192) red[j + 320] = 0.f;
  __syncthreads();
  for (int s = 256; s >= 1; s >>= 1) {
    if (j < s) red[j] += red[j + s];
    __syncthreads();
  }
  if (j < NN) out[i * NN + j] = e / red[0];
}

__global__ __launch_bounds__(256) void k_adjT(
    const float* __restrict__ s1, const float* __restrict__ s2,
    const float* __restrict__ s3, const float* __restrict__ sws,
    unsigned int* __restrict__ adjTw) {
  int idx = blockIdx.x * 256 + threadIdx.x;   // 0 .. 320*160-1
  if (idx >= 320 * 160) return;
  int n = idx / 160, wp = idx - n * 160;
  int pos0 = 2 * wp;
  int bq = pos0 & 31;
  int g = bq >> 3, sub = (bq >> 2) & 1, i = bq & 3;
  int m0 = (pos0 & ~31) + sub * 16 + 4 * g + i;
  float w0 = sws[0], w1 = sws[1], w2 = sws[2];
  float mm = fmaxf(w0, fmaxf(w1, w2));
  float e0 = __expf(w0 - mm), e1 = __expf(w1 - mm), e2 = __expf(w2 - mm);
  float inv = 1.f / (e0 + e1 + e2);
  e0 *= inv; e1 *= inv; e2 *= inv;
  float v0 = 0.f, v1 = 0.f;
  if (n < NN) {
    if (m0 < NN)     v0 = e0 * s1[m0 * NN + n] + e1 * s2[m0 * NN + n] + e2 * s3[m0 * NN + n];
    if (m0 + 1 < NN) v1 = e0 * s1[(m0 + 1) * NN + n] + e1 * s2[(m0 + 1) * NN + n] + e2 * s3[(m0 + 1) * NN + n];
  }
  adjTw[n * 160 + wp] = (unsigned int)f2bf(v0) | ((unsigned int)f2bf(v1) << 16);
}

__global__ __launch_bounds__(256) void k_avg(
    const float* __restrict__ x, float* __restrict__ avg) {
  const int row = blockIdx.x * 4 + (threadIdx.x >> 6);
  const int lane = threadIdx.x & 63;
  const float* p = x + (size_t)row * SP;
  float s = 0.f;
  for (int i = lane; i < SP / 4; i += 64) {
    float4 v = *(const float4*)(p + i * 4);
    s += v.x + v.y + v.z + v.w;
  }
  s += __shfl_xor(s, 1);  s += __shfl_xor(s, 2);  s += __shfl_xor(s, 4);
  s += __shfl_xor(s, 8);  s += __shfl_xor(s, 16); s += __shfl_xor(s, 32);
  if (lane == 0) avg[row] = s * (1.f / SP);
}

__global__ __launch_bounds__(128) void k_memw2(
    const float* __restrict__ avgg, const float* __restrict__ A1,
    const float* __restrict__ a1b, const float* __restrict__ A2,
    const float* __restrict__ a2b, const float* __restrict__ mimp,
    float* __restrict__ memw) {
  const int b = blockIdx.x, t = threadIdx.x;
  __shared__ float avg[128];
  __shared__ float hbuf[64];
  __shared__ float lg[4];
  avg[t] = avgg[b * 128 + t];
  __syncthreads();
  if (t < 64) {
    float a = a1b[t];
    for (int d = 0; d < 128; ++d) a += avg[d] * A1[d * 64 + t];
    hbuf[t] = fmaxf(a, 0.f);
  }
  __syncthreads();
  if (t < 4) {
    float a = a2b[t];
    for (int j = 0; j < 64; ++j) a += hbuf[j] * A2[j * 4 + t];
    lg[t] = a;
  }
  __syncthreads();
  if (t == 0) {
    float mx = fmaxf(fmaxf(lg[0], lg[1]), fmaxf(lg[2], lg[3]));
    float e[4]; float se = 0.f;
    for (int m = 0; m < 4; ++m) { e[m] = __expf(lg[m] - mx); se += e[m]; }
    float w[4]; float mx2 = -3.4e38f;
    for (int m = 0; m < 4; ++m) { w[m] = mimp[m] * (e[m] / se); mx2 = fmaxf(mx2, w[m]); }
    float se2 = 0.f;
    for (int m = 0; m < 4; ++m) { e[m] = __expf(w[m] - mx2); se2 += e[m]; }
    for (int m = 0; m < 4; ++m) memw[b * 4 + m] = e[m] / se2;
  }
}

// ---------------- MFMA 1x1 conv, std fp32 input (q/v projections) ----------------
// MODE 0: out = relu(acc+b) -> q5b bf16 [sl][n][16]
// MODE 4: out = relu(acc+b) -> vt5b bf16 [sl][16][posm(n)]
template <int MODE>
__global__ __launch_bounds__(256) void k_convm(
    const unsigned short* __restrict__ Wbf, const float* __restrict__ X,
    const float* __restrict__ bvec, unsigned short* __restrict__ outb) {
  __shared__ unsigned short Xs[64 * 128];
  __shared__ unsigned short Ws[128 * 128];
  const int sBase = blockIdx.x * 64;
  const int b = blockIdx.z;
  const int t = threadIdx.x;

  {
    const int u = t & 63, cp = t >> 6;
    const int s = sBase + u;
    const bool in = s < SP;
#pragma unroll
    for (int it = 0; it < 16; ++it) {
      int c0 = it * 8 + cp * 2;
      float v0 = 0.f, v1 = 0.f;
      if (in) {
        v0 = X[(size_t)(b * DCH + c0) * SP + s];
        v1 = X[(size_t)(b * DCH + c0 + 1) * SP + s];
      }
      unsigned int pk;
      asm("v_cvt_pk_bf16_f32 %0, %1, %2" : "=v"(pk) : "v"(v0), "v"(v1));
      *(unsigned int*)((char*)Xs + u * 256 + ((2 * c0) ^ ((u & 7) << 4))) = pk;
    }
  }
  {
    const int o = t >> 1, half = t & 1;
    const unsigned short* src = Wbf + o * 128 + half * 64;
#pragma unroll
    for (int j = 0; j < 8; ++j) {
      short8_t v = *(const short8_t*)(src + j * 8);
      *(short8_t*)((char*)Ws + o * 256 + ((half * 128 + j * 16) ^ ((o & 7) << 4))) = v;
    }
  }
  __syncthreads();

  const int wave = t >> 6, lane = t & 63;
  const int r = lane & 15, g = lane >> 4;
  const int swz = (r & 7) << 4;

  short8_t xa[4];
#pragma unroll
  for (int kk = 0; kk < 4; ++kk)
    xa[kk] = *(const short8_t*)((const char*)Xs + (wave * 16 + r) * 256 + ((kk * 64 + g * 16) ^ swz));

  const f32x4 zf = {0.f, 0.f, 0.f, 0.f};
  f32x4 acc[8];
#pragma unroll
  for (int ot = 0; ot < 8; ++ot) acc[ot] = zf;
#pragma unroll
  for (int ot = 0; ot < 8; ++ot) {
#pragma unroll
    for (int kk = 0; kk < 4; ++kk) {
      short8_t wb = *(const short8_t*)((const char*)Ws + (ot * 16 + r) * 256 + ((kk * 64 + g * 16) ^ swz));
      acc[ot] = __builtin_amdgcn_mfma_f32_16x16x32_bf16(xa[kk], wb, acc[ot], 0, 0, 0);
    }
  }

  const int s0 = sBase + wave * 16 + 4 * g;
  if (s0 >= SP) return;

  if constexpr (MODE == 0) {
#pragma unroll
    for (int ot = 0; ot < 8; ++ot) {
      float bv = bvec[ot * 16 + r];
#pragma unroll
      for (int i = 0; i < 4; ++i) {
        int s = s0 + i, n = s / 12, l2 = s - n * 12;
        outb[((b * 8 + ot) * 12 + l2) * 5120 + n * 16 + r] = f2bf(fmaxf(acc[ot][i] + bv, 0.f));
      }
    }
  } else {  // MODE 4
#pragma unroll
    for (int ot = 0; ot < 8; ++ot) {
      float bv = bvec[ot * 16 + r];
#pragma unroll
      for (int i = 0; i < 4; ++i) {
        int s = s0 + i, n = s / 12, l2 = s - n * 12;
        outb[((b * 8 + ot) * 12 + l2) * 5120 + r * 320 + posm(n)] = f2bf(fmaxf(acc[ot][i] + bv, 0.f));
      }
    }
  }
}

// ---------------- MFMA 1x1 conv, bf16 R-layout input [s][c] ----------------
// MODE 1: out = acc + b + y(residual from LDS tile) -> bf16 R
// MODE 2: out = relu(acc+b)*(aw+1) + ab + x(std fp32)  -> bf16 R
// MODE 3: out = (acc + b + LN(z_in))*(aw+1) + ab       -> std fp32
template <int MODE>
__global__ __launch_bounds__(256) void k_convr(
    const unsigned short* __restrict__ Wbf, const unsigned short* __restrict__ Xr,
    const float* __restrict__ bvec, void* __restrict__ outv,
    const float* __restrict__ aw, const float* __restrict__ ab,
    const float* __restrict__ axf, const unsigned short* __restrict__ zr,
    const float* __restrict__ meanp, const float* __restrict__ rstdp) {
  __shared__ unsigned short Xs[64 * 128];
  __shared__ unsigned short Ws[128 * 128];
  const int sBase = blockIdx.x * 64;
  const int b = blockIdx.z;
  const int t = threadIdx.x;

  // stage bf16 R rows -> swizzled LDS (4 x short8 per thread, no cvt)
  {
    const int sl = t >> 2, q = t & 3;
    const int s = sBase + sl;
    const short8_t z8 = {0, 0, 0, 0, 0, 0, 0, 0};
    const unsigned short* row = Xr + (((size_t)b * SP + s) << 7);
#pragma unroll
    for (int j = 0; j < 4; ++j) {
      int cb = 16 * (4 * j + q);
      short8_t v = (s < SP) ? *(const short8_t*)((const char*)row + cb) : z8;
      *(short8_t*)((char*)Xs + sl * 256 + (cb ^ ((sl & 7) << 4))) = v;
    }
  }
  {
    const int o = t >> 1, half = t & 1;
    const unsigned short* src = Wbf + o * 128 + half * 64;
#pragma unroll
    for (int j = 0; j < 8; ++j) {
      short8_t v = *(const short8_t*)(src + j * 8);
      *(short8_t*)((char*)Ws + o * 256 + ((half * 128 + j * 16) ^ ((o & 7) << 4))) = v;
    }
  }
  __syncthreads();

  const int wave = t >> 6, lane = t & 63;
  const int r = lane & 15, g = lane >> 4;
  const int swz = (r & 7) << 4;

  short8_t xa[4];
#pragma unroll
  for (int kk = 0; kk < 4; ++kk)
    xa[kk] = *(const short8_t*)((const char*)Xs + (wave * 16 + r) * 256 + ((kk * 64 + g * 16) ^ swz));

  const f32x4 zf = {0.f, 0.f, 0.f, 0.f};
  f32x4 acc[8];
#pragma unroll
  for (int ot = 0; ot < 8; ++ot) acc[ot] = zf;
#pragma unroll
  for (int ot = 0; ot < 8; ++ot) {
#pragma unroll
    for (int kk = 0; kk < 4; ++kk) {
      short8_t wb = *(const short8_t*)((const char*)Ws + (ot * 16 + r) * 256 + ((kk * 64 + g * 16) ^ swz));
      acc[ot] = __builtin_amdgcn_mfma_f32_16x16x32_bf16(xa[kk], wb, acc[ot], 0, 0, 0);
    }
  }

  const int s0 = sBase + wave * 16 + 4 * g;
  if (s0 >= SP) return;

  if constexpr (MODE == 1) {
    unsigned short* outR = (unsigned short*)outv;
#pragma unroll
    for (int ot = 0; ot < 8; ++ot) {
      int o = ot * 16 + r;
      float bv = bvec[o];
#pragma unroll
      for (int i = 0; i < 4; ++i) {
        int u = wave * 16 + 4 * g + i;
        float y = bf2f(*(const unsigned short*)((const char*)Xs + u * 256 + ((2 * o) ^ ((u & 7) << 4))));
        outR[(((size_t)b * SP + s0 + i) << 7) + o] = f2bf(acc[ot][i] + bv + y);
      }
    }
  } else if constexpr (MODE == 2) {
    unsigned short* outR = (unsigned short*)outv;
#pragma unroll
    for (int ot = 0; ot < 8; ++ot) {
      int o = ot * 16 + r;
      float bv = bvec[o];
      float4 w4 = *(const float4*)(aw + o * SP + s0);
      float4 b4 = *(const float4*)(ab + o * SP + s0);
      float4 x4 = *(const float4*)(axf + (size_t)(b * DCH + o) * SP + s0);
#pragma unroll
      for (int i = 0; i < 4; ++i) {
        float rr = fmaxf(acc[ot][i] + bv, 0.f);
        float val = rr * ((&w4.x)[i] + 1.f) + (&b4.x)[i] + (&x4.x)[i];
        outR[(((size_t)b * SP + s0 + i) << 7) + o] = f2bf(val);
      }
    }
  } else {  // MODE 3
    float* out = (float*)outv;
    float m4[4], r4[4];
#pragma unroll
    for (int i = 0; i < 4; ++i) {
      int l = (s0 + i) % 12;
      m4[i] = meanp[b * 12 + l];
      r4[i] = rstdp[b * 12 + l];
    }
#pragma unroll
    for (int ot = 0; ot < 8; ++ot) {
      int o = ot * 16 + r;
      float bv = bvec[o];
      float4 w4 = *(const float4*)(aw + o * SP + s0);
      float4 b4 = *(const float4*)(ab + o * SP + s0);
      float4 val;
#pragma unroll
      for (int i = 0; i < 4; ++i) {
        float zin = bf2f(zr[(((size_t)b * SP + s0 + i) << 7) + o]);
        float z = (zin - m4[i]) * r4[i];
        float tt = acc[ot][i] + bv + z;
        (&val.x)[i] = tt * ((&w4.x)[i] + 1.f) + (&b4.x)[i];
      }
      *(float4*)(out + (size_t)(b * DCH + o) * SP + s0) = val;
    }
  }
}

// GLU conv: input z_in bf16 R-layout, LN applied inline during staging.
__global__ __launch_bounds__(256) void k_convr_glu(
    const unsigned short* __restrict__ Wb1, const unsigned short* __restrict__ Wb2,
    const unsigned short* __restrict__ Zr, const float* __restrict__ b1,
    const float* __restrict__ b2, const float* __restrict__ meanp,
    const float* __restrict__ rstdp, unsigned short* __restrict__ outR) {
  __shared__ unsigned short Xs[64 * 128];
  __shared__ unsigned short Ws[128 * 128];
  const int sBase = blockIdx.x * 64;
  const int b = blockIdx.z;
  const int t = threadIdx.x;

  {
    const int sl = t >> 2, q = t & 3;
    const int s = sBase + sl;
    float m = 0.f, rr = 0.f;
    if (s < SP) { int l = s % 12; m = meanp[b * 12 + l]; rr = rstdp[b * 12 + l]; }
    const short8_t z8 = {0, 0, 0, 0, 0, 0, 0, 0};
    const unsigned short* row = Zr + (((size_t)b * SP + s) << 7);
#pragma unroll
    for (int j = 0; j < 4; ++j) {
      int cb = 16 * (4 * j + q);
      short8_t v = (s < SP) ? *(const short8_t*)((const char*)row + cb) : z8;
      union { unsigned int w[4]; short8_t s8; } u;
#pragma unroll
      for (int k2 = 0; k2 < 4; ++k2) {
        float f0 = (bf2f((unsigned short)v[2 * k2]) - m) * rr;
        float f1 = (bf2f((unsigned short)v[2 * k2 + 1]) - m) * rr;
        asm("v_cvt_pk_bf16_f32 %0, %1, %2" : "=v"(u.w[k2]) : "v"(f0), "v"(f1));
      }
      *(short8_t*)((char*)Xs + sl * 256 + (cb ^ ((sl & 7) << 4))) = u.s8;
    }
  }
  const int o = t >> 1, half = t & 1;
  {
    const unsigned short* src = Wb1 + o * 128 + half * 64;
#pragma unroll
    for (int j = 0; j < 8; ++j) {
      short8_t v = *(const short8_t*)(src + j * 8);
      *(short8_t*)((char*)Ws + o * 256 + ((half * 128 + j * 16) ^ ((o & 7) << 4))) = v;
    }
  }
  __syncthreads();

  const int wave = t >> 6, lane = t & 63;
  const int r = lane & 15, g = lane >> 4;
  const int swz = (r & 7) << 4;

  short8_t xa[4];
#pragma unroll
  for (int kk = 0; kk < 4; ++kk)
    xa[kk] = *(const short8_t*)((const char*)Xs + (wave * 16 + r) * 256 + ((kk * 64 + g * 16) ^ swz));

  const f32x4 zf = {0.f, 0.f, 0.f, 0.f};
  f32x4 acc1[8], acc2[8];
#pragma unroll
  for (int ot = 0; ot < 8; ++ot) { acc1[ot] = zf; acc2[ot] = zf; }
#pragma unroll
  for (int ot = 0; ot < 8; ++ot) {
#pragma unroll
    for (int kk = 0; kk < 4; ++kk) {
      short8_t wb = *(const short8_t*)((const char*)Ws + (ot * 16 + r) * 256 + ((kk * 64 + g * 16) ^ swz));
      acc1[ot] = __builtin_amdgcn_mfma_f32_16x16x32_bf16(xa[kk], wb, acc1[ot], 0, 0, 0);
    }
  }
  __syncthreads();
  {
    const unsigned short* src = Wb2 + o * 128 + half * 64;
#pragma unroll
    for (int j = 0; j < 8; ++j) {
      short8_t v = *(const short8_t*)(src + j * 8);
      *(short8_t*)((char*)Ws + o * 256 + ((half * 128 + j * 16) ^ ((o & 7) << 4))) = v;
    }
  }
  __syncthreads();
#pragma unroll
  for (int ot = 0; ot < 8; ++ot) {
#pragma unroll
    for (int kk = 0; kk < 4; ++kk) {
      short8_t wb = *(const short8_t*)((const char*)Ws + (ot * 16 + r) * 256 + ((kk * 64 + g * 16) ^ swz));
      acc2[ot] = __builtin_amdgcn_mfma_f32_16x16x32_bf16(xa[kk], wb, acc2[ot], 0, 0, 0);
    }
  }

  const int s0 = sBase + wave * 16 + 4 * g;
  if (s0 >= SP) return;
#pragma unroll
  for (int ot = 0; ot < 8; ++ot) {
    int oo = ot * 16 + r;
    float bb1 = b1[oo], bb2 = b2[oo];
#pragma unroll
    for (int i = 0; i < 4; ++i) {
      float v1 = acc1[ot][i] + bb1;
      float v2 = acc2[ot][i] + bb2;
      outR[(((size_t)b * SP + s0 + i) << 7) + oo] = f2bf(v1 / (1.f + __expf(-v2)));
    }
  }
}

// ---------------- MFMA attention + graph diffusion ----------------
__global__ __launch_bounds__(256) void k_attn_mfma(
    const unsigned short* __restrict__ q5b, const unsigned short* __restrict__ vt5b,
    const float* __restrict__ memb, const float* __restrict__ memw,
    const unsigned short* __restrict__ adjTb, unsigned short* __restrict__ yR) {
  __shared__ unsigned short Mb[320 * 24];
  __shared__ unsigned short Vt[16 * 328];
  const int l = blockIdx.x, h = blockIdx.y, b = blockIdx.z;
  const int t = threadIdx.x;
  const int slice = (b * HH + h) * LNUM + l;
  const int msl = (h * LNUM + l) * NN * DK;
  const float w0 = memw[b * 4 + 0], w1 = memw[b * 4 + 1];
  const float w2 = memw[b * 4 + 2], w3 = memw[b * 4 + 3];

  for (int idx = t; idx < 640; idx += 256) {
    int n = idx >> 1, h8 = idx & 1;
    float v[8];
    if (n < NN) {
      int off = msl + n * 16 + h8 * 8;
      const float4* p0 = (const float4*)(memb + off);
      const float4* p1 = (const float4*)(memb + MST + off);
      const float4* p2 = (const float4*)(memb + 2 * MST + off);
      const float4* p3 = (const float4*)(memb + 3 * MST + off);
      float4 a0 = p0[0], a1 = p1[0], a2 = p2[0], a3 = p3[0];
      float4 c0 = p0[1], c1 = p1[1], c2 = p2[1], c3 = p3[1];
      v[0] = w0 * a0.x + w1 * a1.x + w2 * a2.x + w3 * a3.x;
      v[1] = w0 * a0.y + w1 * a1.y + w2 * a2.y + w3 * a3.y;
      v[2] = w0 * a0.z + w1 * a1.z + w2 * a2.z + w3 * a3.z;
      v[3] = w0 * a0.w + w1 * a1.w + w2 * a2.w + w3 * a3.w;
      v[4] = w0 * c0.x + w1 * c1.x + w2 * c2.x + w3 * c3.x;
      v[5] = w0 * c0.y + w1 * c1.y + w2 * c2.y + w3 * c3.y;
      v[6] = w0 * c0.z + w1 * c1.z + w2 * c2.z + w3 * c3.z;
      v[7] = w0 * c0.w + w1 * c1.w + w2 * c2.w + w3 * c3.w;
    } else {
#pragma unroll
      for (int j = 0; j < 8; ++j) v[j] = 0.f;
    }
    union { unsigned int w[4]; short8_t s; } u;
#pragma unroll
    for (int j = 0; j < 4; ++j)
      u.w[j] = (unsigned int)f2bf(v[2 * j]) | ((unsigned int)f2bf(v[2 * j + 1]) << 16);
    *(short8_t*)(Mb + n * 24 + h8 * 8) = u.s;
  }
  {
    const unsigned short* vsl = vt5b + slice * (16 * 320);
    for (int c = t; c < 640; c += 256) {
      int row = c / 40, ch = c - row * 40;
      short8_t vv = *(const short8_t*)(vsl + row * 320 + ch * 8);
      *(short8_t*)(Vt + row * 328 + ch * 8) = vv;
    }
  }
  __syncthreads();
  // Zero sigma-columns of Vt never written by the v-conv (n=307..319):
  // stale workspace bits would otherwise reach the PV MFMA (0*NaN = NaN).
  for (int idx = t; idx < 16 * 13; idx += 256) {
    int row = idx / 13, j = idx - row * 13;
    Vt[row * 328 + posm(NN + j)] = 0;
  }
  __syncthreads();

  const int wave = t >> 6, lane = t & 63;
  const int r = lane & 15, g = lane >> 4;
  const f32x4 zf = {0.f, 0.f, 0.f, 0.f};
  float maskv[4];
#pragma unroll
  for (int i = 0; i < 4; ++i) maskv[i] = (4 * g + i < 3) ? 1.f : 0.f;
  constexpr float CEXP = 0.25f * 1.44269504089f;

  for (int rt5 = 0; rt5 < 5; ++rt5) {
    const int n0 = (wave * 5 + rt5) * 16;
    short8_t bq = {0, 0, 0, 0, 0, 0, 0, 0};
    if (g < 2 && n0 + r < NN) bq = *(const short8_t*)(q5b + (slice * 320 + n0 + r) * 16 + 8 * g);
    f32x4 accPV = zf, accG = zf;
    float dn = 0.f;
#pragma unroll 2
    for (int mt = 0; mt < 10; ++mt) {
      const int mb = mt * 32;
      short8_t am0 = {0, 0, 0, 0, 0, 0, 0, 0}, am1 = am0;
      if (g < 2) {
        am0 = *(const short8_t*)(Mb + (mb + r) * 24 + 8 * g);
        am1 = *(const short8_t*)(Mb + (mb + 16 + r) * 24 + 8 * g);
      }
      f32x4 s0 = __builtin_amdgcn_mfma_f32_16x16x32_bf16(am0, bq, zf, 0, 0, 0);
      f32x4 s1 = __builtin_amdgcn_mfma_f32_16x16x32_bf16(am1, bq, zf, 0, 0, 0);
      float p0[4], p1[4];
#pragma unroll
      for (int i = 0; i < 4; ++i) {
        p0[i] = __builtin_amdgcn_exp2f(s0[i] * CEXP);
        p1[i] = __builtin_amdgcn_exp2f(s1[i] * CEXP);
      }
      if (mt == 9) {
#pragma unroll
        for (int i = 0; i < 4; ++i) p1[i] *= maskv[i];
      }
      dn += p0[0] + p0[1] + p0[2] + p0[3] + p1[0] + p1[1] + p1[2] + p1[3];
      union { unsigned int w[4]; short8_t s; } up;
      asm("v_cvt_pk_bf16_f32 %0, %1, %2" : "=v"(up.w[0]) : "v"(p0[0]), "v"(p0[1]));
      asm("v_cvt_pk_bf16_f32 %0, %1, %2" : "=v"(up.w[1]) : "v"(p0[2]), "v"(p0[3]));
      asm("v_cvt_pk_bf16_f32 %0, %1, %2" : "=v"(up.w[2]) : "v"(p1[0]), "v"(p1[1]));
      asm("v_cvt_pk_bf16_f32 %0, %1, %2" : "=v"(up.w[3]) : "v"(p1[2]), "v"(p1[3]));
      short8_t bv = *(const short8_t*)(Vt + r * 328 + mb + 8 * g);
      accPV = __builtin_amdgcn_mfma_f32_16x16x32_bf16(up.s, bv, accPV, 0, 0, 0);
      short8_t aj = *(const short8_t*)(adjTb + (n0 + r) * 320 + mb + 8 * g);
      accG = __builtin_amdgcn_mfma_f32_16x16x32_bf16(aj, bv, accG, 0, 0, 0);
    }
    dn += __shfl_xor(dn, 16);
    dn += __shfl_xor(dn, 32);
#pragma unroll
    for (int i = 0; i < 4; ++i) {
      int n = n0 + 4 * g + i;
      float di = __shfl(dn, 4 * g + i);
      if (n < NN) {
        // y in bf16 R-layout [b][s=n*12+l][c=h*16+k]
        yR[(((size_t)b * SP + n * 12 + l) << 7) + h * 16 + r] = f2bf(accPV[i] / di + accG[i]);
      }
    }
  }
}

// ---------------- layernorm ----------------

// stats over bf16 R-layout input; chunk = 64 s rows
__global__ __launch_bounds__(256) void k_lnstatR(
    const unsigned short* __restrict__ inR, float* __restrict__ pS, float* __restrict__ pSS) {
  const int chunk = blockIdx.x, b = blockIdx.y, t = threadIdx.x;
  const int sl = t >> 2, q = t & 3;
  const int s = chunk * 64 + sl;
  float sm = 0.f, sq = 0.f;
  if (s < SP) {
    const unsigned short* row = inR + (((size_t)b * SP + s) << 7);
#pragma unroll
    for (int j = 0; j < 4; ++j) {
      short8_t v = *(const short8_t*)((const char*)row + 16 * (4 * j + q));
#pragma unroll
      for (int k = 0; k < 8; ++k) {
        float f = bf2f((unsigned short)v[k]);
        sm += f; sq += f * f;
      }
    }
  }
  __shared__ float ls[256], lq[256];
  ls[t] = sm; lq[t] = sq;
  __syncthreads();
  if (t < 64) {
    ls[t * 4] = ls[t * 4] + ls[t * 4 + 1] + ls[t * 4 + 2] + ls[t * 4 + 3];
    lq[t * 4] = lq[t * 4] + lq[t * 4 + 1] + lq[t * 4 + 2] + lq[t * 4 + 3];
  }
  __syncthreads();
  if (t < 12) {
    float S = 0.f, SS = 0.f;
    for (int u2 = 0; u2 < 64; ++u2) {
      int s2 = chunk * 64 + u2;
      if (s2 < SP && s2 % 12 == t) { S += ls[u2 * 4]; SS += lq[u2 * 4]; }
    }
    pS[(b * LN_RCH + chunk) * 12 + t] = S;
    pSS[(b * LN_RCH + chunk) * 12 + t] = SS;
  }
}

// stats over std fp32 layout (final LN)
__global__ __launch_bounds__(192) void k_lnstat(
    const float* __restrict__ in, float* __restrict__ pS, float* __restrict__ pSS) {
  const int c = blockIdx.x, b = blockIdx.y, t = threadIdx.x;
  const int dn0 = c * LN_DNC;
  const int dn1 = min(dn0 + LN_DNC, DN);
  const int cnt = (dn1 - dn0) * LNUM;
  const float* p = in + (size_t)b * SZB + (size_t)dn0 * LNUM;
  float s = 0.f, ss = 0.f;
  for (int i = t; i < cnt; i += 192) {
    float v = p[i];
    s += v; ss += v * v;
  }
  __shared__ float rs[192], rss[192];
  rs[t] = s; rss[t] = ss;
  __syncthreads();
  if (t < 12) {
    float S = 0.f, SS = 0.f;
    for (int j = t; j < 192; j += 12) { S += rs[j]; SS += rss[j]; }
    pS[(b * LN_CH + c) * 12 + t] = S;
    pSS[(b * LN_CH + c) * 12 + t] = SS;
  }
}

__global__ __launch_bounds__(96) void k_lnfin2(
    const float* __restrict__ pS, const float* __restrict__ pSS,
    float* __restrict__ meanp, float* __restrict__ rstdp, int nch) {
  const int t = threadIdx.x;
  const int b = t / 12, l = t % 12;
  float S = 0.f, SS = 0.f;
  for (int c = 0; c < nch; ++c) {
    S += pS[(b * nch + c) * 12 + l];
    SS += pSS[(b * nch + c) * 12 + l];
  }
  float mu = S * (1.f / DN);
  float var = SS * (1.f / DN) - mu * mu;
  meanp[t] = mu;
  rstdp[t] = rsqrtf(fmaxf(var, 0.f) + 1e-5f);
}

__global__ __launch_bounds__(256) void k_lnapply(
    const float* __restrict__ in, const float* __restrict__ meanp,
    const float* __restrict__ rstdp, float* __restrict__ outp) {
  const int i0 = (blockIdx.x * 256 + threadIdx.x) * 4;
  float4 v = *(const float4*)(in + i0);
  const int b = (int)((unsigned)i0 / (unsigned)SZB);
  const int rr = i0 - b * SZB;
  const int l0 = rr % 12;
  const float* mp = meanp + b * 12;
  const float* rp = rstdp + b * 12;
  float4 o;
  o.x = (v.x - mp[l0 + 0]) * rp[l0 + 0];
  o.y = (v.y - mp[l0 + 1]) * rp[l0 + 1];
  o.z = (v.z - mp[l0 + 2]) * rp[l0 + 2];
  o.w = (v.w - mp[l0 + 3]) * rp[l0 + 3];
  *(float4*)(outp + i0) = o;
}

}  // namespace

extern "C" void kernel_launch(void* const* d_in, const int* in_sizes, int n_in,
                              void* d_out, int out_size, void* d_ws, size_t ws_size,
                              hipStream_t stream) {
  (void)in_sizes; (void)n_in; (void)out_size; (void)ws_size;
  const float* x    = (const float*)d_in[0];
  const float* Wq   = (const float*)d_in[1];
  const float* bq   = (const float*)d_in[2];
  const float* Wv   = (const float*)d_in[3];
  const float* bv   = (const float*)d_in[4];
  const float* Wc   = (const float*)d_in[5];
  const float* bc   = (const float*)d_in[6];
  const float* Wx   = (const float*)d_in[7];
  const float* bx   = (const float*)d_in[8];
  const float* Wg1  = (const float*)d_in[9];
  const float* bg1  = (const float*)d_in[10];
  const float* Wg2  = (const float*)d_in[11];
  const float* bg2  = (const float*)d_in[12];
  const float* Wg3  = (const float*)d_in[13];
  const float* bg3  = (const float*)d_in[14];
  const float* memb = (const float*)d_in[15];
  const float* mimp = (const float*)d_in[16];
  const float* A1   = (const float*)d_in[17];
  const float* a1b  = (const float*)d_in[18];
  const float* A2   = (const float*)d_in[19];
  const float* a2b  = (const float*)d_in[20];
  const float* wgt  = (const float*)d_in[21];
  const float* bia  = (const float*)d_in[22];
  const float* nv1  = (const float*)d_in[23];
  const float* nv2  = (const float*)d_in[24];
  const float* sws  = (const float*)d_in[25];

  float* ws = (float*)d_ws;
  float* P0 = ws;                        // q5b -> tR -> t2(fp32)
  float* P1 = ws + (size_t)SZ;           // vt5b -> zinR
  float* P2 = ws + 2 * (size_t)SZ;       // yR -> gR
  float* sm = ws + 3 * (size_t)SZ;
  float* s1 = sm;
  float* s2 = sm + ADJN;
  float* s3 = sm + 2 * ADJN;
  float* adjT_f = sm + 3 * ADJN;            // 320*320 bf16 = 51200 floats
  float* memw = adjT_f + 51200;
  float* WbSlot = memw + 32;                // 7*16384 floats reserved (bf16 uses half)
  float* pS   = WbSlot + 7 * 16384;         // 8*58*12 = 5568
  float* pSS  = pS + BB * LN_RCH * 12;
  float* meanp = pSS + BB * LN_RCH * 12;    // 96
  float* rstdp = meanp + 96;                // 96
  float* avgb  = rstdp + 96;                // 1024

  unsigned short* q5b   = (unsigned short*)P0;
  unsigned short* vt5b  = (unsigned short*)P1;
  unsigned short* yR    = (unsigned short*)P2;
  unsigned short* tR    = (unsigned short*)P0;
  unsigned short* zinR  = (unsigned short*)P1;
  unsigned short* gR    = (unsigned short*)P2;
  unsigned short* adjTb = (unsigned short*)adjT_f;
  unsigned short* Wb7   = (unsigned short*)WbSlot;

  k_cvtW<<<224, 256, 0, stream>>>(Wq, Wv, Wx, Wc, Wg1, Wg2, Wg3, (unsigned int*)Wb7);
  k_s1<<<NN, 320, 0, stream>>>(nv1, nv2, s1);
  k_smm<<<NN, 320, 0, stream>>>(s1, s1, s2);
  k_smm<<<NN, 320, 0, stream>>>(s2, s1, s3);
  k_adjT<<<(320 * 160 + 255) / 256, 256, 0, stream>>>(s1, s2, s3, sws, (unsigned int*)adjTb);
  k_avg<<<BB * DCH / 4, 256, 0, stream>>>(x, avgb);
  k_memw2<<<BB, 128, 0, stream>>>(avgb, A1, a1b, A2, a2b, mimp, memw);

  // q/v projections (std fp32 in, attention layouts out)
  k_convm<0><<<dim3(58, 1, BB), 256, 0, stream>>>(Wb7 + 0 * 16384, x, bq, q5b);
  k_convm<4><<<dim3(58, 1, BB), 256, 0, stream>>>(Wb7 + 1 * 16384, x, bv, vt5b);

  // attention + graph -> yR (bf16 R-layout)
  k_attn_mfma<<<dim3(LNUM, HH, BB), 256, 0, stream>>>(q5b, vt5b, memb, memw, adjTb, yR);

  // t = y + conv(y)  (yR -> tR)
  k_convr<1><<<dim3(58, 1, BB), 256, 0, stream>>>(Wb7 + 2 * 16384, yR, bx, tR,
                                                  nullptr, nullptr, nullptr, nullptr, nullptr, nullptr);
  // z_in = relu(conv(t))*(w+1) + bias + x  (tR -> zinR)
  k_convr<2><<<dim3(58, 1, BB), 256, 0, stream>>>(Wb7 + 3 * 16384, tR, bc, zinR,
                                                  wgt, bia, x, nullptr, nullptr, nullptr);

  // LN #1 stats (apply is fused into consumers)
  k_lnstatR<<<dim3(LN_RCH, BB), 256, 0, stream>>>(zinR, pS, pSS);
  k_lnfin2<<<1, 96, 0, stream>>>(pS, pSS, meanp, rstdp, LN_RCH);

  // g = conv(LN(z_in),Wg1)*sigmoid(conv(LN(z_in),Wg2))  (zinR -> gR)
  k_convr_glu<<<dim3(58, 1, BB), 256, 0, stream>>>(Wb7 + 4 * 16384, Wb7 + 5 * 16384,
                                                   zinR, bg1, bg2, meanp, rstdp, gR);
  // t2 = (conv(g,Wg3) + LN(z_in))*(w+1) + bias  (gR -> P0 fp32 std)
  k_convr<3><<<dim3(58, 1, BB), 256, 0, stream>>>(Wb7 + 6 * 16384, gR, bg3, P0,
                                                  wgt, bia, nullptr, zinR, meanp, rstdp);

  // out = ln12(t2)
  k_lnstat<<<dim3(LN_CH, BB), 192, 0, stream>>>(P0, pS, pSS);
  k_lnfin2<<<1, 96, 0, stream>>>(pS, pSS, meanp, rstdp, LN_CH);
  k_lnapply<<<SZ / 1024, 256, 0, stream>>>(P0, meanp, rstdp, (float*)d_out);
}

// Round 9
// 228.351 us; speedup vs baseline: 2.8925x; 1.0239x over previous
//
#include <hip/hip_runtime.h>

namespace {

constexpr int NN   = 307;
constexpr int LNUM = 12;
constexpr int SP   = NN * LNUM;        // 3684
constexpr int DCH  = 128;
constexpr int HH   = 8;
constexpr int DK   = 16;
constexpr int BB   = 8;
constexpr int SZB  = DCH * SP;         // 471552 per batch
constexpr int SZ   = BB * SZB;         // 3772416 total
constexpr int ADJN = NN * NN;          // 94249
constexpr int DN   = DCH * NN;         // 39296 (layernorm group size)
constexpr int LN_RCH = 58;             // chunks for R-layout lnstat (64 s each)
constexpr int MST  = HH * LNUM * NN * DK;  // mem_bank per-slot stride

typedef __attribute__((ext_vector_type(8))) short short8_t;
typedef __attribute__((ext_vector_type(4))) float f32x4;

__device__ inline unsigned short f2bf(float f) {
  unsigned int u = __builtin_bit_cast(unsigned int, f);
  unsigned int r = (u + 0x7FFFu + ((u >> 16) & 1u)) >> 16;
  return (unsigned short)r;
}
__device__ inline float bf2f(unsigned short h) {
  unsigned int u = ((unsigned int)h) << 16;
  return __builtin_bit_cast(float, u);
}

// sigma-permuted column position for m within the V / adjT buffers
__device__ __host__ inline int posm(int m) {
  int q = (m & 15) >> 2, sub = (m >> 4) & 1, i = m & 3;
  return (m & ~31) + 8 * q + 4 * sub + i;
}

// ---------------- small prep kernels ----------------

__global__ __launch_bounds__(256) void k_cvtW(
    const float* __restrict__ W0, const float* __restrict__ W1,
    const float* __restrict__ W2, const float* __restrict__ W3,
    const float* __restrict__ W4, const float* __restrict__ W5,
    const float* __restrict__ W6, unsigned int* __restrict__ Wb) {
  const float* srcs[7] = {W0, W1, W2, W3, W4, W5, W6};
  int idx = blockIdx.x * 256 + threadIdx.x;   // 0..57343
  int w = idx >> 13, off = idx & 8191;
  const float* s = srcs[w];
  float v0 = s[off * 2], v1 = s[off * 2 + 1];
  unsigned int pk;
  asm("v_cvt_pk_bf16_f32 %0, %1, %2" : "=v"(pk) : "v"(v0), "v"(v1));
  Wb[idx] = pk;
}

__global__ __launch_bounds__(320) void k_s1(
    const float* __restrict__ nv1, const float* __restrict__ nv2,
    float* __restrict__ out) {
  __shared__ float red[512];
  __shared__ float rowA[10];
  const int i = blockIdx.x, j = threadIdx.x;
  if (j < 10) rowA[j] = nv1[i * 10 + j];
  __syncthreads();
  float val = 0.f;
  if (j < NN) {
#pragma unroll
    for (int k = 0; k < 10; ++k) val += rowA[k] * nv2[k * NN + j];
    val = fmaxf(val, 0.f);
  }
  red[j] = (j < NN) ? val : -3.4e38f;
  if (j < 192) red[j + 320] = -3.4e38f;
  __syncthreads();
  for (int s = 256; s >= 1; s >>= 1) {
    if (j < s) red[j] = fmaxf(red[j], red[j + s]);
    __syncthreads();
  }
  float mx = red[0];
  __syncthreads();
  float e = (j < NN) ? __expf(val - mx) : 0.f;
  red[j] = e;
  if (j < 192) red[j + 320] = 0.f;
  __syncthreads();
  for (int s = 256; s >= 1; s >>= 1) {
    if (j < s) red[j] += red[j + s];
    __syncthreads();
  }
  if (j < NN) out[i * NN + j] = e / red[0];
}

__global__ __launch_bounds__(320) void k_smm(
    const float* __restrict__ Sa, const float* __restrict__ Sb,
    float* __restrict__ out) {
  __shared__ float red[512];
  __shared__ float rowA[320];
  const int i = blockIdx.x, j = threadIdx.x;
  if (j < NN) rowA[j] = Sa[i * NN + j];
  __syncthreads();
  float val = 0.f;
  if (j < NN) {
    for (int k = 0; k < NN; ++k) val += rowA[k] * Sb[k * NN + j];
  }
  red[j] = (j < NN) ? val : -3.4e38f;
  if (j < 192) red[j + 320] = -3.4e38f;
  __syncthreads();
  for (int s = 256; s >= 1; s >>= 1) {
    if (j < s) red[j] = fmaxf(red[j], red[j + s]);
    __syncthreads();
  }
  float mx = red[0];
  __syncthreads();
  float e = (j < NN) ? __expf(val - mx) : 0.f;
  red[j] = e;
  if (j < 192) red[j + 320] = 0.f;
  __syncthreads();
  for (int s = 256; s >= 1; s >>= 1) {
    if (j < s) red[j] += red[j + s];
    __syncthreads();
  }
  if (j < NN) out[i * NN + j] = e / red[0];
}

__global__ __launch_bounds__(256) void k_adjT(
    const float* __restrict__ s1, const float* __restrict__ s2,
    const float* __restrict__ s3, const float* __restrict__ sws,
    unsigned int* __restrict__ adjTw) {
  int idx = blockIdx.x * 256 + threadIdx.x;   // 0 .. 320*160-1
  if (idx >= 320 * 160) return;
  int n = idx / 160, wp = idx - n * 160;
  int pos0 = 2 * wp;
  int bq = pos0 & 31;
  int g = bq >> 3, sub = (bq >> 2) & 1, i = bq & 3;
  int m0 = (pos0 & ~31) + sub * 16 + 4 * g + i;
  float w0 = sws[0], w1 = sws[1], w2 = sws[2];
  float mm = fmaxf(w0, fmaxf(w1, w2));
  float e0 = __expf(w0 - mm), e1 = __expf(w1 - mm), e2 = __expf(w2 - mm);
  float inv = 1.f / (e0 + e1 + e2);
  e0 *= inv; e1 *= inv; e2 *= inv;
  float v0 = 0.f, v1 = 0.f;
  if (n < NN) {
    if (m0 < NN)     v0 = e0 * s1[m0 * NN + n] + e1 * s2[m0 * NN + n] + e2 * s3[m0 * NN + n];
    if (m0 + 1 < NN) v1 = e0 * s1[(m0 + 1) * NN + n] + e1 * s2[(m0 + 1) * NN + n] + e2 * s3[(m0 + 1) * NN + n];
  }
  adjTw[n * 160 + wp] = (unsigned int)f2bf(v0) | ((unsigned int)f2bf(v1) << 16);
}

__global__ __launch_bounds__(256) void k_avg(
    const float* __restrict__ x, float* __restrict__ avg) {
  const int row = blockIdx.x * 4 + (threadIdx.x >> 6);
  const int lane = threadIdx.x & 63;
  const float* p = x + (size_t)row * SP;
  float s = 0.f;
  for (int i = lane; i < SP / 4; i += 64) {
    float4 v = *(const float4*)(p + i * 4);
    s += v.x + v.y + v.z + v.w;
  }
  s += __shfl_xor(s, 1);  s += __shfl_xor(s, 2);  s += __shfl_xor(s, 4);
  s += __shfl_xor(s, 8);  s += __shfl_xor(s, 16); s += __shfl_xor(s, 32);
  if (lane == 0) avg[row] = s * (1.f / SP);
}

__global__ __launch_bounds__(128) void k_memw2(
    const float* __restrict__ avgg, const float* __restrict__ A1,
    const float* __restrict__ a1b, const float* __restrict__ A2,
    const float* __restrict__ a2b, const float* __restrict__ mimp,
    float* __restrict__ memw) {
  const int b = blockIdx.x, t = threadIdx.x;
  __shared__ float avg[128];
  __shared__ float hbuf[64];
  __shared__ float lg[4];
  avg[t] = avgg[b * 128 + t];
  __syncthreads();
  if (t < 64) {
    float a = a1b[t];
    for (int d = 0; d < 128; ++d) a += avg[d] * A1[d * 64 + t];
    hbuf[t] = fmaxf(a, 0.f);
  }
  __syncthreads();
  if (t < 4) {
    float a = a2b[t];
    for (int j = 0; j < 64; ++j) a += hbuf[j] * A2[j * 4 + t];
    lg[t] = a;
  }
  __syncthreads();
  if (t == 0) {
    float mx = fmaxf(fmaxf(lg[0], lg[1]), fmaxf(lg[2], lg[3]));
    float e[4]; float se = 0.f;
    for (int m = 0; m < 4; ++m) { e[m] = __expf(lg[m] - mx); se += e[m]; }
    float w[4]; float mx2 = -3.4e38f;
    for (int m = 0; m < 4; ++m) { w[m] = mimp[m] * (e[m] / se); mx2 = fmaxf(mx2, w[m]); }
    float se2 = 0.f;
    for (int m = 0; m < 4; ++m) { e[m] = __expf(w[m] - mx2); se2 += e[m]; }
    for (int m = 0; m < 4; ++m) memw[b * 4 + m] = e[m] / se2;
  }
}

// ---------------- fused q/v projection (std fp32 in, x staged ONCE) ----------------
// q: relu(x@Wq+bq) -> q5b bf16 [sl][n][16]
// v: relu(x@Wv+bv) -> vt5b bf16 [sl][16][posm(n)]
__global__ __launch_bounds__(256) void k_convqv(
    const unsigned short* __restrict__ Wqb, const unsigned short* __restrict__ Wvb,
    const float* __restrict__ X, const float* __restrict__ bq,
    const float* __restrict__ bv, unsigned short* __restrict__ qb,
    unsigned short* __restrict__ vb) {
  __shared__ unsigned short Xs[64 * 128];
  __shared__ unsigned short Ws[128 * 128];
  const int sBase = blockIdx.x * 64;
  const int b = blockIdx.z;
  const int t = threadIdx.x;

  {
    const int u = t & 63, cp = t >> 6;
    const int s = sBase + u;
    const bool in = s < SP;
#pragma unroll
    for (int it = 0; it < 16; ++it) {
      int c0 = it * 8 + cp * 2;
      float v0 = 0.f, v1 = 0.f;
      if (in) {
        v0 = X[(size_t)(b * DCH + c0) * SP + s];
        v1 = X[(size_t)(b * DCH + c0 + 1) * SP + s];
      }
      unsigned int pk;
      asm("v_cvt_pk_bf16_f32 %0, %1, %2" : "=v"(pk) : "v"(v0), "v"(v1));
      *(unsigned int*)((char*)Xs + u * 256 + ((2 * c0) ^ ((u & 7) << 4))) = pk;
    }
  }
  const int o = t >> 1, half = t & 1;
  {
    const unsigned short* src = Wqb + o * 128 + half * 64;
#pragma unroll
    for (int j = 0; j < 8; ++j) {
      short8_t v = *(const short8_t*)(src + j * 8);
      *(short8_t*)((char*)Ws + o * 256 + ((half * 128 + j * 16) ^ ((o & 7) << 4))) = v;
    }
  }
  __syncthreads();

  const int wave = t >> 6, lane = t & 63;
  const int r = lane & 15, g = lane >> 4;
  const int swz = (r & 7) << 4;

  short8_t xa[4];
#pragma unroll
  for (int kk = 0; kk < 4; ++kk)
    xa[kk] = *(const short8_t*)((const char*)Xs + (wave * 16 + r) * 256 + ((kk * 64 + g * 16) ^ swz));

  const f32x4 zf = {0.f, 0.f, 0.f, 0.f};
  const int s0 = sBase + wave * 16 + 4 * g;
  const bool act = s0 < SP;

  // ---- pass 1: Wq ----
  {
    f32x4 acc[8];
#pragma unroll
    for (int ot = 0; ot < 8; ++ot) acc[ot] = zf;
#pragma unroll
    for (int ot = 0; ot < 8; ++ot) {
#pragma unroll
      for (int kk = 0; kk < 4; ++kk) {
        short8_t wb = *(const short8_t*)((const char*)Ws + (ot * 16 + r) * 256 + ((kk * 64 + g * 16) ^ swz));
        acc[ot] = __builtin_amdgcn_mfma_f32_16x16x32_bf16(xa[kk], wb, acc[ot], 0, 0, 0);
      }
    }
    if (act) {
#pragma unroll
      for (int ot = 0; ot < 8; ++ot) {
        float bvv = bq[ot * 16 + r];
#pragma unroll
        for (int i = 0; i < 4; ++i) {
          int s = s0 + i, n = s / 12, l2 = s - n * 12;
          qb[((b * 8 + ot) * 12 + l2) * 5120 + n * 16 + r] = f2bf(fmaxf(acc[ot][i] + bvv, 0.f));
        }
      }
    }
  }
  __syncthreads();   // all waves done reading Ws (Wq)
  {
    const unsigned short* src = Wvb + o * 128 + half * 64;
#pragma unroll
    for (int j = 0; j < 8; ++j) {
      short8_t v = *(const short8_t*)(src + j * 8);
      *(short8_t*)((char*)Ws + o * 256 + ((half * 128 + j * 16) ^ ((o & 7) << 4))) = v;
    }
  }
  __syncthreads();
  // ---- pass 2: Wv ----
  {
    f32x4 acc[8];
#pragma unroll
    for (int ot = 0; ot < 8; ++ot) acc[ot] = zf;
#pragma unroll
    for (int ot = 0; ot < 8; ++ot) {
#pragma unroll
      for (int kk = 0; kk < 4; ++kk) {
        short8_t wb = *(const short8_t*)((const char*)Ws + (ot * 16 + r) * 256 + ((kk * 64 + g * 16) ^ swz));
        acc[ot] = __builtin_amdgcn_mfma_f32_16x16x32_bf16(xa[kk], wb, acc[ot], 0, 0, 0);
      }
    }
    if (act) {
#pragma unroll
      for (int ot = 0; ot < 8; ++ot) {
        float bvv = bv[ot * 16 + r];
#pragma unroll
        for (int i = 0; i < 4; ++i) {
          int s = s0 + i, n = s / 12, l2 = s - n * 12;
          vb[((b * 8 + ot) * 12 + l2) * 5120 + r * 320 + posm(n)] = f2bf(fmaxf(acc[ot][i] + bvv, 0.f));
        }
      }
    }
  }
}

// ---------------- MFMA 1x1 conv, bf16 R-layout input [s][c] ----------------
// MODE 1: out = acc + b + y(residual from LDS tile) -> bf16 R
// MODE 2: out = relu(acc+b)*(aw+1) + ab + x(std fp32)  -> bf16 R
// MODE 3: out = (acc + b + LN(z_in))*(aw+1) + ab       -> bf16 R
template <int MODE>
__global__ __launch_bounds__(256) void k_convr(
    const unsigned short* __restrict__ Wbf, const unsigned short* __restrict__ Xr,
    const float* __restrict__ bvec, void* __restrict__ outv,
    const float* __restrict__ aw, const float* __restrict__ ab,
    const float* __restrict__ axf, const unsigned short* __restrict__ zr,
    const float* __restrict__ meanp, const float* __restrict__ rstdp) {
  __shared__ unsigned short Xs[64 * 128];
  __shared__ unsigned short Ws[128 * 128];
  const int sBase = blockIdx.x * 64;
  const int b = blockIdx.z;
  const int t = threadIdx.x;

  {
    const int sl = t >> 2, q = t & 3;
    const int s = sBase + sl;
    const short8_t z8 = {0, 0, 0, 0, 0, 0, 0, 0};
    const unsigned short* row = Xr + (((size_t)b * SP + s) << 7);
#pragma unroll
    for (int j = 0; j < 4; ++j) {
      int cb = 16 * (4 * j + q);
      short8_t v = (s < SP) ? *(const short8_t*)((const char*)row + cb) : z8;
      *(short8_t*)((char*)Xs + sl * 256 + (cb ^ ((sl & 7) << 4))) = v;
    }
  }
  {
    const int o = t >> 1, half = t & 1;
    const unsigned short* src = Wbf + o * 128 + half * 64;
#pragma unroll
    for (int j = 0; j < 8; ++j) {
      short8_t v = *(const short8_t*)(src + j * 8);
      *(short8_t*)((char*)Ws + o * 256 + ((half * 128 + j * 16) ^ ((o & 7) << 4))) = v;
    }
  }
  __syncthreads();

  const int wave = t >> 6, lane = t & 63;
  const int r = lane & 15, g = lane >> 4;
  const int swz = (r & 7) << 4;

  short8_t xa[4];
#pragma unroll
  for (int kk = 0; kk < 4; ++kk)
    xa[kk] = *(const short8_t*)((const char*)Xs + (wave * 16 + r) * 256 + ((kk * 64 + g * 16) ^ swz));

  const f32x4 zf = {0.f, 0.f, 0.f, 0.f};
  f32x4 acc[8];
#pragma unroll
  for (int ot = 0; ot < 8; ++ot) acc[ot] = zf;
#pragma unroll
  for (int ot = 0; ot < 8; ++ot) {
#pragma unroll
    for (int kk = 0; kk < 4; ++kk) {
      short8_t wb = *(const short8_t*)((const char*)Ws + (ot * 16 + r) * 256 + ((kk * 64 + g * 16) ^ swz));
      acc[ot] = __builtin_amdgcn_mfma_f32_16x16x32_bf16(xa[kk], wb, acc[ot], 0, 0, 0);
    }
  }

  const int s0 = sBase + wave * 16 + 4 * g;
  if (s0 >= SP) return;

  if constexpr (MODE == 1) {
    unsigned short* outR = (unsigned short*)outv;
#pragma unroll
    for (int ot = 0; ot < 8; ++ot) {
      int o = ot * 16 + r;
      float bv = bvec[o];
#pragma unroll
      for (int i = 0; i < 4; ++i) {
        int u = wave * 16 + 4 * g + i;
        float y = bf2f(*(const unsigned short*)((const char*)Xs + u * 256 + ((2 * o) ^ ((u & 7) << 4))));
        outR[(((size_t)b * SP + s0 + i) << 7) + o] = f2bf(acc[ot][i] + bv + y);
      }
    }
  } else if constexpr (MODE == 2) {
    unsigned short* outR = (unsigned short*)outv;
#pragma unroll
    for (int ot = 0; ot < 8; ++ot) {
      int o = ot * 16 + r;
      float bv = bvec[o];
      float4 w4 = *(const float4*)(aw + o * SP + s0);
      float4 b4 = *(const float4*)(ab + o * SP + s0);
      float4 x4 = *(const float4*)(axf + (size_t)(b * DCH + o) * SP + s0);
#pragma unroll
      for (int i = 0; i < 4; ++i) {
        float rr = fmaxf(acc[ot][i] + bv, 0.f);
        float val = rr * ((&w4.x)[i] + 1.f) + (&b4.x)[i] + (&x4.x)[i];
        outR[(((size_t)b * SP + s0 + i) << 7) + o] = f2bf(val);
      }
    }
  } else {  // MODE 3 -> bf16 R
    unsigned short* outR = (unsigned short*)outv;
    float m4[4], r4[4];
#pragma unroll
    for (int i = 0; i < 4; ++i) {
      int l = (s0 + i) % 12;
      m4[i] = meanp[b * 12 + l];
      r4[i] = rstdp[b * 12 + l];
    }
#pragma unroll
    for (int ot = 0; ot < 8; ++ot) {
      int o = ot * 16 + r;
      float bv = bvec[o];
      float4 w4 = *(const float4*)(aw + o * SP + s0);
      float4 b4 = *(const float4*)(ab + o * SP + s0);
#pragma unroll
      for (int i = 0; i < 4; ++i) {
        float zin = bf2f(zr[(((size_t)b * SP + s0 + i) << 7) + o]);
        float z = (zin - m4[i]) * r4[i];
        float tt = acc[ot][i] + bv + z;
        outR[(((size_t)b * SP + s0 + i) << 7) + o] = f2bf(tt * ((&w4.x)[i] + 1.f) + (&b4.x)[i]);
      }
    }
  }
}

// GLU conv: input z_in bf16 R-layout, LN applied inline during staging.
__global__ __launch_bounds__(256) void k_convr_glu(
    const unsigned short* __restrict__ Wb1, const unsigned short* __restrict__ Wb2,
    const unsigned short* __restrict__ Zr, const float* __restrict__ b1,
    const float* __restrict__ b2, const float* __restrict__ meanp,
    const float* __restrict__ rstdp, unsigned short* __restrict__ outR) {
  __shared__ unsigned short Xs[64 * 128];
  __shared__ unsigned short Ws[128 * 128];
  const int sBase = blockIdx.x * 64;
  const int b = blockIdx.z;
  const int t = threadIdx.x;

  {
    const int sl = t >> 2, q = t & 3;
    const int s = sBase + sl;
    float m = 0.f, rr = 0.f;
    if (s < SP) { int l = s % 12; m = meanp[b * 12 + l]; rr = rstdp[b * 12 + l]; }
    const short8_t z8 = {0, 0, 0, 0, 0, 0, 0, 0};
    const unsigned short* row = Zr + (((size_t)b * SP + s) << 7);
#pragma unroll
    for (int j = 0; j < 4; ++j) {
      int cb = 16 * (4 * j + q);
      short8_t v = (s < SP) ? *(const short8_t*)((const char*)row + cb) : z8;
      union { unsigned int w[4]; short8_t s8; } u;
#pragma unroll
      for (int k2 = 0; k2 < 4; ++k2) {
        float f0 = (bf2f((unsigned short)v[2 * k2]) - m) * rr;
        float f1 = (bf2f((unsigned short)v[2 * k2 + 1]) - m) * rr;
        asm("v_cvt_pk_bf16_f32 %0, %1, %2" : "=v"(u.w[k2]) : "v"(f0), "v"(f1));
      }
      *(short8_t*)((char*)Xs + sl * 256 + (cb ^ ((sl & 7) << 4))) = u.s8;
    }
  }
  const int o = t >> 1, half = t & 1;
  {
    const unsigned short* src = Wb1 + o * 128 + half * 64;
#pragma unroll
    for (int j = 0; j < 8; ++j) {
      short8_t v = *(const short8_t*)(src + j * 8);
      *(short8_t*)((char*)Ws + o * 256 + ((half * 128 + j * 16) ^ ((o & 7) << 4))) = v;
    }
  }
  __syncthreads();

  const int wave = t >> 6, lane = t & 63;
  const int r = lane & 15, g = lane >> 4;
  const int swz = (r & 7) << 4;

  short8_t xa[4];
#pragma unroll
  for (int kk = 0; kk < 4; ++kk)
    xa[kk] = *(const short8_t*)((const char*)Xs + (wave * 16 + r) * 256 + ((kk * 64 + g * 16) ^ swz));

  const f32x4 zf = {0.f, 0.f, 0.f, 0.f};
  f32x4 acc1[8], acc2[8];
#pragma unroll
  for (int ot = 0; ot < 8; ++ot) { acc1[ot] = zf; acc2[ot] = zf; }
#pragma unroll
  for (int ot = 0; ot < 8; ++ot) {
#pragma unroll
    for (int kk = 0; kk < 4; ++kk) {
      short8_t wb = *(const short8_t*)((const char*)Ws + (ot * 16 + r) * 256 + ((kk * 64 + g * 16) ^ swz));
      acc1[ot] = __builtin_amdgcn_mfma_f32_16x16x32_bf16(xa[kk], wb, acc1[ot], 0, 0, 0);
    }
  }
  __syncthreads();
  {
    const unsigned short* src = Wb2 + o * 128 + half * 64;
#pragma unroll
    for (int j = 0; j < 8; ++j) {
      short8_t v = *(const short8_t*)(src + j * 8);
      *(short8_t*)((char*)Ws + o * 256 + ((half * 128 + j * 16) ^ ((o & 7) << 4))) = v;
    }
  }
  __syncthreads();
#pragma unroll
  for (int ot = 0; ot < 8; ++ot) {
#pragma unroll
    for (int kk = 0; kk < 4; ++kk) {
      short8_t wb = *(const short8_t*)((const char*)Ws + (ot * 16 + r) * 256 + ((kk * 64 + g * 16) ^ swz));
      acc2[ot] = __builtin_amdgcn_mfma_f32_16x16x32_bf16(xa[kk], wb, acc2[ot], 0, 0, 0);
    }
  }

  const int s0 = sBase + wave * 16 + 4 * g;
  if (s0 >= SP) return;
#pragma unroll
  for (int ot = 0; ot < 8; ++ot) {
    int oo = ot * 16 + r;
    float bb1 = b1[oo], bb2 = b2[oo];
#pragma unroll
    for (int i = 0; i < 4; ++i) {
      float v1 = acc1[ot][i] + bb1;
      float v2 = acc2[ot][i] + bb2;
      outR[(((size_t)b * SP + s0 + i) << 7) + oo] = f2bf(v1 / (1.f + __expf(-v2)));
    }
  }
}

// ---------------- MFMA attention + graph diffusion ----------------
__global__ __launch_bounds__(256) void k_attn_mfma(
    const unsigned short* __restrict__ q5b, const unsigned short* __restrict__ vt5b,
    const float* __restrict__ memb, const float* __restrict__ memw,
    const unsigned short* __restrict__ adjTb, unsigned short* __restrict__ yR) {
  __shared__ unsigned short Mb[320 * 24];
  __shared__ unsigned short Vt[16 * 328];
  const int l = blockIdx.x, h = blockIdx.y, b = blockIdx.z;
  const int t = threadIdx.x;
  const int slice = (b * HH + h) * LNUM + l;
  const int msl = (h * LNUM + l) * NN * DK;
  const float w0 = memw[b * 4 + 0], w1 = memw[b * 4 + 1];
  const float w2 = memw[b * 4 + 2], w3 = memw[b * 4 + 3];

  for (int idx = t; idx < 640; idx += 256) {
    int n = idx >> 1, h8 = idx & 1;
    float v[8];
    if (n < NN) {
      int off = msl + n * 16 + h8 * 8;
      const float4* p0 = (const float4*)(memb + off);
      const float4* p1 = (const float4*)(memb + MST + off);
      const float4* p2 = (const float4*)(memb + 2 * MST + off);
      const float4* p3 = (const float4*)(memb + 3 * MST + off);
      float4 a0 = p0[0], a1 = p1[0], a2 = p2[0], a3 = p3[0];
      float4 c0 = p0[1], c1 = p1[1], c2 = p2[1], c3 = p3[1];
      v[0] = w0 * a0.x + w1 * a1.x + w2 * a2.x + w3 * a3.x;
      v[1] = w0 * a0.y + w1 * a1.y + w2 * a2.y + w3 * a3.y;
      v[2] = w0 * a0.z + w1 * a1.z + w2 * a2.z + w3 * a3.z;
      v[3] = w0 * a0.w + w1 * a1.w + w2 * a2.w + w3 * a3.w;
      v[4] = w0 * c0.x + w1 * c1.x + w2 * c2.x + w3 * c3.x;
      v[5] = w0 * c0.y + w1 * c1.y + w2 * c2.y + w3 * c3.y;
      v[6] = w0 * c0.z + w1 * c1.z + w2 * c2.z + w3 * c3.z;
      v[7] = w0 * c0.w + w1 * c1.w + w2 * c2.w + w3 * c3.w;
    } else {
#pragma unroll
      for (int j = 0; j < 8; ++j) v[j] = 0.f;
    }
    union { unsigned int w[4]; short8_t s; } u;
#pragma unroll
    for (int j = 0; j < 4; ++j)
      u.w[j] = (unsigned int)f2bf(v[2 * j]) | ((unsigned int)f2bf(v[2 * j + 1]) << 16);
    *(short8_t*)(Mb + n * 24 + h8 * 8) = u.s;
  }
  {
    const unsigned short* vsl = vt5b + slice * (16 * 320);
    for (int c = t; c < 640; c += 256) {
      int row = c / 40, ch = c - row * 40;
      short8_t vv = *(const short8_t*)(vsl + row * 320 + ch * 8);
      *(short8_t*)(Vt + row * 328 + ch * 8) = vv;
    }
  }
  __syncthreads();
  // Zero sigma-columns of Vt never written by the v-conv (n=307..319):
  // stale workspace bits would otherwise reach the PV MFMA (0*NaN = NaN).
  for (int idx = t; idx < 16 * 13; idx += 256) {
    int row = idx / 13, j = idx - row * 13;
    Vt[row * 328 + posm(NN + j)] = 0;
  }
  __syncthreads();

  const int wave = t >> 6, lane = t & 63;
  const int r = lane & 15, g = lane >> 4;
  const f32x4 zf = {0.f, 0.f, 0.f, 0.f};
  float maskv[4];
#pragma unroll
  for (int i = 0; i < 4; ++i) maskv[i] = (4 * g + i < 3) ? 1.f : 0.f;
  constexpr float CEXP = 0.25f * 1.44269504089f;

  for (int rt5 = 0; rt5 < 5; ++rt5) {
    const int n0 = (wave * 5 + rt5) * 16;
    short8_t bq = {0, 0, 0, 0, 0, 0, 0, 0};
    if (g < 2 && n0 + r < NN) bq = *(const short8_t*)(q5b + (slice * 320 + n0 + r) * 16 + 8 * g);
    f32x4 accPV = zf, accG = zf;
    float dn = 0.f;
#pragma unroll 2
    for (int mt = 0; mt < 10; ++mt) {
      const int mb = mt * 32;
      short8_t am0 = {0, 0, 0, 0, 0, 0, 0, 0}, am1 = am0;
      if (g < 2) {
        am0 = *(const short8_t*)(Mb + (mb + r) * 24 + 8 * g);
        am1 = *(const short8_t*)(Mb + (mb + 16 + r) * 24 + 8 * g);
      }
      f32x4 s0 = __builtin_amdgcn_mfma_f32_16x16x32_bf16(am0, bq, zf, 0, 0, 0);
      f32x4 s1 = __builtin_amdgcn_mfma_f32_16x16x32_bf16(am1, bq, zf, 0, 0, 0);
      float p0[4], p1[4];
#pragma unroll
      for (int i = 0; i < 4; ++i) {
        p0[i] = __builtin_amdgcn_exp2f(s0[i] * CEXP);
        p1[i] = __builtin_amdgcn_exp2f(s1[i] * CEXP);
      }
      if (mt == 9) {
#pragma unroll
        for (int i = 0; i < 4; ++i) p1[i] *= maskv[i];
      }
      dn += p0[0] + p0[1] + p0[2] + p0[3] + p1[0] + p1[1] + p1[2] + p1[3];
      union { unsigned int w[4]; short8_t s; } up;
      asm("v_cvt_pk_bf16_f32 %0, %1, %2" : "=v"(up.w[0]) : "v"(p0[0]), "v"(p0[1]));
      asm("v_cvt_pk_bf16_f32 %0, %1, %2" : "=v"(up.w[1]) : "v"(p0[2]), "v"(p0[3]));
      asm("v_cvt_pk_bf16_f32 %0, %1, %2" : "=v"(up.w[2]) : "v"(p1[0]), "v"(p1[1]));
      asm("v_cvt_pk_bf16_f32 %0, %1, %2" : "=v"(up.w[3]) : "v"(p1[2]), "v"(p1[3]));
      short8_t bv = *(const short8_t*)(Vt + r * 328 + mb + 8 * g);
      accPV = __builtin_amdgcn_mfma_f32_16x16x32_bf16(up.s, bv, accPV, 0, 0, 0);
      short8_t aj = *(const short8_t*)(adjTb + (n0 + r) * 320 + mb + 8 * g);
      accG = __builtin_amdgcn_mfma_f32_16x16x32_bf16(aj, bv, accG, 0, 0, 0);
    }
    dn += __shfl_xor(dn, 16);
    dn += __shfl_xor(dn, 32);
#pragma unroll
    for (int i = 0; i < 4; ++i) {
      int n = n0 + 4 * g + i;
      float di = __shfl(dn, 4 * g + i);
      if (n < NN) {
        yR[(((size_t)b * SP + n * 12 + l) << 7) + h * 16 + r] = f2bf(accPV[i] / di + accG[i]);
      }
    }
  }
}

// ---------------- layernorm (R-layout stats, fused/transposed apply) ----------------

__global__ __launch_bounds__(256) void k_lnstatR(
    const unsigned short* __restrict__ inR, float* __restrict__ pS, float* __restrict__ pSS) {
  const int chunk = blockIdx.x, b = blockIdx.y, t = threadIdx.x;
  const int sl = t >> 2, q = t & 3;
  const int s = chunk * 64 + sl;
  float sm = 0.f, sq = 0.f;
  if (s < SP) {
    const unsigned short* row = inR + (((size_t)b * SP + s) << 7);
#pragma unroll
    for (int j = 0; j < 4; ++j) {
      short8_t v = *(const short8_t*)((const char*)row + 16 * (4 * j + q));
#pragma unroll
      for (int k = 0; k < 8; ++k) {
        float f = bf2f((unsigned short)v[k]);
        sm += f; sq += f * f;
      }
    }
  }
  __shared__ float ls[256], lq[256];
  ls[t] = sm; lq[t] = sq;
  __syncthreads();
  if (t < 64) {
    ls[t * 4] = ls[t * 4] + ls[t * 4 + 1] + ls[t * 4 + 2] + ls[t * 4 + 3];
    lq[t * 4] = lq[t * 4] + lq[t * 4 + 1] + lq[t * 4 + 2] + lq[t * 4 + 3];
  }
  __syncthreads();
  if (t < 12) {
    float S = 0.f, SS = 0.f;
    for (int u2 = 0; u2 < 64; ++u2) {
      int s2 = chunk * 64 + u2;
      if (s2 < SP && s2 % 12 == t) { S += ls[u2 * 4]; SS += lq[u2 * 4]; }
    }
    pS[(b * LN_RCH + chunk) * 12 + t] = S;
    pSS[(b * LN_RCH + chunk) * 12 + t] = SS;
  }
}

__global__ __launch_bounds__(96) void k_lnfin2(
    const float* __restrict__ pS, const float* __restrict__ pSS,
    float* __restrict__ meanp, float* __restrict__ rstdp, int nch) {
  const int t = threadIdx.x;
  const int b = t / 12, l = t % 12;
  float S = 0.f, SS = 0.f;
  for (int c = 0; c < nch; ++c) {
    S += pS[(b * nch + c) * 12 + l];
    SS += pSS[(b * nch + c) * 12 + l];
  }
  float mu = S * (1.f / DN);
  float var = SS * (1.f / DN) - mu * mu;
  meanp[t] = mu;
  rstdp[t] = rsqrtf(fmaxf(var, 0.f) + 1e-5f);
}

// LN-apply from bf16 R-layout to std fp32 output via LDS transpose tile.
__global__ __launch_bounds__(256) void k_lnapplyT(
    const unsigned short* __restrict__ inR, const float* __restrict__ meanp,
    const float* __restrict__ rstdp, float* __restrict__ outp) {
  __shared__ float Ls[64][129];
  const int sBase = blockIdx.x * 64;
  const int b = blockIdx.y;
  const int t = threadIdx.x;
  {
    const int sl = t >> 2, q = t & 3;
    const int s = sBase + sl;
    if (s < SP) {
      int l = s % 12;
      float m = meanp[b * 12 + l], rr = rstdp[b * 12 + l];
      const unsigned short* row = inR + (((size_t)b * SP + s) << 7);
#pragma unroll
      for (int j = 0; j < 4; ++j) {
        short8_t v = *(const short8_t*)((const char*)row + 16 * (4 * j + q));
        int c0 = 8 * (4 * j + q);
#pragma unroll
        for (int k = 0; k < 8; ++k)
          Ls[sl][c0 + k] = (bf2f((unsigned short)v[k]) - m) * rr;
      }
    }
  }
  __syncthreads();
  const int c = t >> 1, h = t & 1;
  const int sW = sBase + h * 32;
  float* dst = outp + (size_t)(b * DCH + c) * SP + sW;
  const int lim = SP - sW;
#pragma unroll
  for (int j4 = 0; j4 < 8; ++j4) {
    int j = j4 * 4;
    if (j + 3 < lim) {
      float4 v;
      v.x = Ls[h * 32 + j + 0][c];
      v.y = Ls[h * 32 + j + 1][c];
      v.z = Ls[h * 32 + j + 2][c];
      v.w = Ls[h * 32 + j + 3][c];
      *(float4*)(dst + j) = v;
    } else {
#pragma unroll
      for (int e = 0; e < 4; ++e)
        if (j + e < lim) dst[j + e] = Ls[h * 32 + j + e][c];
    }
  }
}

}  // namespace

extern "C" void kernel_launch(void* const* d_in, const int* in_sizes, int n_in,
                              void* d_out, int out_size, void* d_ws, size_t ws_size,
                              hipStream_t stream) {
  (void)in_sizes; (void)n_in; (void)out_size; (void)ws_size;
  const float* x    = (const float*)d_in[0];
  const float* Wq   = (const float*)d_in[1];
  const float* bq   = (const float*)d_in[2];
  const float* Wv   = (const float*)d_in[3];
  const float* bv   = (const float*)d_in[4];
  const float* Wc   = (const float*)d_in[5];
  const float* bc   = (const float*)d_in[6];
  const float* Wx   = (const float*)d_in[7];
  const float* bx   = (const float*)d_in[8];
  const float* Wg1  = (const float*)d_in[9];
  const float* bg1  = (const float*)d_in[10];
  const float* Wg2  = (const float*)d_in[11];
  const float* bg2  = (const float*)d_in[12];
  const float* Wg3  = (const float*)d_in[13];
  const float* bg3  = (const float*)d_in[14];
  const float* memb = (const float*)d_in[15];
  const float* mimp = (const float*)d_in[16];
  const float* A1   = (const float*)d_in[17];
  const float* a1b  = (const float*)d_in[18];
  const float* A2   = (const float*)d_in[19];
  const float* a2b  = (const float*)d_in[20];
  const float* wgt  = (const float*)d_in[21];
  const float* bia  = (const float*)d_in[22];
  const float* nv1  = (const float*)d_in[23];
  const float* nv2  = (const float*)d_in[24];
  const float* sws  = (const float*)d_in[25];

  float* ws = (float*)d_ws;
  float* P0 = ws;                        // q5b -> tR -> t2R
  float* P1 = ws + (size_t)SZ;           // vt5b -> zinR
  float* P2 = ws + 2 * (size_t)SZ;       // yR -> gR
  float* sm = ws + 3 * (size_t)SZ;
  float* s1 = sm;
  float* s2 = sm + ADJN;
  float* s3 = sm + 2 * ADJN;
  float* adjT_f = sm + 3 * ADJN;            // 320*320 bf16 = 51200 floats
  float* memw = adjT_f + 51200;
  float* WbSlot = memw + 32;                // 7*16384 floats reserved (bf16 uses half)
  float* pS   = WbSlot + 7 * 16384;         // 8*58*12
  float* pSS  = pS + BB * LN_RCH * 12;
  float* meanp = pSS + BB * LN_RCH * 12;    // 96
  float* rstdp = meanp + 96;                // 96
  float* avgb  = rstdp + 96;                // 1024

  unsigned short* q5b   = (unsigned short*)P0;
  unsigned short* vt5b  = (unsigned short*)P1;
  unsigned short* yR    = (unsigned short*)P2;
  unsigned short* tR    = (unsigned short*)P0;
  unsigned short* zinR  = (unsigned short*)P1;
  unsigned short* gR    = (unsigned short*)P2;
  unsigned short* t2R   = (unsigned short*)P0;
  unsigned short* adjTb = (unsigned short*)adjT_f;
  unsigned short* Wb7   = (unsigned short*)WbSlot;

  k_cvtW<<<224, 256, 0, stream>>>(Wq, Wv, Wx, Wc, Wg1, Wg2, Wg3, (unsigned int*)Wb7);
  k_s1<<<NN, 320, 0, stream>>>(nv1, nv2, s1);
  k_smm<<<NN, 320, 0, stream>>>(s1, s1, s2);
  k_smm<<<NN, 320, 0, stream>>>(s2, s1, s3);
  k_adjT<<<(320 * 160 + 255) / 256, 256, 0, stream>>>(s1, s2, s3, sws, (unsigned int*)adjTb);
  k_avg<<<BB * DCH / 4, 256, 0, stream>>>(x, avgb);
  k_memw2<<<BB, 128, 0, stream>>>(avgb, A1, a1b, A2, a2b, mimp, memw);

  // fused q/v projection: x staged once, Wq then Wv through the same LDS
  k_convqv<<<dim3(58, 1, BB), 256, 0, stream>>>(Wb7 + 0 * 16384, Wb7 + 1 * 16384,
                                                x, bq, bv, q5b, vt5b);

  // attention + graph -> yR (bf16 R-layout)
  k_attn_mfma<<<dim3(LNUM, HH, BB), 256, 0, stream>>>(q5b, vt5b, memb, memw, adjTb, yR);

  // t = y + conv(y)  (yR -> tR)
  k_convr<1><<<dim3(58, 1, BB), 256, 0, stream>>>(Wb7 + 2 * 16384, yR, bx, tR,
                                                  nullptr, nullptr, nullptr, nullptr, nullptr, nullptr);
  // z_in = relu(conv(t))*(w+1) + bias + x  (tR -> zinR)
  k_convr<2><<<dim3(58, 1, BB), 256, 0, stream>>>(Wb7 + 3 * 16384, tR, bc, zinR,
                                                  wgt, bia, x, nullptr, nullptr, nullptr);

  // LN #1 stats (apply fused into consumers)
  k_lnstatR<<<dim3(LN_RCH, BB), 256, 0, stream>>>(zinR, pS, pSS);
  k_lnfin2<<<1, 96, 0, stream>>>(pS, pSS, meanp, rstdp, LN_RCH);

  // g = conv(LN(z_in),Wg1)*sigmoid(conv(LN(z_in),Wg2))  (zinR -> gR)
  k_convr_glu<<<dim3(58, 1, BB), 256, 0, stream>>>(Wb7 + 4 * 16384, Wb7 + 5 * 16384,
                                                   zinR, bg1, bg2, meanp, rstdp, gR);
  // t2 = (conv(g,Wg3) + LN(z_in))*(w+1) + bias  (gR -> t2R bf16 R)
  k_convr<3><<<dim3(58, 1, BB), 256, 0, stream>>>(Wb7 + 6 * 16384, gR, bg3, t2R,
                                                  wgt, bia, nullptr, zinR, meanp, rstdp);

  // out = ln12(t2): R-layout stats + transposed apply to std fp32
  k_lnstatR<<<dim3(LN_RCH, BB), 256, 0, stream>>>(t2R, pS, pSS);
  k_lnfin2<<<1, 96, 0, stream>>>(pS, pSS, meanp, rstdp, LN_RCH);
  k_lnapplyT<<<dim3(58, BB), 256, 0, stream>>>(t2R, meanp, rstdp, (float*)d_out);
}

// Round 10
// 220.332 us; speedup vs baseline: 2.9978x; 1.0364x over previous
//
#include <hip/hip_runtime.h>

namespace {

constexpr int NN   = 307;
constexpr int LNUM = 12;
constexpr int SP   = NN * LNUM;        // 3684
constexpr int DCH  = 128;
constexpr int HH   = 8;
constexpr int DK   = 16;
constexpr int BB   = 8;
constexpr int SZB  = DCH * SP;         // 471552 per batch
constexpr int SZ   = BB * SZB;         // 3772416 total
constexpr int ADJN = NN * NN;          // 94249
constexpr int DN   = DCH * NN;         // 39296 (layernorm group size)
constexpr int LN_RCH = 58;             // chunks for R-layout lnstat (64 s each)
constexpr int MST  = HH * LNUM * NN * DK;  // mem_bank per-slot stride

typedef __attribute__((ext_vector_type(8))) short short8_t;
typedef __attribute__((ext_vector_type(4))) float f32x4;

__device__ inline unsigned short f2bf(float f) {
  unsigned int u = __builtin_bit_cast(unsigned int, f);
  unsigned int r = (u + 0x7FFFu + ((u >> 16) & 1u)) >> 16;
  return (unsigned short)r;
}
__device__ inline float bf2f(unsigned short h) {
  unsigned int u = ((unsigned int)h) << 16;
  return __builtin_bit_cast(float, u);
}

// sigma-permuted column position for m within the V / adjT buffers
__device__ __host__ inline int posm(int m) {
  int q = (m & 15) >> 2, sub = (m >> 4) & 1, i = m & 3;
  return (m & ~31) + 8 * q + 4 * sub + i;
}

// ---------------- small prep kernels ----------------

__global__ __launch_bounds__(256) void k_cvtW(
    const float* __restrict__ W0, const float* __restrict__ W1,
    const float* __restrict__ W2, const float* __restrict__ W3,
    const float* __restrict__ W4, const float* __restrict__ W5,
    const float* __restrict__ W6, unsigned int* __restrict__ Wb) {
  const float* srcs[7] = {W0, W1, W2, W3, W4, W5, W6};
  int idx = blockIdx.x * 256 + threadIdx.x;   // 0..57343
  int w = idx >> 13, off = idx & 8191;
  const float* s = srcs[w];
  float v0 = s[off * 2], v1 = s[off * 2 + 1];
  unsigned int pk;
  asm("v_cvt_pk_bf16_f32 %0, %1, %2" : "=v"(pk) : "v"(v0), "v"(v1));
  Wb[idx] = pk;
}

__global__ __launch_bounds__(320) void k_s1(
    const float* __restrict__ nv1, const float* __restrict__ nv2,
    float* __restrict__ out) {
  __shared__ float red[512];
  __shared__ float rowA[10];
  const int i = blockIdx.x, j = threadIdx.x;
  if (j < 10) rowA[j] = nv1[i * 10 + j];
  __syncthreads();
  float val = 0.f;
  if (j < NN) {
#pragma unroll
    for (int k = 0; k < 10; ++k) val += rowA[k] * nv2[k * NN + j];
    val = fmaxf(val, 0.f);
  }
  red[j] = (j < NN) ? val : -3.4e38f;
  if (j < 192) red[j + 320] = -3.4e38f;
  __syncthreads();
  for (int s = 256; s >= 1; s >>= 1) {
    if (j < s) red[j] = fmaxf(red[j], red[j + s]);
    __syncthreads();
  }
  float mx = red[0];
  __syncthreads();
  float e = (j < NN) ? __expf(val - mx) : 0.f;
  red[j] = e;
  if (j < 192) red[j + 320] = 0.f;
  __syncthreads();
  for (int s = 256; s >= 1; s >>= 1) {
    if (j < s) red[j] += red[j + s];
    __syncthreads();
  }
  if (j < NN) out[i * NN + j] = e / red[0];
}

__global__ __launch_bounds__(320) void k_smm(
    const float* __restrict__ Sa, const float* __restrict__ Sb,
    float* __restrict__ out) {
  __shared__ float red[512];
  __shared__ float rowA[320];
  const int i = blockIdx.x, j = threadIdx.x;
  if (j < NN) rowA[j] = Sa[i * NN + j];
  __syncthreads();
  float val = 0.f;
  if (j < NN) {
    for (int k = 0; k < NN; ++k) val += rowA[k] * Sb[k * NN + j];
  }
  red[j] = (j < NN) ? val : -3.4e38f;
  if (j < 192) red[j + 320] = -3.4e38f;
  __syncthreads();
  for (int s = 256; s >= 1; s >>= 1) {
    if (j < s) red[j] = fmaxf(red[j], red[j + s]);
    __syncthreads();
  }
  float mx = red[0];
  __syncthreads();
  float e = (j < NN) ? __expf(val - mx) : 0.f;
  red[j] = e;
  if (j < 192) red[j + 320] = 0.f;
  __syncthreads();
  for (int s = 256; s >= 1; s >>= 1) {
    if (j < s) red[j] += red[j + s];
    __syncthreads();
  }
  if (j < NN) out[i * NN + j] = e / red[0];
}

__global__ __launch_bounds__(256) void k_adjT(
    const float* __restrict__ s1, const float* __restrict__ s2,
    const float* __restrict__ s3, const float* __restrict__ sws,
    unsigned int* __restrict__ adjTw) {
  int idx = blockIdx.x * 256 + threadIdx.x;   // 0 .. 320*160-1
  if (idx >= 320 * 160) return;
  int n = idx / 160, wp = idx - n * 160;
  int pos0 = 2 * wp;
  int bq = pos0 & 31;
  int g = bq >> 3, sub = (bq >> 2) & 1, i = bq & 3;
  int m0 = (pos0 & ~31) + sub * 16 + 4 * g + i;
  float w0 = sws[0], w1 = sws[1], w2 = sws[2];
  float mm = fmaxf(w0, fmaxf(w1, w2));
  float e0 = __expf(w0 - mm), e1 = __expf(w1 - mm), e2 = __expf(w2 - mm);
  float inv = 1.f / (e0 + e1 + e2);
  e0 *= inv; e1 *= inv; e2 *= inv;
  float v0 = 0.f, v1 = 0.f;
  if (n < NN) {
    if (m0 < NN)     v0 = e0 * s1[m0 * NN + n] + e1 * s2[m0 * NN + n] + e2 * s3[m0 * NN + n];
    if (m0 + 1 < NN) v1 = e0 * s1[(m0 + 1) * NN + n] + e1 * s2[(m0 + 1) * NN + n] + e2 * s3[(m0 + 1) * NN + n];
  }
  adjTw[n * 160 + wp] = (unsigned int)f2bf(v0) | ((unsigned int)f2bf(v1) << 16);
}

__global__ __launch_bounds__(256) void k_avg(
    const float* __restrict__ x, float* __restrict__ avg) {
  const int row = blockIdx.x * 4 + (threadIdx.x >> 6);
  const int lane = threadIdx.x & 63;
  const float* p = x + (size_t)row * SP;
  float s = 0.f;
  for (int i = lane; i < SP / 4; i += 64) {
    float4 v = *(const float4*)(p + i * 4);
    s += v.x + v.y + v.z + v.w;
  }
  s += __shfl_xor(s, 1);  s += __shfl_xor(s, 2);  s += __shfl_xor(s, 4);
  s += __shfl_xor(s, 8);  s += __shfl_xor(s, 16); s += __shfl_xor(s, 32);
  if (lane == 0) avg[row] = s * (1.f / SP);
}

__global__ __launch_bounds__(128) void k_memw2(
    const float* __restrict__ avgg, const float* __restrict__ A1,
    const float* __restrict__ a1b, const float* __restrict__ A2,
    const float* __restrict__ a2b, const float* __restrict__ mimp,
    float* __restrict__ memw) {
  const int b = blockIdx.x, t = threadIdx.x;
  __shared__ float avg[128];
  __shared__ float hbuf[64];
  __shared__ float lg[4];
  avg[t] = avgg[b * 128 + t];
  __syncthreads();
  if (t < 64) {
    float a = a1b[t];
    for (int d = 0; d < 128; ++d) a += avg[d] * A1[d * 64 + t];
    hbuf[t] = fmaxf(a, 0.f);
  }
  __syncthreads();
  if (t < 4) {
    float a = a2b[t];
    for (int j = 0; j < 64; ++j) a += hbuf[j] * A2[j * 4 + t];
    lg[t] = a;
  }
  __syncthreads();
  if (t == 0) {
    float mx = fmaxf(fmaxf(lg[0], lg[1]), fmaxf(lg[2], lg[3]));
    float e[4]; float se = 0.f;
    for (int m = 0; m < 4; ++m) { e[m] = __expf(lg[m] - mx); se += e[m]; }
    float w[4]; float mx2 = -3.4e38f;
    for (int m = 0; m < 4; ++m) { w[m] = mimp[m] * (e[m] / se); mx2 = fmaxf(mx2, w[m]); }
    float se2 = 0.f;
    for (int m = 0; m < 4; ++m) { e[m] = __expf(w[m] - mx2); se2 += e[m]; }
    for (int m = 0; m < 4; ++m) memw[b * 4 + m] = e[m] / se2;
  }
}

// ---------------- fused q/v projection (std fp32 in, x staged ONCE) ----------------
__global__ __launch_bounds__(256) void k_convqv(
    const unsigned short* __restrict__ Wqb, const unsigned short* __restrict__ Wvb,
    const float* __restrict__ X, const float* __restrict__ bq,
    const float* __restrict__ bv, unsigned short* __restrict__ qb,
    unsigned short* __restrict__ vb) {
  __shared__ unsigned short Xs[64 * 128];
  __shared__ unsigned short Ws[128 * 128];
  const int sBase = blockIdx.x * 64;
  const int b = blockIdx.z;
  const int t = threadIdx.x;

  {
    const int u = t & 63, cp = t >> 6;
    const int s = sBase + u;
    const bool in = s < SP;
#pragma unroll
    for (int it = 0; it < 16; ++it) {
      int c0 = it * 8 + cp * 2;
      float v0 = 0.f, v1 = 0.f;
      if (in) {
        v0 = X[(size_t)(b * DCH + c0) * SP + s];
        v1 = X[(size_t)(b * DCH + c0 + 1) * SP + s];
      }
      unsigned int pk;
      asm("v_cvt_pk_bf16_f32 %0, %1, %2" : "=v"(pk) : "v"(v0), "v"(v1));
      *(unsigned int*)((char*)Xs + u * 256 + ((2 * c0) ^ ((u & 7) << 4))) = pk;
    }
  }
  const int o = t >> 1, half = t & 1;
  {
    const unsigned short* src = Wqb + o * 128 + half * 64;
#pragma unroll
    for (int j = 0; j < 8; ++j) {
      short8_t v = *(const short8_t*)(src + j * 8);
      *(short8_t*)((char*)Ws + o * 256 + ((half * 128 + j * 16) ^ ((o & 7) << 4))) = v;
    }
  }
  __syncthreads();

  const int wave = t >> 6, lane = t & 63;
  const int r = lane & 15, g = lane >> 4;
  const int swz = (r & 7) << 4;

  short8_t xa[4];
#pragma unroll
  for (int kk = 0; kk < 4; ++kk)
    xa[kk] = *(const short8_t*)((const char*)Xs + (wave * 16 + r) * 256 + ((kk * 64 + g * 16) ^ swz));

  const f32x4 zf = {0.f, 0.f, 0.f, 0.f};
  const int s0 = sBase + wave * 16 + 4 * g;
  const bool act = s0 < SP;

  // ---- pass 1: Wq ----
  {
    f32x4 acc[8];
#pragma unroll
    for (int ot = 0; ot < 8; ++ot) acc[ot] = zf;
#pragma unroll
    for (int ot = 0; ot < 8; ++ot) {
#pragma unroll
      for (int kk = 0; kk < 4; ++kk) {
        short8_t wb = *(const short8_t*)((const char*)Ws + (ot * 16 + r) * 256 + ((kk * 64 + g * 16) ^ swz));
        acc[ot] = __builtin_amdgcn_mfma_f32_16x16x32_bf16(xa[kk], wb, acc[ot], 0, 0, 0);
      }
    }
    if (act) {
#pragma unroll
      for (int ot = 0; ot < 8; ++ot) {
        float bvv = bq[ot * 16 + r];
#pragma unroll
        for (int i = 0; i < 4; ++i) {
          int s = s0 + i, n = s / 12, l2 = s - n * 12;
          qb[((b * 8 + ot) * 12 + l2) * 5120 + n * 16 + r] = f2bf(fmaxf(acc[ot][i] + bvv, 0.f));
        }
      }
    }
  }
  __syncthreads();   // all waves done reading Ws (Wq)
  {
    const unsigned short* src = Wvb + o * 128 + half * 64;
#pragma unroll
    for (int j = 0; j < 8; ++j) {
      short8_t v = *(const short8_t*)(src + j * 8);
      *(short8_t*)((char*)Ws + o * 256 + ((half * 128 + j * 16) ^ ((o & 7) << 4))) = v;
    }
  }
  __syncthreads();
  // ---- pass 2: Wv ----
  {
    f32x4 acc[8];
#pragma unroll
    for (int ot = 0; ot < 8; ++ot) acc[ot] = zf;
#pragma unroll
    for (int ot = 0; ot < 8; ++ot) {
#pragma unroll
      for (int kk = 0; kk < 4; ++kk) {
        short8_t wb = *(const short8_t*)((const char*)Ws + (ot * 16 + r) * 256 + ((kk * 64 + g * 16) ^ swz));
        acc[ot] = __builtin_amdgcn_mfma_f32_16x16x32_bf16(xa[kk], wb, acc[ot], 0, 0, 0);
      }
    }
    if (act) {
#pragma unroll
      for (int ot = 0; ot < 8; ++ot) {
        float bvv = bv[ot * 16 + r];
#pragma unroll
        for (int i = 0; i < 4; ++i) {
          int s = s0 + i, n = s / 12, l2 = s - n * 12;
          vb[((b * 8 + ot) * 12 + l2) * 5120 + r * 320 + posm(n)] = f2bf(fmaxf(acc[ot][i] + bvv, 0.f));
        }
      }
    }
  }
}

// ---------------- FUSED conv chain A: yR -> t -> zinR ----------------
// t = y + y@Wx + bx  (t kept in LDS, bf16)
// zin = relu(t@Wc + bc)*(wgt+1) + bias + x   -> bf16 R
__global__ __launch_bounds__(256) void k_conv12(
    const unsigned short* __restrict__ Wxb, const unsigned short* __restrict__ Wcb,
    const unsigned short* __restrict__ yRp, const float* __restrict__ bx,
    const float* __restrict__ bc, const float* __restrict__ aw,
    const float* __restrict__ ab, const float* __restrict__ axf,
    unsigned short* __restrict__ outR) {
  __shared__ unsigned short Xs[64 * 128];
  __shared__ unsigned short Ws[128 * 128];
  const int sBase = blockIdx.x * 64;
  const int b = blockIdx.z;
  const int t = threadIdx.x;

  {
    const int sl = t >> 2, q = t & 3;
    const int s = sBase + sl;
    const short8_t z8 = {0, 0, 0, 0, 0, 0, 0, 0};
    const unsigned short* row = yRp + (((size_t)b * SP + s) << 7);
#pragma unroll
    for (int j = 0; j < 4; ++j) {
      int cb = 16 * (4 * j + q);
      short8_t v = (s < SP) ? *(const short8_t*)((const char*)row + cb) : z8;
      *(short8_t*)((char*)Xs + sl * 256 + (cb ^ ((sl & 7) << 4))) = v;
    }
  }
  const int o = t >> 1, half = t & 1;
  {
    const unsigned short* src = Wxb + o * 128 + half * 64;
#pragma unroll
    for (int j = 0; j < 8; ++j) {
      short8_t v = *(const short8_t*)(src + j * 8);
      *(short8_t*)((char*)Ws + o * 256 + ((half * 128 + j * 16) ^ ((o & 7) << 4))) = v;
    }
  }
  __syncthreads();

  const int wave = t >> 6, lane = t & 63;
  const int r = lane & 15, g = lane >> 4;
  const int swz = (r & 7) << 4;
  const int s0 = sBase + wave * 16 + 4 * g;
  const bool act = s0 < SP;

  short8_t xa[4];
#pragma unroll
  for (int kk = 0; kk < 4; ++kk)
    xa[kk] = *(const short8_t*)((const char*)Xs + (wave * 16 + r) * 256 + ((kk * 64 + g * 16) ^ swz));

  const f32x4 zf = {0.f, 0.f, 0.f, 0.f};
  f32x4 acc[8];
#pragma unroll
  for (int ot = 0; ot < 8; ++ot) acc[ot] = zf;
#pragma unroll
  for (int ot = 0; ot < 8; ++ot) {
#pragma unroll
    for (int kk = 0; kk < 4; ++kk) {
      short8_t wb = *(const short8_t*)((const char*)Ws + (ot * 16 + r) * 256 + ((kk * 64 + g * 16) ^ swz));
      acc[ot] = __builtin_amdgcn_mfma_f32_16x16x32_bf16(xa[kk], wb, acc[ot], 0, 0, 0);
    }
  }

  // t = acc + bx + y (y from Xs), bf16-rounded
  unsigned short tpk[8][4];
  if (act) {
#pragma unroll
    for (int ot = 0; ot < 8; ++ot) {
      int oo = ot * 16 + r;
      float bvv = bx[oo];
#pragma unroll
      for (int i = 0; i < 4; ++i) {
        int u = wave * 16 + 4 * g + i;
        float y = bf2f(*(const unsigned short*)((const char*)Xs + u * 256 + ((2 * oo) ^ ((u & 7) << 4))));
        tpk[ot][i] = f2bf(acc[ot][i] + bvv + y);
      }
    }
  }
  __syncthreads();   // all reads of Xs (xa,y) and Ws (Wx) complete

  // overwrite Xs with t (rows >= SP stay zero), stage Wc
  if (act) {
#pragma unroll
    for (int ot = 0; ot < 8; ++ot) {
      int oo = ot * 16 + r;
#pragma unroll
      for (int i = 0; i < 4; ++i) {
        int u = wave * 16 + 4 * g + i;
        *(unsigned short*)((char*)Xs + u * 256 + ((2 * oo) ^ ((u & 7) << 4))) = tpk[ot][i];
      }
    }
  }
  {
    const unsigned short* src = Wcb + o * 128 + half * 64;
#pragma unroll
    for (int j = 0; j < 8; ++j) {
      short8_t v = *(const short8_t*)(src + j * 8);
      *(short8_t*)((char*)Ws + o * 256 + ((half * 128 + j * 16) ^ ((o & 7) << 4))) = v;
    }
  }
  __syncthreads();

  // GEMM2: t @ Wc
#pragma unroll
  for (int kk = 0; kk < 4; ++kk)
    xa[kk] = *(const short8_t*)((const char*)Xs + (wave * 16 + r) * 256 + ((kk * 64 + g * 16) ^ swz));
#pragma unroll
  for (int ot = 0; ot < 8; ++ot) acc[ot] = zf;
#pragma unroll
  for (int ot = 0; ot < 8; ++ot) {
#pragma unroll
    for (int kk = 0; kk < 4; ++kk) {
      short8_t wb = *(const short8_t*)((const char*)Ws + (ot * 16 + r) * 256 + ((kk * 64 + g * 16) ^ swz));
      acc[ot] = __builtin_amdgcn_mfma_f32_16x16x32_bf16(xa[kk], wb, acc[ot], 0, 0, 0);
    }
  }

  if (!act) return;
#pragma unroll
  for (int ot = 0; ot < 8; ++ot) {
    int oo = ot * 16 + r;
    float bvv = bc[oo];
    float4 w4 = *(const float4*)(aw + oo * SP + s0);
    float4 b4 = *(const float4*)(ab + oo * SP + s0);
    float4 x4 = *(const float4*)(axf + (size_t)(b * DCH + oo) * SP + s0);
#pragma unroll
    for (int i = 0; i < 4; ++i) {
      float rr = fmaxf(acc[ot][i] + bvv, 0.f);
      float val = rr * ((&w4.x)[i] + 1.f) + (&b4.x)[i] + (&x4.x)[i];
      outR[(((size_t)b * SP + s0 + i) << 7) + oo] = f2bf(val);
    }
  }
}

// ---------------- FUSED conv chain B: LN(zin) -> GLU -> t2R ----------------
// zn = LN(zin); g = (zn@Wg1+b1)*sigmoid(zn@Wg2+b2) (in LDS);
// t2 = (g@Wg3 + bg3 + zn)*(wgt+1) + bias  -> bf16 R
__global__ __launch_bounds__(256) void k_conv345(
    const unsigned short* __restrict__ Wb1, const unsigned short* __restrict__ Wb2,
    const unsigned short* __restrict__ Wb3, const unsigned short* __restrict__ Zr,
    const float* __restrict__ b1, const float* __restrict__ b2,
    const float* __restrict__ b3, const float* __restrict__ meanp,
    const float* __restrict__ rstdp, const float* __restrict__ aw,
    const float* __restrict__ ab, unsigned short* __restrict__ outR) {
  __shared__ unsigned short Xs[64 * 128];
  __shared__ unsigned short Ws[128 * 128];
  const int sBase = blockIdx.x * 64;
  const int b = blockIdx.z;
  const int t = threadIdx.x;

  // stage LN(zin) -> Xs (bf16)
  {
    const int sl = t >> 2, q = t & 3;
    const int s = sBase + sl;
    float m = 0.f, rr = 0.f;
    if (s < SP) { int l = s % 12; m = meanp[b * 12 + l]; rr = rstdp[b * 12 + l]; }
    const short8_t z8 = {0, 0, 0, 0, 0, 0, 0, 0};
    const unsigned short* row = Zr + (((size_t)b * SP + s) << 7);
#pragma unroll
    for (int j = 0; j < 4; ++j) {
      int cb = 16 * (4 * j + q);
      short8_t v = (s < SP) ? *(const short8_t*)((const char*)row + cb) : z8;
      union { unsigned int w[4]; short8_t s8; } u;
#pragma unroll
      for (int k2 = 0; k2 < 4; ++k2) {
        float f0 = (bf2f((unsigned short)v[2 * k2]) - m) * rr;
        float f1 = (bf2f((unsigned short)v[2 * k2 + 1]) - m) * rr;
        asm("v_cvt_pk_bf16_f32 %0, %1, %2" : "=v"(u.w[k2]) : "v"(f0), "v"(f1));
      }
      *(short8_t*)((char*)Xs + sl * 256 + (cb ^ ((sl & 7) << 4))) = u.s8;
    }
  }
  const int o = t >> 1, half = t & 1;
  {
    const unsigned short* src = Wb1 + o * 128 + half * 64;
#pragma unroll
    for (int j = 0; j < 8; ++j) {
      short8_t v = *(const short8_t*)(src + j * 8);
      *(short8_t*)((char*)Ws + o * 256 + ((half * 128 + j * 16) ^ ((o & 7) << 4))) = v;
    }
  }
  __syncthreads();

  const int wave = t >> 6, lane = t & 63;
  const int r = lane & 15, g = lane >> 4;
  const int swz = (r & 7) << 4;
  const int s0 = sBase + wave * 16 + 4 * g;
  const bool act = s0 < SP;

  short8_t xa[4];
#pragma unroll
  for (int kk = 0; kk < 4; ++kk)
    xa[kk] = *(const short8_t*)((const char*)Xs + (wave * 16 + r) * 256 + ((kk * 64 + g * 16) ^ swz));

  const f32x4 zf = {0.f, 0.f, 0.f, 0.f};
  f32x4 acc1[8], acc2[8];
#pragma unroll
  for (int ot = 0; ot < 8; ++ot) { acc1[ot] = zf; acc2[ot] = zf; }
#pragma unroll
  for (int ot = 0; ot < 8; ++ot) {
#pragma unroll
    for (int kk = 0; kk < 4; ++kk) {
      short8_t wb = *(const short8_t*)((const char*)Ws + (ot * 16 + r) * 256 + ((kk * 64 + g * 16) ^ swz));
      acc1[ot] = __builtin_amdgcn_mfma_f32_16x16x32_bf16(xa[kk], wb, acc1[ot], 0, 0, 0);
    }
  }
  __syncthreads();   // Ws (Wg1) readers done
  {
    const unsigned short* src = Wb2 + o * 128 + half * 64;
#pragma unroll
    for (int j = 0; j < 8; ++j) {
      short8_t v = *(const short8_t*)(src + j * 8);
      *(short8_t*)((char*)Ws + o * 256 + ((half * 128 + j * 16) ^ ((o & 7) << 4))) = v;
    }
  }
  __syncthreads();
#pragma unroll
  for (int ot = 0; ot < 8; ++ot) {
#pragma unroll
    for (int kk = 0; kk < 4; ++kk) {
      short8_t wb = *(const short8_t*)((const char*)Ws + (ot * 16 + r) * 256 + ((kk * 64 + g * 16) ^ swz));
      acc2[ot] = __builtin_amdgcn_mfma_f32_16x16x32_bf16(xa[kk], wb, acc2[ot], 0, 0, 0);
    }
  }

  // g (bf16) and LN(z) residual (bf16) into registers
  unsigned short gpk[8][4], zres[8][4];
  if (act) {
#pragma unroll
    for (int ot = 0; ot < 8; ++ot) {
      int oo = ot * 16 + r;
      float bb1 = b1[oo], bb2 = b2[oo];
#pragma unroll
      for (int i = 0; i < 4; ++i) {
        int u = wave * 16 + 4 * g + i;
        float v1 = acc1[ot][i] + bb1;
        float v2 = acc2[ot][i] + bb2;
        gpk[ot][i] = f2bf(v1 / (1.f + __expf(-v2)));
        zres[ot][i] = *(const unsigned short*)((const char*)Xs + u * 256 + ((2 * oo) ^ ((u & 7) << 4)));
      }
    }
  }
  __syncthreads();   // all reads of Xs (xa,zres) and Ws (Wg2) complete

  // overwrite Xs with g, stage Wg3
  if (act) {
#pragma unroll
    for (int ot = 0; ot < 8; ++ot) {
      int oo = ot * 16 + r;
#pragma unroll
      for (int i = 0; i < 4; ++i) {
        int u = wave * 16 + 4 * g + i;
        *(unsigned short*)((char*)Xs + u * 256 + ((2 * oo) ^ ((u & 7) << 4))) = gpk[ot][i];
      }
    }
  }
  {
    const unsigned short* src = Wb3 + o * 128 + half * 64;
#pragma unroll
    for (int j = 0; j < 8; ++j) {
      short8_t v = *(const short8_t*)(src + j * 8);
      *(short8_t*)((char*)Ws + o * 256 + ((half * 128 + j * 16) ^ ((o & 7) << 4))) = v;
    }
  }
  __syncthreads();

  // GEMM3: g @ Wg3
#pragma unroll
  for (int kk = 0; kk < 4; ++kk)
    xa[kk] = *(const short8_t*)((const char*)Xs + (wave * 16 + r) * 256 + ((kk * 64 + g * 16) ^ swz));
#pragma unroll
  for (int ot = 0; ot < 8; ++ot) acc1[ot] = zf;
#pragma unroll
  for (int ot = 0; ot < 8; ++ot) {
#pragma unroll
    for (int kk = 0; kk < 4; ++kk) {
      short8_t wb = *(const short8_t*)((const char*)Ws + (ot * 16 + r) * 256 + ((kk * 64 + g * 16) ^ swz));
      acc1[ot] = __builtin_amdgcn_mfma_f32_16x16x32_bf16(xa[kk], wb, acc1[ot], 0, 0, 0);
    }
  }

  if (!act) return;
#pragma unroll
  for (int ot = 0; ot < 8; ++ot) {
    int oo = ot * 16 + r;
    float bvv = b3[oo];
    float4 w4 = *(const float4*)(aw + oo * SP + s0);
    float4 b4 = *(const float4*)(ab + oo * SP + s0);
#pragma unroll
    for (int i = 0; i < 4; ++i) {
      float tt = acc1[ot][i] + bvv + bf2f(zres[ot][i]);
      outR[(((size_t)b * SP + s0 + i) << 7) + oo] = f2bf(tt * ((&w4.x)[i] + 1.f) + (&b4.x)[i]);
    }
  }
}

// ---------------- MFMA attention + graph diffusion ----------------
__global__ __launch_bounds__(256) void k_attn_mfma(
    const unsigned short* __restrict__ q5b, const unsigned short* __restrict__ vt5b,
    const float* __restrict__ memb, const float* __restrict__ memw,
    const unsigned short* __restrict__ adjTb, unsigned short* __restrict__ yR) {
  __shared__ unsigned short Mb[320 * 24];
  __shared__ unsigned short Vt[16 * 328];
  const int l = blockIdx.x, h = blockIdx.y, b = blockIdx.z;
  const int t = threadIdx.x;
  const int slice = (b * HH + h) * LNUM + l;
  const int msl = (h * LNUM + l) * NN * DK;
  const float w0 = memw[b * 4 + 0], w1 = memw[b * 4 + 1];
  const float w2 = memw[b * 4 + 2], w3 = memw[b * 4 + 3];

  for (int idx = t; idx < 640; idx += 256) {
    int n = idx >> 1, h8 = idx & 1;
    float v[8];
    if (n < NN) {
      int off = msl + n * 16 + h8 * 8;
      const float4* p0 = (const float4*)(memb + off);
      const float4* p1 = (const float4*)(memb + MST + off);
      const float4* p2 = (const float4*)(memb + 2 * MST + off);
      const float4* p3 = (const float4*)(memb + 3 * MST + off);
      float4 a0 = p0[0], a1 = p1[0], a2 = p2[0], a3 = p3[0];
      float4 c0 = p0[1], c1 = p1[1], c2 = p2[1], c3 = p3[1];
      v[0] = w0 * a0.x + w1 * a1.x + w2 * a2.x + w3 * a3.x;
      v[1] = w0 * a0.y + w1 * a1.y + w2 * a2.y + w3 * a3.y;
      v[2] = w0 * a0.z + w1 * a1.z + w2 * a2.z + w3 * a3.z;
      v[3] = w0 * a0.w + w1 * a1.w + w2 * a2.w + w3 * a3.w;
      v[4] = w0 * c0.x + w1 * c1.x + w2 * c2.x + w3 * c3.x;
      v[5] = w0 * c0.y + w1 * c1.y + w2 * c2.y + w3 * c3.y;
      v[6] = w0 * c0.z + w1 * c1.z + w2 * c2.z + w3 * c3.z;
      v[7] = w0 * c0.w + w1 * c1.w + w2 * c2.w + w3 * c3.w;
    } else {
#pragma unroll
      for (int j = 0; j < 8; ++j) v[j] = 0.f;
    }
    union { unsigned int w[4]; short8_t s; } u;
#pragma unroll
    for (int j = 0; j < 4; ++j)
      u.w[j] = (unsigned int)f2bf(v[2 * j]) | ((unsigned int)f2bf(v[2 * j + 1]) << 16);
    *(short8_t*)(Mb + n * 24 + h8 * 8) = u.s;
  }
  {
    const unsigned short* vsl = vt5b + slice * (16 * 320);
    for (int c = t; c < 640; c += 256) {
      int row = c / 40, ch = c - row * 40;
      short8_t vv = *(const short8_t*)(vsl + row * 320 + ch * 8);
      *(short8_t*)(Vt + row * 328 + ch * 8) = vv;
    }
  }
  __syncthreads();
  // Zero sigma-columns of Vt never written by the v-conv (n=307..319):
  // stale workspace bits would otherwise reach the PV MFMA (0*NaN = NaN).
  for (int idx = t; idx < 16 * 13; idx += 256) {
    int row = idx / 13, j = idx - row * 13;
    Vt[row * 328 + posm(NN + j)] = 0;
  }
  __syncthreads();

  const int wave = t >> 6, lane = t & 63;
  const int r = lane & 15, g = lane >> 4;
  const f32x4 zf = {0.f, 0.f, 0.f, 0.f};
  float maskv[4];
#pragma unroll
  for (int i = 0; i < 4; ++i) maskv[i] = (4 * g + i < 3) ? 1.f : 0.f;
  constexpr float CEXP = 0.25f * 1.44269504089f;

  for (int rt5 = 0; rt5 < 5; ++rt5) {
    const int n0 = (wave * 5 + rt5) * 16;
    short8_t bq = {0, 0, 0, 0, 0, 0, 0, 0};
    if (g < 2 && n0 + r < NN) bq = *(const short8_t*)(q5b + (slice * 320 + n0 + r) * 16 + 8 * g);
    f32x4 accPV = zf, accG = zf;
    float dn = 0.f;
#pragma unroll 2
    for (int mt = 0; mt < 10; ++mt) {
      const int mb = mt * 32;
      short8_t am0 = {0, 0, 0, 0, 0, 0, 0, 0}, am1 = am0;
      if (g < 2) {
        am0 = *(const short8_t*)(Mb + (mb + r) * 24 + 8 * g);
        am1 = *(const short8_t*)(Mb + (mb + 16 + r) * 24 + 8 * g);
      }
      f32x4 s0 = __builtin_amdgcn_mfma_f32_16x16x32_bf16(am0, bq, zf, 0, 0, 0);
      f32x4 s1 = __builtin_amdgcn_mfma_f32_16x16x32_bf16(am1, bq, zf, 0, 0, 0);
      float p0[4], p1[4];
#pragma unroll
      for (int i = 0; i < 4; ++i) {
        p0[i] = __builtin_amdgcn_exp2f(s0[i] * CEXP);
        p1[i] = __builtin_amdgcn_exp2f(s1[i] * CEXP);
      }
      if (mt == 9) {
#pragma unroll
        for (int i = 0; i < 4; ++i) p1[i] *= maskv[i];
      }
      dn += p0[0] + p0[1] + p0[2] + p0[3] + p1[0] + p1[1] + p1[2] + p1[3];
      union { unsigned int w[4]; short8_t s; } up;
      asm("v_cvt_pk_bf16_f32 %0, %1, %2" : "=v"(up.w[0]) : "v"(p0[0]), "v"(p0[1]));
      asm("v_cvt_pk_bf16_f32 %0, %1, %2" : "=v"(up.w[1]) : "v"(p0[2]), "v"(p0[3]));
      asm("v_cvt_pk_bf16_f32 %0, %1, %2" : "=v"(up.w[2]) : "v"(p1[0]), "v"(p1[1]));
      asm("v_cvt_pk_bf16_f32 %0, %1, %2" : "=v"(up.w[3]) : "v"(p1[2]), "v"(p1[3]));
      short8_t bv = *(const short8_t*)(Vt + r * 328 + mb + 8 * g);
      accPV = __builtin_amdgcn_mfma_f32_16x16x32_bf16(up.s, bv, accPV, 0, 0, 0);
      short8_t aj = *(const short8_t*)(adjTb + (n0 + r) * 320 + mb + 8 * g);
      accG = __builtin_amdgcn_mfma_f32_16x16x32_bf16(aj, bv, accG, 0, 0, 0);
    }
    dn += __shfl_xor(dn, 16);
    dn += __shfl_xor(dn, 32);
#pragma unroll
    for (int i = 0; i < 4; ++i) {
      int n = n0 + 4 * g + i;
      float di = __shfl(dn, 4 * g + i);
      if (n < NN) {
        yR[(((size_t)b * SP + n * 12 + l) << 7) + h * 16 + r] = f2bf(accPV[i] / di + accG[i]);
      }
    }
  }
}

// ---------------- layernorm (R-layout stats, fused/transposed apply) ----------------

__global__ __launch_bounds__(256) void k_lnstatR(
    const unsigned short* __restrict__ inR, float* __restrict__ pS, float* __restrict__ pSS) {
  const int chunk = blockIdx.x, b = blockIdx.y, t = threadIdx.x;
  const int sl = t >> 2, q = t & 3;
  const int s = chunk * 64 + sl;
  float sm = 0.f, sq = 0.f;
  if (s < SP) {
    const unsigned short* row = inR + (((size_t)b * SP + s) << 7);
#pragma unroll
    for (int j = 0; j < 4; ++j) {
      short8_t v = *(const short8_t*)((const char*)row + 16 * (4 * j + q));
#pragma unroll
      for (int k = 0; k < 8; ++k) {
        float f = bf2f((unsigned short)v[k]);
        sm += f; sq += f * f;
      }
    }
  }
  __shared__ float ls[256], lq[256];
  ls[t] = sm; lq[t] = sq;
  __syncthreads();
  if (t < 64) {
    ls[t * 4] = ls[t * 4] + ls[t * 4 + 1] + ls[t * 4 + 2] + ls[t * 4 + 3];
    lq[t * 4] = lq[t * 4] + lq[t * 4 + 1] + lq[t * 4 + 2] + lq[t * 4 + 3];
  }
  __syncthreads();
  if (t < 12) {
    float S = 0.f, SS = 0.f;
    for (int u2 = 0; u2 < 64; ++u2) {
      int s2 = chunk * 64 + u2;
      if (s2 < SP && s2 % 12 == t) { S += ls[u2 * 4]; SS += lq[u2 * 4]; }
    }
    pS[(b * LN_RCH + chunk) * 12 + t] = S;
    pSS[(b * LN_RCH + chunk) * 12 + t] = SS;
  }
}

__global__ __launch_bounds__(96) void k_lnfin2(
    const float* __restrict__ pS, const float* __restrict__ pSS,
    float* __restrict__ meanp, float* __restrict__ rstdp, int nch) {
  const int t = threadIdx.x;
  const int b = t / 12, l = t % 12;
  float S = 0.f, SS = 0.f;
  for (int c = 0; c < nch; ++c) {
    S += pS[(b * nch + c) * 12 + l];
    SS += pSS[(b * nch + c) * 12 + l];
  }
  float mu = S * (1.f / DN);
  float var = SS * (1.f / DN) - mu * mu;
  meanp[t] = mu;
  rstdp[t] = rsqrtf(fmaxf(var, 0.f) + 1e-5f);
}

// LN-apply from bf16 R-layout to std fp32 output via LDS transpose tile.
__global__ __launch_bounds__(256) void k_lnapplyT(
    const unsigned short* __restrict__ inR, const float* __restrict__ meanp,
    const float* __restrict__ rstdp, float* __restrict__ outp) {
  __shared__ float Ls[64][129];
  const int sBase = blockIdx.x * 64;
  const int b = blockIdx.y;
  const int t = threadIdx.x;
  {
    const int sl = t >> 2, q = t & 3;
    const int s = sBase + sl;
    if (s < SP) {
      int l = s % 12;
      float m = meanp[b * 12 + l], rr = rstdp[b * 12 + l];
      const unsigned short* row = inR + (((size_t)b * SP + s) << 7);
#pragma unroll
      for (int j = 0; j < 4; ++j) {
        short8_t v = *(const short8_t*)((const char*)row + 16 * (4 * j + q));
        int c0 = 8 * (4 * j + q);
#pragma unroll
        for (int k = 0; k < 8; ++k)
          Ls[sl][c0 + k] = (bf2f((unsigned short)v[k]) - m) * rr;
      }
    }
  }
  __syncthreads();
  const int c = t >> 1, h = t & 1;
  const int sW = sBase + h * 32;
  float* dst = outp + (size_t)(b * DCH + c) * SP + sW;
  const int lim = SP - sW;
#pragma unroll
  for (int j4 = 0; j4 < 8; ++j4) {
    int j = j4 * 4;
    if (j + 3 < lim) {
      float4 v;
      v.x = Ls[h * 32 + j + 0][c];
      v.y = Ls[h * 32 + j + 1][c];
      v.z = Ls[h * 32 + j + 2][c];
      v.w = Ls[h * 32 + j + 3][c];
      *(float4*)(dst + j) = v;
    } else {
#pragma unroll
      for (int e = 0; e < 4; ++e)
        if (j + e < lim) dst[j + e] = Ls[h * 32 + j + e][c];
    }
  }
}

}  // namespace

extern "C" void kernel_launch(void* const* d_in, const int* in_sizes, int n_in,
                              void* d_out, int out_size, void* d_ws, size_t ws_size,
                              hipStream_t stream) {
  (void)in_sizes; (void)n_in; (void)out_size; (void)ws_size;
  const float* x    = (const float*)d_in[0];
  const float* Wq   = (const float*)d_in[1];
  const float* bq   = (const float*)d_in[2];
  const float* Wv   = (const float*)d_in[3];
  const float* bv   = (const float*)d_in[4];
  const float* Wc   = (const float*)d_in[5];
  const float* bc   = (const float*)d_in[6];
  const float* Wx   = (const float*)d_in[7];
  const float* bx   = (const float*)d_in[8];
  const float* Wg1  = (const float*)d_in[9];
  const float* bg1  = (const float*)d_in[10];
  const float* Wg2  = (const float*)d_in[11];
  const float* bg2  = (const float*)d_in[12];
  const float* Wg3  = (const float*)d_in[13];
  const float* bg3  = (const float*)d_in[14];
  const float* memb = (const float*)d_in[15];
  const float* mimp = (const float*)d_in[16];
  const float* A1   = (const float*)d_in[17];
  const float* a1b  = (const float*)d_in[18];
  const float* A2   = (const float*)d_in[19];
  const float* a2b  = (const float*)d_in[20];
  const float* wgt  = (const float*)d_in[21];
  const float* bia  = (const float*)d_in[22];
  const float* nv1  = (const float*)d_in[23];
  const float* nv2  = (const float*)d_in[24];
  const float* sws  = (const float*)d_in[25];

  float* ws = (float*)d_ws;
  float* P0 = ws;                        // q5b -> t2R
  float* P1 = ws + (size_t)SZ;           // vt5b -> zinR
  float* P2 = ws + 2 * (size_t)SZ;       // yR
  float* sm = ws + 3 * (size_t)SZ;
  float* s1 = sm;
  float* s2 = sm + ADJN;
  float* s3 = sm + 2 * ADJN;
  float* adjT_f = sm + 3 * ADJN;            // 320*320 bf16 = 51200 floats
  float* memw = adjT_f + 51200;
  float* WbSlot = memw + 32;                // 7*16384 floats reserved (bf16 uses half)
  float* pS   = WbSlot + 7 * 16384;         // 8*58*12
  float* pSS  = pS + BB * LN_RCH * 12;
  float* meanp = pSS + BB * LN_RCH * 12;    // 96
  float* rstdp = meanp + 96;                // 96
  float* avgb  = rstdp + 96;                // 1024

  unsigned short* q5b   = (unsigned short*)P0;
  unsigned short* vt5b  = (unsigned short*)P1;
  unsigned short* yR    = (unsigned short*)P2;
  unsigned short* zinR  = (unsigned short*)P1;
  unsigned short* t2R   = (unsigned short*)P0;
  unsigned short* adjTb = (unsigned short*)adjT_f;
  unsigned short* Wb7   = (unsigned short*)WbSlot;

  k_cvtW<<<224, 256, 0, stream>>>(Wq, Wv, Wx, Wc, Wg1, Wg2, Wg3, (unsigned int*)Wb7);
  k_s1<<<NN, 320, 0, stream>>>(nv1, nv2, s1);
  k_smm<<<NN, 320, 0, stream>>>(s1, s1, s2);
  k_smm<<<NN, 320, 0, stream>>>(s2, s1, s3);
  k_adjT<<<(320 * 160 + 255) / 256, 256, 0, stream>>>(s1, s2, s3, sws, (unsigned int*)adjTb);
  k_avg<<<BB * DCH / 4, 256, 0, stream>>>(x, avgb);
  k_memw2<<<BB, 128, 0, stream>>>(avgb, A1, a1b, A2, a2b, mimp, memw);

  // fused q/v projection
  k_convqv<<<dim3(58, 1, BB), 256, 0, stream>>>(Wb7 + 0 * 16384, Wb7 + 1 * 16384,
                                                x, bq, bv, q5b, vt5b);

  // attention + graph -> yR
  k_attn_mfma<<<dim3(LNUM, HH, BB), 256, 0, stream>>>(q5b, vt5b, memb, memw, adjTb, yR);

  // fused: t = y + conv(y,Wx); zin = relu(conv(t,Wc))*(w+1)+bias+x  (yR -> zinR)
  k_conv12<<<dim3(58, 1, BB), 256, 0, stream>>>(Wb7 + 2 * 16384, Wb7 + 3 * 16384,
                                                yR, bx, bc, wgt, bia, x, zinR);

  // LN #1 stats
  k_lnstatR<<<dim3(LN_RCH, BB), 256, 0, stream>>>(zinR, pS, pSS);
  k_lnfin2<<<1, 96, 0, stream>>>(pS, pSS, meanp, rstdp, LN_RCH);

  // fused: zn=LN(zin); g=GLU(zn); t2=(conv(g,Wg3)+zn)*(w+1)+bias  (zinR -> t2R)
  k_conv345<<<dim3(58, 1, BB), 256, 0, stream>>>(Wb7 + 4 * 16384, Wb7 + 5 * 16384,
                                                 Wb7 + 6 * 16384, zinR, bg1, bg2, bg3,
                                                 meanp, rstdp, wgt, bia, t2R);

  // out = ln12(t2)
  k_lnstatR<<<dim3(LN_RCH, BB), 256, 0, stream>>>(t2R, pS, pSS);
  k_lnfin2<<<1, 96, 0, stream>>>(pS, pSS, meanp, rstdp, LN_RCH);
  k_lnapplyT<<<dim3(58, BB), 256, 0, stream>>>(t2R, meanp, rstdp, (float*)d_out);
}

// Round 12
// 193.620 us; speedup vs baseline: 3.4114x; 1.1380x over previous
//
#include <hip/hip_runtime.h>

namespace {

constexpr int NN   = 307;
constexpr int LNUM = 12;
constexpr int SP   = NN * LNUM;        // 3684
constexpr int DCH  = 128;
constexpr int HH   = 8;
constexpr int DK   = 16;
constexpr int BB   = 8;
constexpr int SZB  = DCH * SP;         // 471552 per batch
constexpr int SZ   = BB * SZB;         // 3772416 total
constexpr int ADJN = NN * NN;          // 94249
constexpr int DN   = DCH * NN;         // 39296 (layernorm group size)
constexpr int LN_RCH = 58;             // R-layout stat chunks (64 s each)
constexpr int MST  = HH * LNUM * NN * DK;  // mem_bank per-slot stride

typedef __attribute__((ext_vector_type(8))) short short8_t;
typedef __attribute__((ext_vector_type(4))) float f32x4;

__device__ inline unsigned short f2bf(float f) {
  unsigned int u = __builtin_bit_cast(unsigned int, f);
  unsigned int r = (u + 0x7FFFu + ((u >> 16) & 1u)) >> 16;
  return (unsigned short)r;
}
__device__ inline float bf2f(unsigned short h) {
  unsigned int u = ((unsigned int)h) << 16;
  return __builtin_bit_cast(float, u);
}

// sigma-permuted column position for m within the V / adjT buffers
__device__ __host__ inline int posm(int m) {
  int q = (m & 15) >> 2, sub = (m >> 4) & 1, i = m & 3;
  return (m & ~31) + 8 * q + 4 * sub + i;
}

// ---------------- small prep kernels ----------------

__global__ __launch_bounds__(256) void k_cvtW(
    const float* __restrict__ W0, const float* __restrict__ W1,
    const float* __restrict__ W2, const float* __restrict__ W3,
    const float* __restrict__ W4, const float* __restrict__ W5,
    const float* __restrict__ W6, unsigned int* __restrict__ Wb) {
  const float* srcs[7] = {W0, W1, W2, W3, W4, W5, W6};
  int idx = blockIdx.x * 256 + threadIdx.x;   // 0..57343
  int w = idx >> 13, off = idx & 8191;
  const float* s = srcs[w];
  float v0 = s[off * 2], v1 = s[off * 2 + 1];
  unsigned int pk;
  asm("v_cvt_pk_bf16_f32 %0, %1, %2" : "=v"(pk) : "v"(v0), "v"(v1));
  Wb[idx] = pk;
}

__global__ __launch_bounds__(320) void k_s1(
    const float* __restrict__ nv1, const float* __restrict__ nv2,
    float* __restrict__ out) {
  __shared__ float red[512];
  __shared__ float rowA[10];
  const int i = blockIdx.x, j = threadIdx.x;
  if (j < 10) rowA[j] = nv1[i * 10 + j];
  __syncthreads();
  float val = 0.f;
  if (j < NN) {
#pragma unroll
    for (int k = 0; k < 10; ++k) val += rowA[k] * nv2[k * NN + j];
    val = fmaxf(val, 0.f);
  }
  red[j] = (j < NN) ? val : -3.4e38f;
  if (j < 192) red[j + 320] = -3.4e38f;
  __syncthreads();
  for (int s = 256; s >= 1; s >>= 1) {
    if (j < s) red[j] = fmaxf(red[j], red[j + s]);
    __syncthreads();
  }
  float mx = red[0];
  __syncthreads();
  float e = (j < NN) ? __expf(val - mx) : 0.f;
  red[j] = e;
  if (j < 192) red[j + 320] = 0.f;
  __syncthreads();
  for (int s = 256; s >= 1; s >>= 1) {
    if (j < s) red[j] += red[j + s];
    __syncthreads();
  }
  if (j < NN) out[i * NN + j] = e / red[0];
}

__global__ __launch_bounds__(320) void k_smm(
    const float* __restrict__ Sa, const float* __restrict__ Sb,
    float* __restrict__ out) {
  __shared__ float red[512];
  __shared__ float rowA[320];
  const int i = blockIdx.x, j = threadIdx.x;
  if (j < NN) rowA[j] = Sa[i * NN + j];
  __syncthreads();
  float val = 0.f;
  if (j < NN) {
    for (int k = 0; k < NN; ++k) val += rowA[k] * Sb[k * NN + j];
  }
  red[j] = (j < NN) ? val : -3.4e38f;
  if (j < 192) red[j + 320] = -3.4e38f;
  __syncthreads();
  for (int s = 256; s >= 1; s >>= 1) {
    if (j < s) red[j] = fmaxf(red[j], red[j + s]);
    __syncthreads();
  }
  float mx = red[0];
  __syncthreads();
  float e = (j < NN) ? __expf(val - mx) : 0.f;
  red[j] = e;
  if (j < 192) red[j + 320] = 0.f;
  __syncthreads();
  for (int s = 256; s >= 1; s >>= 1) {
    if (j < s) red[j] += red[j + s];
    __syncthreads();
  }
  if (j < NN) out[i * NN + j] = e / red[0];
}

__global__ __launch_bounds__(256) void k_adjT(
    const float* __restrict__ s1, const float* __restrict__ s2,
    const float* __restrict__ s3, const float* __restrict__ sws,
    unsigned int* __restrict__ adjTw) {
  int idx = blockIdx.x * 256 + threadIdx.x;   // 0 .. 320*160-1
  if (idx >= 320 * 160) return;
  int n = idx / 160, wp = idx - n * 160;
  int pos0 = 2 * wp;
  int bq = pos0 & 31;
  int g = bq >> 3, sub = (bq >> 2) & 1, i = bq & 3;
  int m0 = (pos0 & ~31) + sub * 16 + 4 * g + i;
  float w0 = sws[0], w1 = sws[1], w2 = sws[2];
  float mm = fmaxf(w0, fmaxf(w1, w2));
  float e0 = __expf(w0 - mm), e1 = __expf(w1 - mm), e2 = __expf(w2 - mm);
  float inv = 1.f / (e0 + e1 + e2);
  e0 *= inv; e1 *= inv; e2 *= inv;
  float v0 = 0.f, v1 = 0.f;
  if (n < NN) {
    if (m0 < NN)     v0 = e0 * s1[m0 * NN + n] + e1 * s2[m0 * NN + n] + e2 * s3[m0 * NN + n];
    if (m0 + 1 < NN) v1 = e0 * s1[(m0 + 1) * NN + n] + e1 * s2[(m0 + 1) * NN + n] + e2 * s3[(m0 + 1) * NN + n];
  }
  adjTw[n * 160 + wp] = (unsigned int)f2bf(v0) | ((unsigned int)f2bf(v1) << 16);
}

__global__ __launch_bounds__(256) void k_avg(
    const float* __restrict__ x, float* __restrict__ avg) {
  const int row = blockIdx.x * 4 + (threadIdx.x >> 6);
  const int lane = threadIdx.x & 63;
  const float* p = x + (size_t)row * SP;
  float s = 0.f;
  for (int i = lane; i < SP / 4; i += 64) {
    float4 v = *(const float4*)(p + i * 4);
    s += v.x + v.y + v.z + v.w;
  }
  s += __shfl_xor(s, 1);  s += __shfl_xor(s, 2);  s += __shfl_xor(s, 4);
  s += __shfl_xor(s, 8);  s += __shfl_xor(s, 16); s += __shfl_xor(s, 32);
  if (lane == 0) avg[row] = s * (1.f / SP);
}

__global__ __launch_bounds__(128) void k_memw2(
    const float* __restrict__ avgg, const float* __restrict__ A1,
    const float* __restrict__ a1b, const float* __restrict__ A2,
    const float* __restrict__ a2b, const float* __restrict__ mimp,
    float* __restrict__ memw) {
  const int b = blockIdx.x, t = threadIdx.x;
  __shared__ float avg[128];
  __shared__ float hbuf[64];
  __shared__ float lg[4];
  avg[t] = avgg[b * 128 + t];
  __syncthreads();
  if (t < 64) {
    float a = a1b[t];
    for (int d = 0; d < 128; ++d) a += avg[d] * A1[d * 64 + t];
    hbuf[t] = fmaxf(a, 0.f);
  }
  __syncthreads();
  if (t < 4) {
    float a = a2b[t];
    for (int j = 0; j < 64; ++j) a += hbuf[j] * A2[j * 4 + t];
    lg[t] = a;
  }
  __syncthreads();
  if (t == 0) {
    float mx = fmaxf(fmaxf(lg[0], lg[1]), fmaxf(lg[2], lg[3]));
    float e[4]; float se = 0.f;
    for (int m = 0; m < 4; ++m) { e[m] = __expf(lg[m] - mx); se += e[m]; }
    float w[4]; float mx2 = -3.4e38f;
    for (int m = 0; m < 4; ++m) { w[m] = mimp[m] * (e[m] / se); mx2 = fmaxf(mx2, w[m]); }
    float se2 = 0.f;
    for (int m = 0; m < 4; ++m) { e[m] = __expf(w[m] - mx2); se2 += e[m]; }
    for (int m = 0; m < 4; ++m) memw[b * 4 + m] = e[m] / se2;
  }
}

// ---------------- fused q/v projection ----------------
__global__ __launch_bounds__(256) void k_convqv(
    const unsigned short* __restrict__ Wqb, const unsigned short* __restrict__ Wvb,
    const float* __restrict__ X, const float* __restrict__ bq,
    const float* __restrict__ bv, unsigned short* __restrict__ qb,
    unsigned short* __restrict__ vb) {
  __shared__ unsigned short Xs[64 * 128];
  __shared__ unsigned short Ws[128 * 128];
  const int sBase = blockIdx.x * 64;
  const int b = blockIdx.z;
  const int t = threadIdx.x;

  {
    const int u = t & 63, cp = t >> 6;
    const int s = sBase + u;
    const bool in = s < SP;
#pragma unroll
    for (int it = 0; it < 16; ++it) {
      int c0 = it * 8 + cp * 2;
      float v0 = 0.f, v1 = 0.f;
      if (in) {
        v0 = X[(size_t)(b * DCH + c0) * SP + s];
        v1 = X[(size_t)(b * DCH + c0 + 1) * SP + s];
      }
      unsigned int pk;
      asm("v_cvt_pk_bf16_f32 %0, %1, %2" : "=v"(pk) : "v"(v0), "v"(v1));
      *(unsigned int*)((char*)Xs + u * 256 + ((2 * c0) ^ ((u & 7) << 4))) = pk;
    }
  }
  const int o = t >> 1, half = t & 1;
  {
    const unsigned short* src = Wqb + o * 128 + half * 64;
#pragma unroll
    for (int j = 0; j < 8; ++j) {
      short8_t v = *(const short8_t*)(src + j * 8);
      *(short8_t*)((char*)Ws + o * 256 + ((half * 128 + j * 16) ^ ((o & 7) << 4))) = v;
    }
  }
  __syncthreads();

  const int wave = t >> 6, lane = t & 63;
  const int r = lane & 15, g = lane >> 4;
  const int swz = (r & 7) << 4;

  short8_t xa[4];
#pragma unroll
  for (int kk = 0; kk < 4; ++kk)
    xa[kk] = *(const short8_t*)((const char*)Xs + (wave * 16 + r) * 256 + ((kk * 64 + g * 16) ^ swz));

  const f32x4 zf = {0.f, 0.f, 0.f, 0.f};
  const int s0 = sBase + wave * 16 + 4 * g;
  const bool act = s0 < SP;

  // ---- pass 1: Wq ----
  {
    f32x4 acc[8];
#pragma unroll
    for (int ot = 0; ot < 8; ++ot) acc[ot] = zf;
#pragma unroll
    for (int ot = 0; ot < 8; ++ot) {
#pragma unroll
      for (int kk = 0; kk < 4; ++kk) {
        short8_t wb = *(const short8_t*)((const char*)Ws + (ot * 16 + r) * 256 + ((kk * 64 + g * 16) ^ swz));
        acc[ot] = __builtin_amdgcn_mfma_f32_16x16x32_bf16(xa[kk], wb, acc[ot], 0, 0, 0);
      }
    }
    if (act) {
#pragma unroll
      for (int ot = 0; ot < 8; ++ot) {
        float bvv = bq[ot * 16 + r];
#pragma unroll
        for (int i = 0; i < 4; ++i) {
          int s = s0 + i, n = s / 12, l2 = s - n * 12;
          qb[((b * 8 + ot) * 12 + l2) * 5120 + n * 16 + r] = f2bf(fmaxf(acc[ot][i] + bvv, 0.f));
        }
      }
    }
  }
  __syncthreads();
  {
    const unsigned short* src = Wvb + o * 128 + half * 64;
#pragma unroll
    for (int j = 0; j < 8; ++j) {
      short8_t v = *(const short8_t*)(src + j * 8);
      *(short8_t*)((char*)Ws + o * 256 + ((half * 128 + j * 16) ^ ((o & 7) << 4))) = v;
    }
  }
  __syncthreads();
  // ---- pass 2: Wv ----
  {
    f32x4 acc[8];
#pragma unroll
    for (int ot = 0; ot < 8; ++ot) acc[ot] = zf;
#pragma unroll
    for (int ot = 0; ot < 8; ++ot) {
#pragma unroll
      for (int kk = 0; kk < 4; ++kk) {
        short8_t wb = *(const short8_t*)((const char*)Ws + (ot * 16 + r) * 256 + ((kk * 64 + g * 16) ^ swz));
        acc[ot] = __builtin_amdgcn_mfma_f32_16x16x32_bf16(xa[kk], wb, acc[ot], 0, 0, 0);
      }
    }
    if (act) {
#pragma unroll
      for (int ot = 0; ot < 8; ++ot) {
        float bvv = bv[ot * 16 + r];
#pragma unroll
        for (int i = 0; i < 4; ++i) {
          int s = s0 + i, n = s / 12, l2 = s - n * 12;
          vb[((b * 8 + ot) * 12 + l2) * 5120 + r * 320 + posm(n)] = f2bf(fmaxf(acc[ot][i] + bvv, 0.f));
        }
      }
    }
  }
}

// ---------------- FUSED conv chain A: yR -> t -> zinR  (+ zin LN stats) ----------------
__global__ __launch_bounds__(256) void k_conv12(
    const unsigned short* __restrict__ Wxb, const unsigned short* __restrict__ Wcb,
    const unsigned short* __restrict__ yRp, const float* __restrict__ bx,
    const float* __restrict__ bc, const float* __restrict__ aw,
    const float* __restrict__ ab, const float* __restrict__ axf,
    unsigned short* __restrict__ outR, float* __restrict__ pS,
    float* __restrict__ pSS) {
  __shared__ unsigned short Xs[64 * 128];
  __shared__ unsigned short Ws[128 * 128];
  __shared__ float rowS[64], rowQ[64];
  const int sBase = blockIdx.x * 64;
  const int b = blockIdx.z;
  const int t = threadIdx.x;

  if (t < 64) { rowS[t] = 0.f; rowQ[t] = 0.f; }
  {
    const int sl = t >> 2, q = t & 3;
    const int s = sBase + sl;
    const short8_t z8 = {0, 0, 0, 0, 0, 0, 0, 0};
    const unsigned short* row = yRp + (((size_t)b * SP + s) << 7);
#pragma unroll
    for (int j = 0; j < 4; ++j) {
      int cb = 16 * (4 * j + q);
      short8_t v = (s < SP) ? *(const short8_t*)((const char*)row + cb) : z8;
      *(short8_t*)((char*)Xs + sl * 256 + (cb ^ ((sl & 7) << 4))) = v;
    }
  }
  const int o = t >> 1, half = t & 1;
  {
    const unsigned short* src = Wxb + o * 128 + half * 64;
#pragma unroll
    for (int j = 0; j < 8; ++j) {
      short8_t v = *(const short8_t*)(src + j * 8);
      *(short8_t*)((char*)Ws + o * 256 + ((half * 128 + j * 16) ^ ((o & 7) << 4))) = v;
    }
  }
  __syncthreads();

  const int wave = t >> 6, lane = t & 63;
  const int r = lane & 15, g = lane >> 4;
  const int swz = (r & 7) << 4;
  const int s0 = sBase + wave * 16 + 4 * g;
  const bool act = s0 < SP;

  short8_t xa[4];
#pragma unroll
  for (int kk = 0; kk < 4; ++kk)
    xa[kk] = *(const short8_t*)((const char*)Xs + (wave * 16 + r) * 256 + ((kk * 64 + g * 16) ^ swz));

  const f32x4 zf = {0.f, 0.f, 0.f, 0.f};
  f32x4 acc[8];
#pragma unroll
  for (int ot = 0; ot < 8; ++ot) acc[ot] = zf;
#pragma unroll
  for (int ot = 0; ot < 8; ++ot) {
#pragma unroll
    for (int kk = 0; kk < 4; ++kk) {
      short8_t wb = *(const short8_t*)((const char*)Ws + (ot * 16 + r) * 256 + ((kk * 64 + g * 16) ^ swz));
      acc[ot] = __builtin_amdgcn_mfma_f32_16x16x32_bf16(xa[kk], wb, acc[ot], 0, 0, 0);
    }
  }

  unsigned short tpk[8][4];
  if (act) {
#pragma unroll
    for (int ot = 0; ot < 8; ++ot) {
      int oo = ot * 16 + r;
      float bvv = bx[oo];
#pragma unroll
      for (int i = 0; i < 4; ++i) {
        int u = wave * 16 + 4 * g + i;
        float y = bf2f(*(const unsigned short*)((const char*)Xs + u * 256 + ((2 * oo) ^ ((u & 7) << 4))));
        tpk[ot][i] = f2bf(acc[ot][i] + bvv + y);
      }
    }
  }
  __syncthreads();

  if (act) {
#pragma unroll
    for (int ot = 0; ot < 8; ++ot) {
      int oo = ot * 16 + r;
#pragma unroll
      for (int i = 0; i < 4; ++i) {
        int u = wave * 16 + 4 * g + i;
        *(unsigned short*)((char*)Xs + u * 256 + ((2 * oo) ^ ((u & 7) << 4))) = tpk[ot][i];
      }
    }
  }
  {
    const unsigned short* src = Wcb + o * 128 + half * 64;
#pragma unroll
    for (int j = 0; j < 8; ++j) {
      short8_t v = *(const short8_t*)(src + j * 8);
      *(short8_t*)((char*)Ws + o * 256 + ((half * 128 + j * 16) ^ ((o & 7) << 4))) = v;
    }
  }
  __syncthreads();

#pragma unroll
  for (int kk = 0; kk < 4; ++kk)
    xa[kk] = *(const short8_t*)((const char*)Xs + (wave * 16 + r) * 256 + ((kk * 64 + g * 16) ^ swz));
#pragma unroll
  for (int ot = 0; ot < 8; ++ot) acc[ot] = zf;
#pragma unroll
  for (int ot = 0; ot < 8; ++ot) {
#pragma unroll
    for (int kk = 0; kk < 4; ++kk) {
      short8_t wb = *(const short8_t*)((const char*)Ws + (ot * 16 + r) * 256 + ((kk * 64 + g * 16) ^ swz));
      acc[ot] = __builtin_amdgcn_mfma_f32_16x16x32_bf16(xa[kk], wb, acc[ot], 0, 0, 0);
    }
  }

  float sm_[4] = {0.f, 0.f, 0.f, 0.f}, sq_[4] = {0.f, 0.f, 0.f, 0.f};
  if (act) {
#pragma unroll
    for (int ot = 0; ot < 8; ++ot) {
      int oo = ot * 16 + r;
      float bvv = bc[oo];
      float4 w4 = *(const float4*)(aw + oo * SP + s0);
      float4 b4 = *(const float4*)(ab + oo * SP + s0);
      float4 x4 = *(const float4*)(axf + (size_t)(b * DCH + oo) * SP + s0);
#pragma unroll
      for (int i = 0; i < 4; ++i) {
        float rr = fmaxf(acc[ot][i] + bvv, 0.f);
        float val = rr * ((&w4.x)[i] + 1.f) + (&b4.x)[i] + (&x4.x)[i];
        unsigned short pk = f2bf(val);
        outR[(((size_t)b * SP + s0 + i) << 7) + oo] = pk;
        float vq = bf2f(pk);
        sm_[i] += vq; sq_[i] += vq * vq;
      }
    }
  }
  // reduce across the 16 lanes sharing g (they cover all 128 channels of rows s0..s0+3)
#pragma unroll
  for (int msk = 1; msk <= 8; msk <<= 1) {
#pragma unroll
    for (int i = 0; i < 4; ++i) {
      sm_[i] += __shfl_xor(sm_[i], msk);
      sq_[i] += __shfl_xor(sq_[i], msk);
    }
  }
  if (r == 0 && act) {
#pragma unroll
    for (int i = 0; i < 4; ++i) {
      rowS[wave * 16 + 4 * g + i] = sm_[i];
      rowQ[wave * 16 + 4 * g + i] = sq_[i];
    }
  }
  __syncthreads();
  if (t < 12) {
    float S = 0.f, SS = 0.f;
    for (int u2 = 0; u2 < 64; ++u2) {
      int s2 = sBase + u2;
      if (s2 < SP && s2 % 12 == t) { S += rowS[u2]; SS += rowQ[u2]; }
    }
    pS[(b * LN_RCH + blockIdx.x) * 12 + t] = S;
    pSS[(b * LN_RCH + blockIdx.x) * 12 + t] = SS;
  }
}

// ---------------- FUSED conv chain B: LN(zin) -> GLU -> t2R (+ t2 LN stats) ----------------
__global__ __launch_bounds__(256) void k_conv345(
    const unsigned short* __restrict__ Wb1, const unsigned short* __restrict__ Wb2,
    const unsigned short* __restrict__ Wb3, const unsigned short* __restrict__ Zr,
    const float* __restrict__ b1, const float* __restrict__ b2,
    const float* __restrict__ b3, const float* __restrict__ pSin,
    const float* __restrict__ pSSin, const float* __restrict__ aw,
    const float* __restrict__ ab, unsigned short* __restrict__ outR,
    float* __restrict__ pSo, float* __restrict__ pSSo) {
  __shared__ unsigned short Xs[64 * 128];
  __shared__ unsigned short Ws[128 * 128];
  __shared__ float rowS[64], rowQ[64];
  __shared__ float meanv[12], rstdv[12];
  const int sBase = blockIdx.x * 64;
  const int b = blockIdx.z;
  const int t = threadIdx.x;

  if (t < 64) { rowS[t] = 0.f; rowQ[t] = 0.f; }
  // inline lnfin: fold 58 chunk partials for this b
  if (t < 12) {
    float S = 0.f, SS = 0.f;
    for (int c = 0; c < LN_RCH; ++c) {
      S += pSin[(b * LN_RCH + c) * 12 + t];
      SS += pSSin[(b * LN_RCH + c) * 12 + t];
    }
    float mu = S * (1.f / DN);
    float var = SS * (1.f / DN) - mu * mu;
    meanv[t] = mu;
    rstdv[t] = rsqrtf(fmaxf(var, 0.f) + 1e-5f);
  }
  __syncthreads();

  // stage LN(zin) -> Xs (bf16)
  {
    const int sl = t >> 2, q = t & 3;
    const int s = sBase + sl;
    float m = 0.f, rr = 0.f;
    if (s < SP) { int l = s % 12; m = meanv[l]; rr = rstdv[l]; }
    const short8_t z8 = {0, 0, 0, 0, 0, 0, 0, 0};
    const unsigned short* row = Zr + (((size_t)b * SP + s) << 7);
#pragma unroll
    for (int j = 0; j < 4; ++j) {
      int cb = 16 * (4 * j + q);
      short8_t v = (s < SP) ? *(const short8_t*)((const char*)row + cb) : z8;
      union { unsigned int w[4]; short8_t s8; } u;
#pragma unroll
      for (int k2 = 0; k2 < 4; ++k2) {
        float f0 = (bf2f((unsigned short)v[2 * k2]) - m) * rr;
        float f1 = (bf2f((unsigned short)v[2 * k2 + 1]) - m) * rr;
        asm("v_cvt_pk_bf16_f32 %0, %1, %2" : "=v"(u.w[k2]) : "v"(f0), "v"(f1));
      }
      *(short8_t*)((char*)Xs + sl * 256 + (cb ^ ((sl & 7) << 4))) = u.s8;
    }
  }
  const int o = t >> 1, half = t & 1;
  {
    const unsigned short* src = Wb1 + o * 128 + half * 64;
#pragma unroll
    for (int j = 0; j < 8; ++j) {
      short8_t v = *(const short8_t*)(src + j * 8);
      *(short8_t*)((char*)Ws + o * 256 + ((half * 128 + j * 16) ^ ((o & 7) << 4))) = v;
    }
  }
  __syncthreads();

  const int wave = t >> 6, lane = t & 63;
  const int r = lane & 15, g = lane >> 4;
  const int swz = (r & 7) << 4;
  const int s0 = sBase + wave * 16 + 4 * g;
  const bool act = s0 < SP;

  short8_t xa[4];
#pragma unroll
  for (int kk = 0; kk < 4; ++kk)
    xa[kk] = *(const short8_t*)((const char*)Xs + (wave * 16 + r) * 256 + ((kk * 64 + g * 16) ^ swz));

  const f32x4 zf = {0.f, 0.f, 0.f, 0.f};
  f32x4 acc1[8], acc2[8];
#pragma unroll
  for (int ot = 0; ot < 8; ++ot) { acc1[ot] = zf; acc2[ot] = zf; }
#pragma unroll
  for (int ot = 0; ot < 8; ++ot) {
#pragma unroll
    for (int kk = 0; kk < 4; ++kk) {
      short8_t wb = *(const short8_t*)((const char*)Ws + (ot * 16 + r) * 256 + ((kk * 64 + g * 16) ^ swz));
      acc1[ot] = __builtin_amdgcn_mfma_f32_16x16x32_bf16(xa[kk], wb, acc1[ot], 0, 0, 0);
    }
  }
  __syncthreads();
  {
    const unsigned short* src = Wb2 + o * 128 + half * 64;
#pragma unroll
    for (int j = 0; j < 8; ++j) {
      short8_t v = *(const short8_t*)(src + j * 8);
      *(short8_t*)((char*)Ws + o * 256 + ((half * 128 + j * 16) ^ ((o & 7) << 4))) = v;
    }
  }
  __syncthreads();
#pragma unroll
  for (int ot = 0; ot < 8; ++ot) {
#pragma unroll
    for (int kk = 0; kk < 4; ++kk) {
      short8_t wb = *(const short8_t*)((const char*)Ws + (ot * 16 + r) * 256 + ((kk * 64 + g * 16) ^ swz));
      acc2[ot] = __builtin_amdgcn_mfma_f32_16x16x32_bf16(xa[kk], wb, acc2[ot], 0, 0, 0);
    }
  }

  unsigned short gpk[8][4], zres[8][4];
  if (act) {
#pragma unroll
    for (int ot = 0; ot < 8; ++ot) {
      int oo = ot * 16 + r;
      float bb1 = b1[oo], bb2 = b2[oo];
#pragma unroll
      for (int i = 0; i < 4; ++i) {
        int u = wave * 16 + 4 * g + i;
        float v1 = acc1[ot][i] + bb1;
        float v2 = acc2[ot][i] + bb2;
        gpk[ot][i] = f2bf(v1 / (1.f + __expf(-v2)));
        zres[ot][i] = *(const unsigned short*)((const char*)Xs + u * 256 + ((2 * oo) ^ ((u & 7) << 4)));
      }
    }
  }
  __syncthreads();

  if (act) {
#pragma unroll
    for (int ot = 0; ot < 8; ++ot) {
      int oo = ot * 16 + r;
#pragma unroll
      for (int i = 0; i < 4; ++i) {
        int u = wave * 16 + 4 * g + i;
        *(unsigned short*)((char*)Xs + u * 256 + ((2 * oo) ^ ((u & 7) << 4))) = gpk[ot][i];
      }
    }
  }
  {
    const unsigned short* src = Wb3 + o * 128 + half * 64;
#pragma unroll
    for (int j = 0; j < 8; ++j) {
      short8_t v = *(const short8_t*)(src + j * 8);
      *(short8_t*)((char*)Ws + o * 256 + ((half * 128 + j * 16) ^ ((o & 7) << 4))) = v;
    }
  }
  __syncthreads();

#pragma unroll
  for (int kk = 0; kk < 4; ++kk)
    xa[kk] = *(const short8_t*)((const char*)Xs + (wave * 16 + r) * 256 + ((kk * 64 + g * 16) ^ swz));
#pragma unroll
  for (int ot = 0; ot < 8; ++ot) acc1[ot] = zf;
#pragma unroll
  for (int ot = 0; ot < 8; ++ot) {
#pragma unroll
    for (int kk = 0; kk < 4; ++kk) {
      short8_t wb = *(const short8_t*)((const char*)Ws + (ot * 16 + r) * 256 + ((kk * 64 + g * 16) ^ swz));
      acc1[ot] = __builtin_amdgcn_mfma_f32_16x16x32_bf16(xa[kk], wb, acc1[ot], 0, 0, 0);
    }
  }

  float sm_[4] = {0.f, 0.f, 0.f, 0.f}, sq_[4] = {0.f, 0.f, 0.f, 0.f};
  if (act) {
#pragma unroll
    for (int ot = 0; ot < 8; ++ot) {
      int oo = ot * 16 + r;
      float bvv = b3[oo];
      float4 w4 = *(const float4*)(aw + oo * SP + s0);
      float4 b4 = *(const float4*)(ab + oo * SP + s0);
#pragma unroll
      for (int i = 0; i < 4; ++i) {
        float tt = acc1[ot][i] + bvv + bf2f(zres[ot][i]);
        unsigned short pk = f2bf(tt * ((&w4.x)[i] + 1.f) + (&b4.x)[i]);
        outR[(((size_t)b * SP + s0 + i) << 7) + oo] = pk;
        float vq = bf2f(pk);
        sm_[i] += vq; sq_[i] += vq * vq;
      }
    }
  }
#pragma unroll
  for (int msk = 1; msk <= 8; msk <<= 1) {
#pragma unroll
    for (int i = 0; i < 4; ++i) {
      sm_[i] += __shfl_xor(sm_[i], msk);
      sq_[i] += __shfl_xor(sq_[i], msk);
    }
  }
  if (r == 0 && act) {
#pragma unroll
    for (int i = 0; i < 4; ++i) {
      rowS[wave * 16 + 4 * g + i] = sm_[i];
      rowQ[wave * 16 + 4 * g + i] = sq_[i];
    }
  }
  __syncthreads();
  if (t < 12) {
    float S = 0.f, SS = 0.f;
    for (int u2 = 0; u2 < 64; ++u2) {
      int s2 = sBase + u2;
      if (s2 < SP && s2 % 12 == t) { S += rowS[u2]; SS += rowQ[u2]; }
    }
    pSo[(b * LN_RCH + blockIdx.x) * 12 + t] = S;
    pSSo[(b * LN_RCH + blockIdx.x) * 12 + t] = SS;
  }
}

// ---------------- MFMA attention + graph diffusion ----------------
__global__ __launch_bounds__(256) void k_attn_mfma(
    const unsigned short* __restrict__ q5b, const unsigned short* __restrict__ vt5b,
    const float* __restrict__ memb, const float* __restrict__ memw,
    const unsigned short* __restrict__ adjTb, unsigned short* __restrict__ yR) {
  __shared__ unsigned short Mb[320 * 24];
  __shared__ unsigned short Vt[16 * 328];
  const int l = blockIdx.x, h = blockIdx.y, b = blockIdx.z;
  const int t = threadIdx.x;
  const int slice = (b * HH + h) * LNUM + l;
  const int msl = (h * LNUM + l) * NN * DK;
  const float w0 = memw[b * 4 + 0], w1 = memw[b * 4 + 1];
  const float w2 = memw[b * 4 + 2], w3 = memw[b * 4 + 3];

  for (int idx = t; idx < 640; idx += 256) {
    int n = idx >> 1, h8 = idx & 1;
    float v[8];
    if (n < NN) {
      int off = msl + n * 16 + h8 * 8;
      const float4* p0 = (const float4*)(memb + off);
      const float4* p1 = (const float4*)(memb + MST + off);
      const float4* p2 = (const float4*)(memb + 2 * MST + off);
      const float4* p3 = (const float4*)(memb + 3 * MST + off);
      float4 a0 = p0[0], a1 = p1[0], a2 = p2[0], a3 = p3[0];
      float4 c0 = p0[1], c1 = p1[1], c2 = p2[1], c3 = p3[1];
      v[0] = w0 * a0.x + w1 * a1.x + w2 * a2.x + w3 * a3.x;
      v[1] = w0 * a0.y + w1 * a1.y + w2 * a2.y + w3 * a3.y;
      v[2] = w0 * a0.z + w1 * a1.z + w2 * a2.z + w3 * a3.z;
      v[3] = w0 * a0.w + w1 * a1.w + w2 * a2.w + w3 * a3.w;
      v[4] = w0 * c0.x + w1 * c1.x + w2 * c2.x + w3 * c3.x;
      v[5] = w0 * c0.y + w1 * c1.y + w2 * c2.y + w3 * c3.y;
      v[6] = w0 * c0.z + w1 * c1.z + w2 * c2.z + w3 * c3.z;
      v[7] = w0 * c0.w + w1 * c1.w + w2 * c2.w + w3 * c3.w;
    } else {
#pragma unroll
      for (int j = 0; j < 8; ++j) v[j] = 0.f;
    }
    union { unsigned int w[4]; short8_t s; } u;
#pragma unroll
    for (int j = 0; j < 4; ++j)
      u.w[j] = (unsigned int)f2bf(v[2 * j]) | ((unsigned int)f2bf(v[2 * j + 1]) << 16);
    *(short8_t*)(Mb + n * 24 + h8 * 8) = u.s;
  }
  {
    const unsigned short* vsl = vt5b + slice * (16 * 320);
    for (int c = t; c < 640; c += 256) {
      int row = c / 40, ch = c - row * 40;
      short8_t vv = *(const short8_t*)(vsl + row * 320 + ch * 8);
      *(short8_t*)(Vt + row * 328 + ch * 8) = vv;
    }
  }
  __syncthreads();
  // Zero sigma-columns of Vt never written by the v-conv (n=307..319):
  // stale workspace bits would otherwise reach the PV MFMA (0*NaN = NaN).
  for (int idx = t; idx < 16 * 13; idx += 256) {
    int row = idx / 13, j = idx - row * 13;
    Vt[row * 328 + posm(NN + j)] = 0;
  }
  __syncthreads();

  const int wave = t >> 6, lane = t & 63;
  const int r = lane & 15, g = lane >> 4;
  const f32x4 zf = {0.f, 0.f, 0.f, 0.f};
  float maskv[4];
#pragma unroll
  for (int i = 0; i < 4; ++i) maskv[i] = (4 * g + i < 3) ? 1.f : 0.f;
  constexpr float CEXP = 0.25f * 1.44269504089f;

  for (int rt5 = 0; rt5 < 5; ++rt5) {
    const int n0 = (wave * 5 + rt5) * 16;
    short8_t bq = {0, 0, 0, 0, 0, 0, 0, 0};
    if (g < 2 && n0 + r < NN) bq = *(const short8_t*)(q5b + (slice * 320 + n0 + r) * 16 + 8 * g);
    f32x4 accPV = zf, accG = zf;
    float dn = 0.f;
#pragma unroll 2
    for (int mt = 0; mt < 10; ++mt) {
      const int mb = mt * 32;
      short8_t am0 = {0, 0, 0, 0, 0, 0, 0, 0}, am1 = am0;
      if (g < 2) {
        am0 = *(const short8_t*)(Mb + (mb + r) * 24 + 8 * g);
        am1 = *(const short8_t*)(Mb + (mb + 16 + r) * 24 + 8 * g);
      }
      f32x4 s0 = __builtin_amdgcn_mfma_f32_16x16x32_bf16(am0, bq, zf, 0, 0, 0);
      f32x4 s1 = __builtin_amdgcn_mfma_f32_16x16x32_bf16(am1, bq, zf, 0, 0, 0);
      float p0[4], p1[4];
#pragma unroll
      for (int i = 0; i < 4; ++i) {
        p0[i] = __builtin_amdgcn_exp2f(s0[i] * CEXP);
        p1[i] = __builtin_amdgcn_exp2f(s1[i] * CEXP);
      }
      if (mt == 9) {
#pragma unroll
        for (int i = 0; i < 4; ++i) p1[i] *= maskv[i];
      }
      dn += p0[0] + p0[1] + p0[2] + p0[3] + p1[0] + p1[1] + p1[2] + p1[3];
      union { unsigned int w[4]; short8_t s; } up;
      asm("v_cvt_pk_bf16_f32 %0, %1, %2" : "=v"(up.w[0]) : "v"(p0[0]), "v"(p0[1]));
      asm("v_cvt_pk_bf16_f32 %0, %1, %2" : "=v"(up.w[1]) : "v"(p0[2]), "v"(p0[3]));
      asm("v_cvt_pk_bf16_f32 %0, %1, %2" : "=v"(up.w[2]) : "v"(p1[0]), "v"(p1[1]));
      asm("v_cvt_pk_bf16_f32 %0, %1, %2" : "=v"(up.w[3]) : "v"(p1[2]), "v"(p1[3]));
      short8_t bv = *(const short8_t*)(Vt + r * 328 + mb + 8 * g);
      accPV = __builtin_amdgcn_mfma_f32_16x16x32_bf16(up.s, bv, accPV, 0, 0, 0);
      short8_t aj = *(const short8_t*)(adjTb + (n0 + r) * 320 + mb + 8 * g);
      accG = __builtin_amdgcn_mfma_f32_16x16x32_bf16(aj, bv, accG, 0, 0, 0);
    }
    dn += __shfl_xor(dn, 16);
    dn += __shfl_xor(dn, 32);
#pragma unroll
    for (int i = 0; i < 4; ++i) {
      int n = n0 + 4 * g + i;
      float di = __shfl(dn, 4 * g + i);
      if (n < NN) {
        yR[(((size_t)b * SP + n * 12 + l) << 7) + h * 16 + r] = f2bf(accPV[i] / di + accG[i]);
      }
    }
  }
}

// ---------------- final LN apply: stats fold inline, R -> std fp32 transpose ----------------
__global__ __launch_bounds__(256) void k_lnapplyT(
    const unsigned short* __restrict__ inR, const float* __restrict__ pS,
    const float* __restrict__ pSS, float* __restrict__ outp) {
  __shared__ float Ls[64][129];
  __shared__ float meanv[12], rstdv[12];
  const int sBase = blockIdx.x * 64;
  const int b = blockIdx.y;
  const int t = threadIdx.x;
  if (t < 12) {
    float S = 0.f, SS = 0.f;
    for (int c = 0; c < LN_RCH; ++c) {
      S += pS[(b * LN_RCH + c) * 12 + t];
      SS += pSS[(b * LN_RCH + c) * 12 + t];
    }
    float mu = S * (1.f / DN);
    float var = SS * (1.f / DN) - mu * mu;
    meanv[t] = mu;
    rstdv[t] = rsqrtf(fmaxf(var, 0.f) + 1e-5f);
  }
  __syncthreads();
  {
    const int sl = t >> 2, q = t & 3;
    const int s = sBase + sl;
    if (s < SP) {
      int l = s % 12;
      float m = meanv[l], rr = rstdv[l];
      const unsigned short* row = inR + (((size_t)b * SP + s) << 7);
#pragma unroll
      for (int j = 0; j < 4; ++j) {
        short8_t v = *(const short8_t*)((const char*)row + 16 * (4 * j + q));
        int c0 = 8 * (4 * j + q);
#pragma unroll
        for (int k = 0; k < 8; ++k)
          Ls[sl][c0 + k] = (bf2f((unsigned short)v[k]) - m) * rr;
      }
    }
  }
  __syncthreads();
  const int c = t >> 1, h = t & 1;
  const int sW = sBase + h * 32;
  float* dst = outp + (size_t)(b * DCH + c) * SP + sW;
  const int lim = SP - sW;
#pragma unroll
  for (int j4 = 0; j4 < 8; ++j4) {
    int j = j4 * 4;
    if (j + 3 < lim) {
      float4 v;
      v.x = Ls[h * 32 + j + 0][c];
      v.y = Ls[h * 32 + j + 1][c];
      v.z = Ls[h * 32 + j + 2][c];
      v.w = Ls[h * 32 + j + 3][c];
      *(float4*)(dst + j) = v;
    } else {
#pragma unroll
      for (int e = 0; e < 4; ++e)
        if (j + e < lim) dst[j + e] = Ls[h * 32 + j + e][c];
    }
  }
}

}  // namespace

extern "C" void kernel_launch(void* const* d_in, const int* in_sizes, int n_in,
                              void* d_out, int out_size, void* d_ws, size_t ws_size,
                              hipStream_t stream) {
  (void)in_sizes; (void)n_in; (void)out_size; (void)ws_size;
  const float* x    = (const float*)d_in[0];
  const float* Wq   = (const float*)d_in[1];
  const float* bq   = (const float*)d_in[2];
  const float* Wv   = (const float*)d_in[3];
  const float* bv   = (const float*)d_in[4];
  const float* Wc   = (const float*)d_in[5];
  const float* bc   = (const float*)d_in[6];
  const float* Wx   = (const float*)d_in[7];
  const float* bx   = (const float*)d_in[8];
  const float* Wg1  = (const float*)d_in[9];
  const float* bg1  = (const float*)d_in[10];
  const float* Wg2  = (const float*)d_in[11];
  const float* bg2  = (const float*)d_in[12];
  const float* Wg3  = (const float*)d_in[13];
  const float* bg3  = (const float*)d_in[14];
  const float* memb = (const float*)d_in[15];
  const float* mimp = (const float*)d_in[16];
  const float* A1   = (const float*)d_in[17];
  const float* a1b  = (const float*)d_in[18];
  const float* A2   = (const float*)d_in[19];
  const float* a2b  = (const float*)d_in[20];
  const float* wgt  = (const float*)d_in[21];
  const float* bia  = (const float*)d_in[22];
  const float* nv1  = (const float*)d_in[23];
  const float* nv2  = (const float*)d_in[24];
  const float* sws  = (const float*)d_in[25];

  float* ws = (float*)d_ws;
  float* P0 = ws;                        // q5b -> t2R
  float* P1 = ws + (size_t)SZ;           // vt5b -> zinR
  float* P2 = ws + 2 * (size_t)SZ;       // yR
  float* sm = ws + 3 * (size_t)SZ;
  float* s1 = sm;
  float* s2 = sm + ADJN;
  float* s3 = sm + 2 * ADJN;
  float* adjT_f = sm + 3 * ADJN;            // 320*320 bf16 = 51200 floats
  float* memw = adjT_f + 51200;
  float* WbSlot = memw + 32;                // 7*16384 floats reserved (bf16 uses half)
  float* pS1  = WbSlot + 7 * 16384;         // 8*58*12
  float* pSS1 = pS1 + BB * LN_RCH * 12;
  float* pS2  = pSS1 + BB * LN_RCH * 12;
  float* pSS2 = pS2 + BB * LN_RCH * 12;
  float* avgb = pSS2 + BB * LN_RCH * 12;    // 1024

  unsigned short* q5b   = (unsigned short*)P0;
  unsigned short* vt5b  = (unsigned short*)P1;
  unsigned short* yR    = (unsigned short*)P2;
  unsigned short* zinR  = (unsigned short*)P1;
  unsigned short* t2R   = (unsigned short*)P0;
  unsigned short* adjTb = (unsigned short*)adjT_f;
  unsigned short* Wb7   = (unsigned short*)WbSlot;

  k_cvtW<<<224, 256, 0, stream>>>(Wq, Wv, Wx, Wc, Wg1, Wg2, Wg3, (unsigned int*)Wb7);
  k_s1<<<NN, 320, 0, stream>>>(nv1, nv2, s1);
  k_smm<<<NN, 320, 0, stream>>>(s1, s1, s2);
  k_smm<<<NN, 320, 0, stream>>>(s2, s1, s3);
  k_adjT<<<(320 * 160 + 255) / 256, 256, 0, stream>>>(s1, s2, s3, sws, (unsigned int*)adjTb);
  k_avg<<<BB * DCH / 4, 256, 0, stream>>>(x, avgb);
  k_memw2<<<BB, 128, 0, stream>>>(avgb, A1, a1b, A2, a2b, mimp, memw);

  // fused q/v projection
  k_convqv<<<dim3(58, 1, BB), 256, 0, stream>>>(Wb7 + 0 * 16384, Wb7 + 1 * 16384,
                                                x, bq, bv, q5b, vt5b);

  // attention + graph -> yR
  k_attn_mfma<<<dim3(LNUM, HH, BB), 256, 0, stream>>>(q5b, vt5b, memb, memw, adjTb, yR);

  // fused: t = y + conv(y,Wx); zin = relu(conv(t,Wc))*(w+1)+bias+x; + zin LN stats
  k_conv12<<<dim3(58, 1, BB), 256, 0, stream>>>(Wb7 + 2 * 16384, Wb7 + 3 * 16384,
                                                yR, bx, bc, wgt, bia, x, zinR, pS1, pSS1);

  // fused: zn=LN(zin) [stats folded inline]; g=GLU(zn); t2=(conv(g,Wg3)+zn)*(w+1)+bias; + t2 stats
  k_conv345<<<dim3(58, 1, BB), 256, 0, stream>>>(Wb7 + 4 * 16384, Wb7 + 5 * 16384,
                                                 Wb7 + 6 * 16384, zinR, bg1, bg2, bg3,
                                                 pS1, pSS1, wgt, bia, t2R, pS2, pSS2);

  // out = ln12(t2): stats folded inline + transposed apply to std fp32
  k_lnapplyT<<<dim3(58, BB), 256, 0, stream>>>(t2R, pS2, pSS2, (float*)d_out);
}

// Round 14
// 182.016 us; speedup vs baseline: 3.6289x; 1.0638x over previous
//
#include <hip/hip_runtime.h>

namespace {

constexpr int NN   = 307;
constexpr int LNUM = 12;
constexpr int SP   = NN * LNUM;        // 3684
constexpr int DCH  = 128;
constexpr int HH   = 8;
constexpr int DK   = 16;
constexpr int BB   = 8;
constexpr int SZB  = DCH * SP;         // 471552 per batch
constexpr int SZ   = BB * SZB;         // 3772416 total
constexpr int ADJN = NN * NN;          // 94249
constexpr int DN   = DCH * NN;         // 39296 (layernorm group size)
constexpr int LN_RCH = 58;             // R-layout stat chunks (64 s each)
constexpr int MST  = HH * LNUM * NN * DK;  // mem_bank per-slot stride

typedef __attribute__((ext_vector_type(8))) short short8_t;
typedef __attribute__((ext_vector_type(4))) float f32x4;

__device__ inline unsigned short f2bf(float f) {
  unsigned int u = __builtin_bit_cast(unsigned int, f);
  unsigned int r = (u + 0x7FFFu + ((u >> 16) & 1u)) >> 16;
  return (unsigned short)r;
}
__device__ inline float bf2f(unsigned short h) {
  unsigned int u = ((unsigned int)h) << 16;
  return __builtin_bit_cast(float, u);
}

// sigma-permuted column position for m within the V / adjT buffers
__device__ __host__ inline int posm(int m) {
  int q = (m & 15) >> 2, sub = (m >> 4) & 1, i = m & 3;
  return (m & ~31) + 8 * q + 4 * sub + i;
}

// ---------------- merged prep 1: cvtW (224 blk) | avg (256 blk) | s1 (307 blk) ----------------
__global__ __launch_bounds__(256) void k_prep1(
    const float* __restrict__ W0, const float* __restrict__ W1,
    const float* __restrict__ W2, const float* __restrict__ W3,
    const float* __restrict__ W4, const float* __restrict__ W5,
    const float* __restrict__ W6, unsigned int* __restrict__ Wb,
    const float* __restrict__ x, float* __restrict__ avg,
    const float* __restrict__ nv1, const float* __restrict__ nv2,
    float* __restrict__ s1out) {
  __shared__ float red[256];
  __shared__ float rowA[10];
  const int blk = blockIdx.x;
  const int t = threadIdx.x;

  if (blk < 224) {
    // weight fp32 -> bf16, layout [o][c]
    const float* srcs[7] = {W0, W1, W2, W3, W4, W5, W6};
    int idx = blk * 256 + t;              // 0..57343
    int w = idx >> 13, off = idx & 8191;
    const float* s = srcs[w];
    float v0 = s[off * 2], v1 = s[off * 2 + 1];
    unsigned int pk;
    asm("v_cvt_pk_bf16_f32 %0, %1, %2" : "=v"(pk) : "v"(v0), "v"(v1));
    Wb[idx] = pk;
  } else if (blk < 480) {
    // row means of x: one wave per (b,d) row
    const int row = (blk - 224) * 4 + (t >> 6);   // 0..1023
    const int lane = t & 63;
    const float* p = x + (size_t)row * SP;
    float s = 0.f;
    for (int i = lane; i < SP / 4; i += 64) {
      float4 v = *(const float4*)(p + i * 4);
      s += v.x + v.y + v.z + v.w;
    }
    s += __shfl_xor(s, 1);  s += __shfl_xor(s, 2);  s += __shfl_xor(s, 4);
    s += __shfl_xor(s, 8);  s += __shfl_xor(s, 16); s += __shfl_xor(s, 32);
    if (lane == 0) avg[row] = s * (1.f / SP);
  } else {
    // s1 = softmax(relu(nv1 @ nv2)) row i, 256 threads x up-to-2 columns
    const int i = blk - 480;
    if (t < 10) rowA[t] = nv1[i * 10 + t];
    __syncthreads();
    float va = 0.f, vb = 0.f;
#pragma unroll
    for (int k = 0; k < 10; ++k) va += rowA[k] * nv2[k * NN + t];
    va = fmaxf(va, 0.f);
    const bool hasb = t < (NN - 256);   // t < 51
    if (hasb) {
#pragma unroll
      for (int k = 0; k < 10; ++k) vb += rowA[k] * nv2[k * NN + t + 256];
      vb = fmaxf(vb, 0.f);
    }
    red[t] = hasb ? fmaxf(va, vb) : va;
    __syncthreads();
    for (int s = 128; s >= 1; s >>= 1) {
      if (t < s) red[t] = fmaxf(red[t], red[t + s]);
      __syncthreads();
    }
    float M = red[0];
    __syncthreads();
    float ea = __expf(va - M);
    float eb = hasb ? __expf(vb - M) : 0.f;
    red[t] = ea + eb;
    __syncthreads();
    for (int s = 128; s >= 1; s >>= 1) {
      if (t < s) red[t] += red[t + s];
      __syncthreads();
    }
    float inv = 1.f / red[0];
    s1out[i * NN + t] = ea * inv;
    if (hasb) s1out[i * NN + t + 256] = eb * inv;
  }
}

__global__ __launch_bounds__(320) void k_smm(
    const float* __restrict__ Sa, const float* __restrict__ Sb,
    float* __restrict__ out) {
  __shared__ float red[512];
  __shared__ float rowA[320];
  const int i = blockIdx.x, j = threadIdx.x;
  if (j < NN) rowA[j] = Sa[i * NN + j];
  __syncthreads();
  float val = 0.f;
  if (j < NN) {
    for (int k = 0; k < NN; ++k) val += rowA[k] * Sb[k * NN + j];
  }
  red[j] = (j < NN) ? val : -3.4e38f;
  if (j < 192) red[j + 320] = -3.4e38f;
  __syncthreads();
  for (int s = 256; s >= 1; s >>= 1) {
    if (j < s) red[j] = fmaxf(red[j], red[j + s]);
    __syncthreads();
  }
  float mx = red[0];
  __syncthreads();
  float e = (j < NN) ? __expf(val - mx) : 0.f;
  red[j] = e;
  if (j < 192) red[j + 320] = 0.f;
  __syncthreads();
  for (int s = 256; s >= 1; s >>= 1) {
    if (j < s) red[j] += red[j + s];
    __syncthreads();
  }
  if (j < NN) out[i * NN + j] = e / red[0];
}

// ---------------- merged prep 4: adjT (200 blk) | memw2 (8 blk) ----------------
__global__ __launch_bounds__(256) void k_prep4(
    const float* __restrict__ s1, const float* __restrict__ s2,
    const float* __restrict__ s3, const float* __restrict__ sws,
    unsigned int* __restrict__ adjTw,
    const float* __restrict__ avgg, const float* __restrict__ A1,
    const float* __restrict__ a1b, const float* __restrict__ A2,
    const float* __restrict__ a2b, const float* __restrict__ mimp,
    float* __restrict__ memw) {
  __shared__ float avg[128];
  __shared__ float hbuf[64];
  __shared__ float lg[4];
  const int blk = blockIdx.x;
  const int t = threadIdx.x;

  if (blk < 200) {
    int idx = blk * 256 + t;   // 0 .. 51199 (= 320*160)
    int n = idx / 160, wp = idx - n * 160;
    int pos0 = 2 * wp;
    int bq = pos0 & 31;
    int g = bq >> 3, sub = (bq >> 2) & 1, i = bq & 3;
    int m0 = (pos0 & ~31) + sub * 16 + 4 * g + i;
    float w0 = sws[0], w1 = sws[1], w2 = sws[2];
    float mm = fmaxf(w0, fmaxf(w1, w2));
    float e0 = __expf(w0 - mm), e1 = __expf(w1 - mm), e2 = __expf(w2 - mm);
    float inv = 1.f / (e0 + e1 + e2);
    e0 *= inv; e1 *= inv; e2 *= inv;
    float v0 = 0.f, v1 = 0.f;
    if (n < NN) {
      if (m0 < NN)     v0 = e0 * s1[m0 * NN + n] + e1 * s2[m0 * NN + n] + e2 * s3[m0 * NN + n];
      if (m0 + 1 < NN) v1 = e0 * s1[(m0 + 1) * NN + n] + e1 * s2[(m0 + 1) * NN + n] + e2 * s3[(m0 + 1) * NN + n];
    }
    adjTw[n * 160 + wp] = (unsigned int)f2bf(v0) | ((unsigned int)f2bf(v1) << 16);
  } else {
    // memw2 for b = blk - 200 (threads >=128 only participate in barriers)
    const int b = blk - 200;
    if (t < 128) avg[t] = avgg[b * 128 + t];
    __syncthreads();
    if (t < 64) {
      float a = a1b[t];
      for (int d = 0; d < 128; ++d) a += avg[d] * A1[d * 64 + t];
      hbuf[t] = fmaxf(a, 0.f);
    }
    __syncthreads();
    if (t < 4) {
      float a = a2b[t];
      for (int j = 0; j < 64; ++j) a += hbuf[j] * A2[j * 4 + t];
      lg[t] = a;
    }
    __syncthreads();
    if (t == 0) {
      float mx = fmaxf(fmaxf(lg[0], lg[1]), fmaxf(lg[2], lg[3]));
      float e[4]; float se = 0.f;
      for (int m = 0; m < 4; ++m) { e[m] = __expf(lg[m] - mx); se += e[m]; }
      float w[4]; float mx2 = -3.4e38f;
      for (int m = 0; m < 4; ++m) { w[m] = mimp[m] * (e[m] / se); mx2 = fmaxf(mx2, w[m]); }
      float se2 = 0.f;
      for (int m = 0; m < 4; ++m) { e[m] = __expf(w[m] - mx2); se2 += e[m]; }
      for (int m = 0; m < 4; ++m) memw[b * 4 + m] = e[m] / se2;
    }
  }
}

// ---------------- fused q/v projection ----------------
__global__ __launch_bounds__(256) void k_convqv(
    const unsigned short* __restrict__ Wqb, const unsigned short* __restrict__ Wvb,
    const float* __restrict__ X, const float* __restrict__ bq,
    const float* __restrict__ bv, unsigned short* __restrict__ qb,
    unsigned short* __restrict__ vb) {
  __shared__ unsigned short Xs[64 * 128];
  __shared__ unsigned short Ws[128 * 128];
  const int sBase = blockIdx.x * 64;
  const int b = blockIdx.z;
  const int t = threadIdx.x;

  {
    const int u = t & 63, cp = t >> 6;
    const int s = sBase + u;
    const bool in = s < SP;
#pragma unroll
    for (int it = 0; it < 16; ++it) {
      int c0 = it * 8 + cp * 2;
      float v0 = 0.f, v1 = 0.f;
      if (in) {
        v0 = X[(size_t)(b * DCH + c0) * SP + s];
        v1 = X[(size_t)(b * DCH + c0 + 1) * SP + s];
      }
      unsigned int pk;
      asm("v_cvt_pk_bf16_f32 %0, %1, %2" : "=v"(pk) : "v"(v0), "v"(v1));
      *(unsigned int*)((char*)Xs + u * 256 + ((2 * c0) ^ ((u & 7) << 4))) = pk;
    }
  }
  const int o = t >> 1, half = t & 1;
  {
    const unsigned short* src = Wqb + o * 128 + half * 64;
#pragma unroll
    for (int j = 0; j < 8; ++j) {
      short8_t v = *(const short8_t*)(src + j * 8);
      *(short8_t*)((char*)Ws + o * 256 + ((half * 128 + j * 16) ^ ((o & 7) << 4))) = v;
    }
  }
  __syncthreads();

  const int wave = t >> 6, lane = t & 63;
  const int r = lane & 15, g = lane >> 4;
  const int swz = (r & 7) << 4;

  short8_t xa[4];
#pragma unroll
  for (int kk = 0; kk < 4; ++kk)
    xa[kk] = *(const short8_t*)((const char*)Xs + (wave * 16 + r) * 256 + ((kk * 64 + g * 16) ^ swz));

  const f32x4 zf = {0.f, 0.f, 0.f, 0.f};
  const int s0 = sBase + wave * 16 + 4 * g;
  const bool act = s0 < SP;

  // ---- pass 1: Wq ----
  {
    f32x4 acc[8];
#pragma unroll
    for (int ot = 0; ot < 8; ++ot) acc[ot] = zf;
#pragma unroll
    for (int ot = 0; ot < 8; ++ot) {
#pragma unroll
      for (int kk = 0; kk < 4; ++kk) {
        short8_t wb = *(const short8_t*)((const char*)Ws + (ot * 16 + r) * 256 + ((kk * 64 + g * 16) ^ swz));
        acc[ot] = __builtin_amdgcn_mfma_f32_16x16x32_bf16(xa[kk], wb, acc[ot], 0, 0, 0);
      }
    }
    if (act) {
#pragma unroll
      for (int ot = 0; ot < 8; ++ot) {
        float bvv = bq[ot * 16 + r];
#pragma unroll
        for (int i = 0; i < 4; ++i) {
          int s = s0 + i, n = s / 12, l2 = s - n * 12;
          qb[((b * 8 + ot) * 12 + l2) * 5120 + n * 16 + r] = f2bf(fmaxf(acc[ot][i] + bvv, 0.f));
        }
      }
    }
  }
  __syncthreads();
  {
    const unsigned short* src = Wvb + o * 128 + half * 64;
#pragma unroll
    for (int j = 0; j < 8; ++j) {
      short8_t v = *(const short8_t*)(src + j * 8);
      *(short8_t*)((char*)Ws + o * 256 + ((half * 128 + j * 16) ^ ((o & 7) << 4))) = v;
    }
  }
  __syncthreads();
  // ---- pass 2: Wv ----
  {
    f32x4 acc[8];
#pragma unroll
    for (int ot = 0; ot < 8; ++ot) acc[ot] = zf;
#pragma unroll
    for (int ot = 0; ot < 8; ++ot) {
#pragma unroll
      for (int kk = 0; kk < 4; ++kk) {
        short8_t wb = *(const short8_t*)((const char*)Ws + (ot * 16 + r) * 256 + ((kk * 64 + g * 16) ^ swz));
        acc[ot] = __builtin_amdgcn_mfma_f32_16x16x32_bf16(xa[kk], wb, acc[ot], 0, 0, 0);
      }
    }
    if (act) {
#pragma unroll
      for (int ot = 0; ot < 8; ++ot) {
        float bvv = bv[ot * 16 + r];
#pragma unroll
        for (int i = 0; i < 4; ++i) {
          int s = s0 + i, n = s / 12, l2 = s - n * 12;
          vb[((b * 8 + ot) * 12 + l2) * 5120 + r * 320 + posm(n)] = f2bf(fmaxf(acc[ot][i] + bvv, 0.f));
        }
      }
    }
  }
}

// ---------------- FUSED conv chain A: yR -> t -> zinR  (+ zin LN stats) ----------------
__global__ __launch_bounds__(256) void k_conv12(
    const unsigned short* __restrict__ Wxb, const unsigned short* __restrict__ Wcb,
    const unsigned short* __restrict__ yRp, const float* __restrict__ bx,
    const float* __restrict__ bc, const float* __restrict__ aw,
    const float* __restrict__ ab, const float* __restrict__ axf,
    unsigned short* __restrict__ outR, float* __restrict__ pS,
    float* __restrict__ pSS) {
  __shared__ unsigned short Xs[64 * 128];
  __shared__ unsigned short Ws[128 * 128];
  __shared__ float rowS[64], rowQ[64];
  const int sBase = blockIdx.x * 64;
  const int b = blockIdx.z;
  const int t = threadIdx.x;

  if (t < 64) { rowS[t] = 0.f; rowQ[t] = 0.f; }
  {
    const int sl = t >> 2, q = t & 3;
    const int s = sBase + sl;
    const short8_t z8 = {0, 0, 0, 0, 0, 0, 0, 0};
    const unsigned short* row = yRp + (((size_t)b * SP + s) << 7);
#pragma unroll
    for (int j = 0; j < 4; ++j) {
      int cb = 16 * (4 * j + q);
      short8_t v = (s < SP) ? *(const short8_t*)((const char*)row + cb) : z8;
      *(short8_t*)((char*)Xs + sl * 256 + (cb ^ ((sl & 7) << 4))) = v;
    }
  }
  const int o = t >> 1, half = t & 1;
  {
    const unsigned short* src = Wxb + o * 128 + half * 64;
#pragma unroll
    for (int j = 0; j < 8; ++j) {
      short8_t v = *(const short8_t*)(src + j * 8);
      *(short8_t*)((char*)Ws + o * 256 + ((half * 128 + j * 16) ^ ((o & 7) << 4))) = v;
    }
  }
  __syncthreads();

  const int wave = t >> 6, lane = t & 63;
  const int r = lane & 15, g = lane >> 4;
  const int swz = (r & 7) << 4;
  const int s0 = sBase + wave * 16 + 4 * g;
  const bool act = s0 < SP;

  short8_t xa[4];
#pragma unroll
  for (int kk = 0; kk < 4; ++kk)
    xa[kk] = *(const short8_t*)((const char*)Xs + (wave * 16 + r) * 256 + ((kk * 64 + g * 16) ^ swz));

  const f32x4 zf = {0.f, 0.f, 0.f, 0.f};
  f32x4 acc[8];
#pragma unroll
  for (int ot = 0; ot < 8; ++ot) acc[ot] = zf;
#pragma unroll
  for (int ot = 0; ot < 8; ++ot) {
#pragma unroll
    for (int kk = 0; kk < 4; ++kk) {
      short8_t wb = *(const short8_t*)((const char*)Ws + (ot * 16 + r) * 256 + ((kk * 64 + g * 16) ^ swz));
      acc[ot] = __builtin_amdgcn_mfma_f32_16x16x32_bf16(xa[kk], wb, acc[ot], 0, 0, 0);
    }
  }

  unsigned short tpk[8][4];
  if (act) {
#pragma unroll
    for (int ot = 0; ot < 8; ++ot) {
      int oo = ot * 16 + r;
      float bvv = bx[oo];
#pragma unroll
      for (int i = 0; i < 4; ++i) {
        int u = wave * 16 + 4 * g + i;
        float y = bf2f(*(const unsigned short*)((const char*)Xs + u * 256 + ((2 * oo) ^ ((u & 7) << 4))));
        tpk[ot][i] = f2bf(acc[ot][i] + bvv + y);
      }
    }
  }
  __syncthreads();

  if (act) {
#pragma unroll
    for (int ot = 0; ot < 8; ++ot) {
      int oo = ot * 16 + r;
#pragma unroll
      for (int i = 0; i < 4; ++i) {
        int u = wave * 16 + 4 * g + i;
        *(unsigned short*)((char*)Xs + u * 256 + ((2 * oo) ^ ((u & 7) << 4))) = tpk[ot][i];
      }
    }
  }
  {
    const unsigned short* src = Wcb + o * 128 + half * 64;
#pragma unroll
    for (int j = 0; j < 8; ++j) {
      short8_t v = *(const short8_t*)(src + j * 8);
      *(short8_t*)((char*)Ws + o * 256 + ((half * 128 + j * 16) ^ ((o & 7) << 4))) = v;
    }
  }
  __syncthreads();

#pragma unroll
  for (int kk = 0; kk < 4; ++kk)
    xa[kk] = *(const short8_t*)((const char*)Xs + (wave * 16 + r) * 256 + ((kk * 64 + g * 16) ^ swz));
#pragma unroll
  for (int ot = 0; ot < 8; ++ot) acc[ot] = zf;
#pragma unroll
  for (int ot = 0; ot < 8; ++ot) {
#pragma unroll
    for (int kk = 0; kk < 4; ++kk) {
      short8_t wb = *(const short8_t*)((const char*)Ws + (ot * 16 + r) * 256 + ((kk * 64 + g * 16) ^ swz));
      acc[ot] = __builtin_amdgcn_mfma_f32_16x16x32_bf16(xa[kk], wb, acc[ot], 0, 0, 0);
    }
  }

  float sm_[4] = {0.f, 0.f, 0.f, 0.f}, sq_[4] = {0.f, 0.f, 0.f, 0.f};
  if (act) {
#pragma unroll
    for (int ot = 0; ot < 8; ++ot) {
      int oo = ot * 16 + r;
      float bvv = bc[oo];
      float4 w4 = *(const float4*)(aw + oo * SP + s0);
      float4 b4 = *(const float4*)(ab + oo * SP + s0);
      float4 x4 = *(const float4*)(axf + (size_t)(b * DCH + oo) * SP + s0);
#pragma unroll
      for (int i = 0; i < 4; ++i) {
        float rr = fmaxf(acc[ot][i] + bvv, 0.f);
        float val = rr * ((&w4.x)[i] + 1.f) + (&b4.x)[i] + (&x4.x)[i];
        unsigned short pk = f2bf(val);
        outR[(((size_t)b * SP + s0 + i) << 7) + oo] = pk;
        float vq = bf2f(pk);
        sm_[i] += vq; sq_[i] += vq * vq;
      }
    }
  }
  // reduce across the 16 lanes sharing g (they cover all 128 channels of rows s0..s0+3)
#pragma unroll
  for (int msk = 1; msk <= 8; msk <<= 1) {
#pragma unroll
    for (int i = 0; i < 4; ++i) {
      sm_[i] += __shfl_xor(sm_[i], msk);
      sq_[i] += __shfl_xor(sq_[i], msk);
    }
  }
  if (r == 0 && act) {
#pragma unroll
    for (int i = 0; i < 4; ++i) {
      rowS[wave * 16 + 4 * g + i] = sm_[i];
      rowQ[wave * 16 + 4 * g + i] = sq_[i];
    }
  }
  __syncthreads();
  if (t < 12) {
    float S = 0.f, SS = 0.f;
    for (int u2 = 0; u2 < 64; ++u2) {
      int s2 = sBase + u2;
      if (s2 < SP && s2 % 12 == t) { S += rowS[u2]; SS += rowQ[u2]; }
    }
    pS[(b * LN_RCH + blockIdx.x) * 12 + t] = S;
    pSS[(b * LN_RCH + blockIdx.x) * 12 + t] = SS;
  }
}

// ---------------- FUSED conv chain B: LN(zin) -> GLU -> t2R (+ t2 LN stats) ----------------
__global__ __launch_bounds__(256) void k_conv345(
    const unsigned short* __restrict__ Wb1, const unsigned short* __restrict__ Wb2,
    const unsigned short* __restrict__ Wb3, const unsigned short* __restrict__ Zr,
    const float* __restrict__ b1, const float* __restrict__ b2,
    const float* __restrict__ b3, const float* __restrict__ pSin,
    const float* __restrict__ pSSin, const float* __restrict__ aw,
    const float* __restrict__ ab, unsigned short* __restrict__ outR,
    float* __restrict__ pSo, float* __restrict__ pSSo) {
  __shared__ unsigned short Xs[64 * 128];
  __shared__ unsigned short Ws[128 * 128];
  __shared__ float rowS[64], rowQ[64];
  __shared__ float meanv[12], rstdv[12];
  const int sBase = blockIdx.x * 64;
  const int b = blockIdx.z;
  const int t = threadIdx.x;

  if (t < 64) { rowS[t] = 0.f; rowQ[t] = 0.f; }
  // inline lnfin: fold 58 chunk partials for this b
  if (t < 12) {
    float S = 0.f, SS = 0.f;
    for (int c = 0; c < LN_RCH; ++c) {
      S += pSin[(b * LN_RCH + c) * 12 + t];
      SS += pSSin[(b * LN_RCH + c) * 12 + t];
    }
    float mu = S * (1.f / DN);
    float var = SS * (1.f / DN) - mu * mu;
    meanv[t] = mu;
    rstdv[t] = rsqrtf(fmaxf(var, 0.f) + 1e-5f);
  }
  __syncthreads();

  // stage LN(zin) -> Xs (bf16)
  {
    const int sl = t >> 2, q = t & 3;
    const int s = sBase + sl;
    float m = 0.f, rr = 0.f;
    if (s < SP) { int l = s % 12; m = meanv[l]; rr = rstdv[l]; }
    const short8_t z8 = {0, 0, 0, 0, 0, 0, 0, 0};
    const unsigned short* row = Zr + (((size_t)b * SP + s) << 7);
#pragma unroll
    for (int j = 0; j < 4; ++j) {
      int cb = 16 * (4 * j + q);
      short8_t v = (s < SP) ? *(const short8_t*)((const char*)row + cb) : z8;
      union { unsigned int w[4]; short8_t s8; } u;
#pragma unroll
      for (int k2 = 0; k2 < 4; ++k2) {
        float f0 = (bf2f((unsigned short)v[2 * k2]) - m) * rr;
        float f1 = (bf2f((unsigned short)v[2 * k2 + 1]) - m) * rr;
        asm("v_cvt_pk_bf16_f32 %0, %1, %2" : "=v"(u.w[k2]) : "v"(f0), "v"(f1));
      }
      *(short8_t*)((char*)Xs + sl * 256 + (cb ^ ((sl & 7) << 4))) = u.s8;
    }
  }
  const int o = t >> 1, half = t & 1;
  {
    const unsigned short* src = Wb1 + o * 128 + half * 64;
#pragma unroll
    for (int j = 0; j < 8; ++j) {
      short8_t v = *(const short8_t*)(src + j * 8);
      *(short8_t*)((char*)Ws + o * 256 + ((half * 128 + j * 16) ^ ((o & 7) << 4))) = v;
    }
  }
  __syncthreads();

  const int wave = t >> 6, lane = t & 63;
  const int r = lane & 15, g = lane >> 4;
  const int swz = (r & 7) << 4;
  const int s0 = sBase + wave * 16 + 4 * g;
  const bool act = s0 < SP;

  short8_t xa[4];
#pragma unroll
  for (int kk = 0; kk < 4; ++kk)
    xa[kk] = *(const short8_t*)((const char*)Xs + (wave * 16 + r) * 256 + ((kk * 64 + g * 16) ^ swz));

  const f32x4 zf = {0.f, 0.f, 0.f, 0.f};
  f32x4 acc1[8], acc2[8];
#pragma unroll
  for (int ot = 0; ot < 8; ++ot) { acc1[ot] = zf; acc2[ot] = zf; }
#pragma unroll
  for (int ot = 0; ot < 8; ++ot) {
#pragma unroll
    for (int kk = 0; kk < 4; ++kk) {
      short8_t wb = *(const short8_t*)((const char*)Ws + (ot * 16 + r) * 256 + ((kk * 64 + g * 16) ^ swz));
      acc1[ot] = __builtin_amdgcn_mfma_f32_16x16x32_bf16(xa[kk], wb, acc1[ot], 0, 0, 0);
    }
  }
  __syncthreads();
  {
    const unsigned short* src = Wb2 + o * 128 + half * 64;
#pragma unroll
    for (int j = 0; j < 8; ++j) {
      short8_t v = *(const short8_t*)(src + j * 8);
      *(short8_t*)((char*)Ws + o * 256 + ((half * 128 + j * 16) ^ ((o & 7) << 4))) = v;
    }
  }
  __syncthreads();
#pragma unroll
  for (int ot = 0; ot < 8; ++ot) {
#pragma unroll
    for (int kk = 0; kk < 4; ++kk) {
      short8_t wb = *(const short8_t*)((const char*)Ws + (ot * 16 + r) * 256 + ((kk * 64 + g * 16) ^ swz));
      acc2[ot] = __builtin_amdgcn_mfma_f32_16x16x32_bf16(xa[kk], wb, acc2[ot], 0, 0, 0);
    }
  }

  unsigned short gpk[8][4], zres[8][4];
  if (act) {
#pragma unroll
    for (int ot = 0; ot < 8; ++ot) {
      int oo = ot * 16 + r;
      float bb1 = b1[oo], bb2 = b2[oo];
#pragma unroll
      for (int i = 0; i < 4; ++i) {
        int u = wave * 16 + 4 * g + i;
        float v1 = acc1[ot][i] + bb1;
        float v2 = acc2[ot][i] + bb2;
        gpk[ot][i] = f2bf(v1 / (1.f + __expf(-v2)));
        zres[ot][i] = *(const unsigned short*)((const char*)Xs + u * 256 + ((2 * oo) ^ ((u & 7) << 4)));
      }
    }
  }
  __syncthreads();

  if (act) {
#pragma unroll
    for (int ot = 0; ot < 8; ++ot) {
      int oo = ot * 16 + r;
#pragma unroll
      for (int i = 0; i < 4; ++i) {
        int u = wave * 16 + 4 * g + i;
        *(unsigned short*)((char*)Xs + u * 256 + ((2 * oo) ^ ((u & 7) << 4))) = gpk[ot][i];
      }
    }
  }
  {
    const unsigned short* src = Wb3 + o * 128 + half * 64;
#pragma unroll
    for (int j = 0; j < 8; ++j) {
      short8_t v = *(const short8_t*)(src + j * 8);
      *(short8_t*)((char*)Ws + o * 256 + ((half * 128 + j * 16) ^ ((o & 7) << 4))) = v;
    }
  }
  __syncthreads();

#pragma unroll
  for (int kk = 0; kk < 4; ++kk)
    xa[kk] = *(const short8_t*)((const char*)Xs + (wave * 16 + r) * 256 + ((kk * 64 + g * 16) ^ swz));
#pragma unroll
  for (int ot = 0; ot < 8; ++ot) acc1[ot] = zf;
#pragma unroll
  for (int ot = 0; ot < 8; ++ot) {
#pragma unroll
    for (int kk = 0; kk < 4; ++kk) {
      short8_t wb = *(const short8_t*)((const char*)Ws + (ot * 16 + r) * 256 + ((kk * 64 + g * 16) ^ swz));
      acc1[ot] = __builtin_amdgcn_mfma_f32_16x16x32_bf16(xa[kk], wb, acc1[ot], 0, 0, 0);
    }
  }

  float sm_[4] = {0.f, 0.f, 0.f, 0.f}, sq_[4] = {0.f, 0.f, 0.f, 0.f};
  if (act) {
#pragma unroll
    for (int ot = 0; ot < 8; ++ot) {
      int oo = ot * 16 + r;
      float bvv = b3[oo];
      float4 w4 = *(const float4*)(aw + oo * SP + s0);
      float4 b4 = *(const float4*)(ab + oo * SP + s0);
#pragma unroll
      for (int i = 0; i < 4; ++i) {
        float tt = acc1[ot][i] + bvv + bf2f(zres[ot][i]);
        unsigned short pk = f2bf(tt * ((&w4.x)[i] + 1.f) + (&b4.x)[i]);
        outR[(((size_t)b * SP + s0 + i) << 7) + oo] = pk;
        float vq = bf2f(pk);
        sm_[i] += vq; sq_[i] += vq * vq;
      }
    }
  }
#pragma unroll
  for (int msk = 1; msk <= 8; msk <<= 1) {
#pragma unroll
    for (int i = 0; i < 4; ++i) {
      sm_[i] += __shfl_xor(sm_[i], msk);
      sq_[i] += __shfl_xor(sq_[i], msk);
    }
  }
  if (r == 0 && act) {
#pragma unroll
    for (int i = 0; i < 4; ++i) {
      rowS[wave * 16 + 4 * g + i] = sm_[i];
      rowQ[wave * 16 + 4 * g + i] = sq_[i];
    }
  }
  __syncthreads();
  if (t < 12) {
    float S = 0.f, SS = 0.f;
    for (int u2 = 0; u2 < 64; ++u2) {
      int s2 = sBase + u2;
      if (s2 < SP && s2 % 12 == t) { S += rowS[u2]; SS += rowQ[u2]; }
    }
    pSo[(b * LN_RCH + blockIdx.x) * 12 + t] = S;
    pSSo[(b * LN_RCH + blockIdx.x) * 12 + t] = SS;
  }
}

// ---------------- MFMA attention + graph diffusion ----------------
__global__ __launch_bounds__(256) void k_attn_mfma(
    const unsigned short* __restrict__ q5b, const unsigned short* __restrict__ vt5b,
    const float* __restrict__ memb, const float* __restrict__ memw,
    const unsigned short* __restrict__ adjTb, unsigned short* __restrict__ yR) {
  __shared__ unsigned short Mb[320 * 24];
  __shared__ unsigned short Vt[16 * 328];
  const int l = blockIdx.x, h = blockIdx.y, b = blockIdx.z;
  const int t = threadIdx.x;
  const int slice = (b * HH + h) * LNUM + l;
  const int msl = (h * LNUM + l) * NN * DK;
  const float w0 = memw[b * 4 + 0], w1 = memw[b * 4 + 1];
  const float w2 = memw[b * 4 + 2], w3 = memw[b * 4 + 3];

  for (int idx = t; idx < 640; idx += 256) {
    int n = idx >> 1, h8 = idx & 1;
    float v[8];
    if (n < NN) {
      int off = msl + n * 16 + h8 * 8;
      const float4* p0 = (const float4*)(memb + off);
      const float4* p1 = (const float4*)(memb + MST + off);
      const float4* p2 = (const float4*)(memb + 2 * MST + off);
      const float4* p3 = (const float4*)(memb + 3 * MST + off);
      float4 a0 = p0[0], a1 = p1[0], a2 = p2[0], a3 = p3[0];
      float4 c0 = p0[1], c1 = p1[1], c2 = p2[1], c3 = p3[1];
      v[0] = w0 * a0.x + w1 * a1.x + w2 * a2.x + w3 * a3.x;
      v[1] = w0 * a0.y + w1 * a1.y + w2 * a2.y + w3 * a3.y;
      v[2] = w0 * a0.z + w1 * a1.z + w2 * a2.z + w3 * a3.z;
      v[3] = w0 * a0.w + w1 * a1.w + w2 * a2.w + w3 * a3.w;
      v[4] = w0 * c0.x + w1 * c1.x + w2 * c2.x + w3 * c3.x;
      v[5] = w0 * c0.y + w1 * c1.y + w2 * c2.y + w3 * c3.y;
      v[6] = w0 * c0.z + w1 * c1.z + w2 * c2.z + w3 * c3.z;
      v[7] = w0 * c0.w + w1 * c1.w + w2 * c2.w + w3 * c3.w;
    } else {
#pragma unroll
      for (int j = 0; j < 8; ++j) v[j] = 0.f;
    }
    union { unsigned int w[4]; short8_t s; } u;
#pragma unroll
    for (int j = 0; j < 4; ++j)
      u.w[j] = (unsigned int)f2bf(v[2 * j]) | ((unsigned int)f2bf(v[2 * j + 1]) << 16);
    *(short8_t*)(Mb + n * 24 + h8 * 8) = u.s;
  }
  {
    const unsigned short* vsl = vt5b + slice * (16 * 320);
    for (int c = t; c < 640; c += 256) {
      int row = c / 40, ch = c - row * 40;
      short8_t vv = *(const short8_t*)(vsl + row * 320 + ch * 8);
      *(short8_t*)(Vt + row * 328 + ch * 8) = vv;
    }
  }
  __syncthreads();
  // Zero sigma-columns of Vt never written by the v-conv (n=307..319):
  // stale workspace bits would otherwise reach the PV MFMA (0*NaN = NaN).
  for (int idx = t; idx < 16 * 13; idx += 256) {
    int row = idx / 13, j = idx - row * 13;
    Vt[row * 328 + posm(NN + j)] = 0;
  }
  __syncthreads();

  const int wave = t >> 6, lane = t & 63;
  const int r = lane & 15, g = lane >> 4;
  const f32x4 zf = {0.f, 0.f, 0.f, 0.f};
  float maskv[4];
#pragma unroll
  for (int i = 0; i < 4; ++i) maskv[i] = (4 * g + i < 3) ? 1.f : 0.f;
  constexpr float CEXP = 0.25f * 1.44269504089f;

  for (int rt5 = 0; rt5 < 5; ++rt5) {
    const int n0 = (wave * 5 + rt5) * 16;
    short8_t bq = {0, 0, 0, 0, 0, 0, 0, 0};
    if (g < 2 && n0 + r < NN) bq = *(const short8_t*)(q5b + (slice * 320 + n0 + r) * 16 + 8 * g);
    f32x4 accPV = zf, accG = zf;
    float dn = 0.f;
#pragma unroll 2
    for (int mt = 0; mt < 10; ++mt) {
      const int mb = mt * 32;
      short8_t am0 = {0, 0, 0, 0, 0, 0, 0, 0}, am1 = am0;
      if (g < 2) {
        am0 = *(const short8_t*)(Mb + (mb + r) * 24 + 8 * g);
        am1 = *(const short8_t*)(Mb + (mb + 16 + r) * 24 + 8 * g);
      }
      f32x4 s0 = __builtin_amdgcn_mfma_f32_16x16x32_bf16(am0, bq, zf, 0, 0, 0);
      f32x4 s1 = __builtin_amdgcn_mfma_f32_16x16x32_bf16(am1, bq, zf, 0, 0, 0);
      float p0[4], p1[4];
#pragma unroll
      for (int i = 0; i < 4; ++i) {
        p0[i] = __builtin_amdgcn_exp2f(s0[i] * CEXP);
        p1[i] = __builtin_amdgcn_exp2f(s1[i] * CEXP);
      }
      if (mt == 9) {
#pragma unroll
        for (int i = 0; i < 4; ++i) p1[i] *= maskv[i];
      }
      dn += p0[0] + p0[1] + p0[2] + p0[3] + p1[0] + p1[1] + p1[2] + p1[3];
      union { unsigned int w[4]; short8_t s; } up;
      asm("v_cvt_pk_bf16_f32 %0, %1, %2" : "=v"(up.w[0]) : "v"(p0[0]), "v"(p0[1]));
      asm("v_cvt_pk_bf16_f32 %0, %1, %2" : "=v"(up.w[1]) : "v"(p0[2]), "v"(p0[3]));
      asm("v_cvt_pk_bf16_f32 %0, %1, %2" : "=v"(up.w[2]) : "v"(p1[0]), "v"(p1[1]));
      asm("v_cvt_pk_bf16_f32 %0, %1, %2" : "=v"(up.w[3]) : "v"(p1[2]), "v"(p1[3]));
      short8_t bv = *(const short8_t*)(Vt + r * 328 + mb + 8 * g);
      accPV = __builtin_amdgcn_mfma_f32_16x16x32_bf16(up.s, bv, accPV, 0, 0, 0);
      short8_t aj = *(const short8_t*)(adjTb + (n0 + r) * 320 + mb + 8 * g);
      accG = __builtin_amdgcn_mfma_f32_16x16x32_bf16(aj, bv, accG, 0, 0, 0);
    }
    dn += __shfl_xor(dn, 16);
    dn += __shfl_xor(dn, 32);
#pragma unroll
    for (int i = 0; i < 4; ++i) {
      int n = n0 + 4 * g + i;
      float di = __shfl(dn, 4 * g + i);
      if (n < NN) {
        yR[(((size_t)b * SP + n * 12 + l) << 7) + h * 16 + r] = f2bf(accPV[i] / di + accG[i]);
      }
    }
  }
}

// ---------------- final LN apply: stats fold inline, R -> std fp32 transpose ----------------
__global__ __launch_bounds__(256) void k_lnapplyT(
    const unsigned short* __restrict__ inR, const float* __restrict__ pS,
    const float* __restrict__ pSS, float* __restrict__ outp) {
  __shared__ float Ls[64][129];
  __shared__ float meanv[12], rstdv[12];
  const int sBase = blockIdx.x * 64;
  const int b = blockIdx.y;
  const int t = threadIdx.x;
  if (t < 12) {
    float S = 0.f, SS = 0.f;
    for (int c = 0; c < LN_RCH; ++c) {
      S += pS[(b * LN_RCH + c) * 12 + t];
      SS += pSS[(b * LN_RCH + c) * 12 + t];
    }
    float mu = S * (1.f / DN);
    float var = SS * (1.f / DN) - mu * mu;
    meanv[t] = mu;
    rstdv[t] = rsqrtf(fmaxf(var, 0.f) + 1e-5f);
  }
  __syncthreads();
  {
    const int sl = t >> 2, q = t & 3;
    const int s = sBase + sl;
    if (s < SP) {
      int l = s % 12;
      float m = meanv[l], rr = rstdv[l];
      const unsigned short* row = inR + (((size_t)b * SP + s) << 7);
#pragma unroll
      for (int j = 0; j < 4; ++j) {
        short8_t v = *(const short8_t*)((const char*)row + 16 * (4 * j + q));
        int c0 = 8 * (4 * j + q);
#pragma unroll
        for (int k = 0; k < 8; ++k)
          Ls[sl][c0 + k] = (bf2f((unsigned short)v[k]) - m) * rr;
      }
    }
  }
  __syncthreads();
  const int c = t >> 1, h = t & 1;
  const int sW = sBase + h * 32;
  float* dst = outp + (size_t)(b * DCH + c) * SP + sW;
  const int lim = SP - sW;
#pragma unroll
  for (int j4 = 0; j4 < 8; ++j4) {
    int j = j4 * 4;
    if (j + 3 < lim) {
      float4 v;
      v.x = Ls[h * 32 + j + 0][c];
      v.y = Ls[h * 32 + j + 1][c];
      v.z = Ls[h * 32 + j + 2][c];
      v.w = Ls[h * 32 + j + 3][c];
      *(float4*)(dst + j) = v;
    } else {
#pragma unroll
      for (int e = 0; e < 4; ++e)
        if (j + e < lim) dst[j + e] = Ls[h * 32 + j + e][c];
    }
  }
}

}  // namespace

extern "C" void kernel_launch(void* const* d_in, const int* in_sizes, int n_in,
                              void* d_out, int out_size, void* d_ws, size_t ws_size,
                              hipStream_t stream) {
  (void)in_sizes; (void)n_in; (void)out_size; (void)ws_size;
  const float* x    = (const float*)d_in[0];
  const float* Wq   = (const float*)d_in[1];
  const float* bq   = (const float*)d_in[2];
  const float* Wv   = (const float*)d_in[3];
  const float* bv   = (const float*)d_in[4];
  const float* Wc   = (const float*)d_in[5];
  const float* bc   = (const float*)d_in[6];
  const float* Wx   = (const float*)d_in[7];
  const float* bx   = (const float*)d_in[8];
  const float* Wg1  = (const float*)d_in[9];
  const float* bg1  = (const float*)d_in[10];
  const float* Wg2  = (const float*)d_in[11];
  const float* bg2  = (const float*)d_in[12];
  const float* Wg3  = (const float*)d_in[13];
  const float* bg3  = (const float*)d_in[14];
  const float* memb = (const float*)d_in[15];
  const float* mimp = (const float*)d_in[16];
  const float* A1   = (const float*)d_in[17];
  const float* a1b  = (const float*)d_in[18];
  const float* A2   = (const float*)d_in[19];
  const float* a2b  = (const float*)d_in[20];
  const float* wgt  = (const float*)d_in[21];
  const float* bia  = (const float*)d_in[22];
  const float* nv1  = (const float*)d_in[23];
  const float* nv2  = (const float*)d_in[24];
  const float* sws  = (const float*)d_in[25];

  float* ws = (float*)d_ws;
  float* P0 = ws;                        // q5b -> t2R
  float* P1 = ws + (size_t)SZ;           // vt5b -> zinR
  float* P2 = ws + 2 * (size_t)SZ;       // yR
  float* sm = ws + 3 * (size_t)SZ;
  float* s1 = sm;
  float* s2 = sm + ADJN;
  float* s3 = sm + 2 * ADJN;
  float* adjT_f = sm + 3 * ADJN;            // 320*320 bf16 = 51200 floats
  float* memw = adjT_f + 51200;
  float* WbSlot = memw + 32;                // 7*16384 floats reserved (bf16 uses half)
  float* pS1  = WbSlot + 7 * 16384;         // 8*58*12
  float* pSS1 = pS1 + BB * LN_RCH * 12;
  float* pS2  = pSS1 + BB * LN_RCH * 12;
  float* pSS2 = pS2 + BB * LN_RCH * 12;
  float* avgb = pSS2 + BB * LN_RCH * 12;    // 1024

  unsigned short* q5b   = (unsigned short*)P0;
  unsigned short* vt5b  = (unsigned short*)P1;
  unsigned short* yR    = (unsigned short*)P2;
  unsigned short* zinR  = (unsigned short*)P1;
  unsigned short* t2R   = (unsigned short*)P0;
  unsigned short* adjTb = (unsigned short*)adjT_f;
  unsigned short* Wb7   = (unsigned short*)WbSlot;

  // merged prep: cvtW | avg | s1
  k_prep1<<<224 + 256 + NN, 256, 0, stream>>>(Wq, Wv, Wx, Wc, Wg1, Wg2, Wg3,
                                              (unsigned int*)Wb7, x, avgb, nv1, nv2, s1);
  k_smm<<<NN, 320, 0, stream>>>(s1, s1, s2);
  k_smm<<<NN, 320, 0, stream>>>(s2, s1, s3);
  // merged prep: adjT | memw2
  k_prep4<<<200 + BB, 256, 0, stream>>>(s1, s2, s3, sws, (unsigned int*)adjTb,
                                        avgb, A1, a1b, A2, a2b, mimp, memw);

  // fused q/v projection
  k_convqv<<<dim3(58, 1, BB), 256, 0, stream>>>(Wb7 + 0 * 16384, Wb7 + 1 * 16384,
                                                x, bq, bv, q5b, vt5b);

  // attention + graph -> yR
  k_attn_mfma<<<dim3(LNUM, HH, BB), 256, 0, stream>>>(q5b, vt5b, memb, memw, adjTb, yR);

  // fused: t = y + conv(y,Wx); zin = relu(conv(t,Wc))*(w+1)+bias+x; + zin LN stats
  k_conv12<<<dim3(58, 1, BB), 256, 0, stream>>>(Wb7 + 2 * 16384, Wb7 + 3 * 16384,
                                                yR, bx, bc, wgt, bia, x, zinR, pS1, pSS1);

  // fused: zn=LN(zin) [stats folded inline]; g=GLU(zn); t2=(conv(g,Wg3)+zn)*(w+1)+bias; + t2 stats
  k_conv345<<<dim3(58, 1, BB), 256, 0, stream>>>(Wb7 + 4 * 16384, Wb7 + 5 * 16384,
                                                 Wb7 + 6 * 16384, zinR, bg1, bg2, bg3,
                                                 pS1, pSS1, wgt, bia, t2R, pS2, pSS2);

  // out = ln12(t2): stats folded inline + transposed apply to std fp32
  k_lnapplyT<<<dim3(58, BB), 256, 0, stream>>>(t2R, pS2, pSS2, (float*)d_out);
}